// Round 10
// baseline (369.228 us; speedup 1.0000x reference)
//
#include <hip/hip_runtime.h>
#include <hip/hip_bf16.h>

typedef __hip_bfloat16 bf16;
typedef unsigned short ushort_t;
typedef __attribute__((ext_vector_type(8))) __bf16 bfv8;
typedef __attribute__((ext_vector_type(16))) float f32x16;

#define B_   4
#define CIN  64
#define CI   16
#define H_   127
#define W_   127
#define HW   (H_*W_)
#define KS   7
#define ST   4
#define OH_  31
#define L_   961
#define D_   784
#define TOPM 100

// ---- workspace layout (float offsets) ----
#define N1   1032256          // B*HW*CI elements (one conv-out array)
#define WG_O 4
#define WT_O (WG_O + 9216)
#define WP_O (WT_O + 1024)
#define BG_O (WP_O + 1024)
#define BT_O (BG_O + 16)
#define BP_O (BT_O + 16)
#define SM_O (BP_O + 16)
#define SB_O (SM_O + 16)
#define RW_O (SB_O + 16)
#define RB_O (RW_O + 1024)
#define B1_O 12448
// planes region at B1_O: b1h,b1l,b2h,b2l each N1 ushorts (total 2*N1 floats)
#define S3_O (B1_O + 3*N1)
#define WB_O (S3_O + B_*D_)   // conv MFMA B matrix: 9*64*64 ushorts = 18432 floats
#define REG_O (WB_O + 18432)
#define XHSZ 4129024
#define SROW 964              // padded Sc row stride
#define SCSLOT 926464
#define AGSZ 753424
#define TKROW 112
#define SLST 72               // LDS row stride in ushorts (conflict-free, measured r8)

#define FULL_BYTES ((size_t)(REG_O + XHSZ + 4*AGSZ) * 4)   // ~41.1 MB
#define MID_BYTES  ((size_t)(REG_O + XHSZ) * 4)            // ~29.0 MB

__device__ __forceinline__ float bf2f(bf16 v) { return __bfloat162float(v); }

template <typename T> struct Ld;
template <> struct Ld<float> {
  static __device__ __forceinline__ float f(const void* p, int i) { return ((const float*)p)[i]; }
};
template <> struct Ld<bf16> {
  static __device__ __forceinline__ float f(const void* p, int i) { return bf2f(((const bf16*)p)[i]); }
};

__device__ __forceinline__ unsigned fmap(float f) {
  unsigned u = __float_as_uint(f);
  return (u & 0x80000000u) ? ~u : (u | 0x80000000u);
}
__device__ __forceinline__ float unfmap(unsigned kk) {
  unsigned u = (kk & 0x80000000u) ? (kk & 0x7fffffffu) : ~kk;
  return __uint_as_float(u);
}

// RNE fp32 -> bf16 bits, and hi/lo split
__device__ __forceinline__ ushort_t f2bf(float x) {
  unsigned u = __float_as_uint(x);
  return (ushort_t)((u + 0x7FFFu + ((u >> 16) & 1u)) >> 16);
}
__device__ __forceinline__ void splitbf(float x, ushort_t& h, ushort_t& l) {
  h = f2bf(x);
  float hf = __uint_as_float(((unsigned)h) << 16);
  l = f2bf(x - hf);
}

// -------- dtype detector: flag=1 -> fp32 buffers, flag=0 -> bf16 -----------------
__global__ void k_detect(const unsigned short* __restrict__ xh, int* __restrict__ flag) {
  int tid = threadIdx.x;  // 64
  int c = 0;
#pragma unroll
  for (int j = 0; j < 2; ++j) {
    unsigned u = xh[tid * 2 + j];
    unsigned e = (u >> 7) & 0xFF;
    if (e >= 134) c++;
  }
#pragma unroll
  for (int o = 32; o; o >>= 1) c += __shfl_down(c, o);
  if (tid == 0) *flag = (c >= 8) ? 1 : 0;
}

// -------- weight prep ------------------------------------------------------------
#define LDW(ptr, i) (f ? ((const float*)(ptr))[i] : bf2f(((const bf16*)(ptr))[i]))
__global__ __launch_bounds__(256) void k_prep(
    const int* __restrict__ flag,
    const void* g_w, const void* t_w, const void* p_w,
    const void* g_b, const void* t_b, const void* p_b,
    const void* m_w, const void* m_b, const void* r_w, const void* r_b,
    float* __restrict__ ws)
{
  int tid = threadIdx.x;
  int f = *flag;
  for (int i = tid; i < 9216; i += 256) {
    int o = i & 15, t = i >> 4, c = t & 63, tap = t >> 6;
    ws[WG_O + i] = LDW(g_w, (o * 64 + c) * 9 + tap);
  }
  for (int i = tid; i < 1024; i += 256) {
    int o = i & 15, c = i >> 4;
    ws[WT_O + i] = LDW(t_w, o * 64 + c);
    ws[WP_O + i] = LDW(p_w, o * 64 + c);
  }
  if (tid < 16) {
    ws[BG_O + tid] = LDW(g_b, tid);
    ws[BT_O + tid] = LDW(t_b, tid);
    ws[BP_O + tid] = LDW(p_b, tid);
    float s = 0.f;
    for (int c = 0; c < 64; ++c) s += LDW(m_w, tid * 64 + c);
    ws[SM_O + tid] = s;
    ws[SB_O + tid] = LDW(m_b, tid);
  }
  for (int i = tid; i < 1024; i += 256) ws[RW_O + i] = LDW(r_w, i);
  if (tid < 64) ws[RB_O + tid] = LDW(r_b, tid);
  // conv MFMA B: wB[tap][col64][c64] bf16. col 0-15 g, 16-31 theta(tap4), 32-47 phi(tap4)
  ushort_t* wB = (ushort_t*)(ws + WB_O);
  for (int i = tid; i < 9 * 64 * 64; i += 256) {
    int c = i & 63, t = i >> 6, col = t & 63, tap = t >> 6;
    float v = 0.f;
    if (col < 16) v = LDW(g_w, (col * 64 + c) * 9 + tap);
    else if (col < 32) { if (tap == 4) v = LDW(t_w, (col - 16) * 64 + c); }
    else if (col < 48) { if (tap == 4) v = LDW(p_w, (col - 32) * 64 + c); }
    wB[i] = f2bf(v);
  }
}

// -------- x [B,64,H,W] -> HWC: fp32 (flag=1 or mode=0) or bf16 (flag=0, mode=1) --
__global__ __launch_bounds__(256) void k_hwc(
    const int* __restrict__ flag, const void* __restrict__ x,
    float* __restrict__ xh, ushort_t* __restrict__ xhb, int mode)
{
  __shared__ float tile[64][65];
  int pix0 = blockIdx.x * 64;
  int tid = threadIdx.x;
  int g = tid >> 6, p = tid & 63;
  int pix = pix0 + p;
  bool ok = pix < B_ * HW;
  int bb = ok ? pix / HW : 0;
  int r  = ok ? pix - bb * HW : 0;
  int fl = *flag;
  if (fl) {
    const float* xf = (const float*)x;
    for (int c = g * 16; c < g * 16 + 16; ++c)
      tile[p][c] = ok ? xf[((size_t)bb * CIN + c) * HW + r] : 0.f;
  } else {
    const bf16* xb = (const bf16*)x;
    for (int c = g * 16; c < g * 16 + 16; ++c)
      tile[p][c] = ok ? bf2f(xb[((size_t)bb * CIN + c) * HW + r]) : 0.f;
  }
  __syncthreads();
  int c2 = tid & 63, pg = tid >> 6;
  if (fl || !mode) {
    for (int k = 0; k < 16; ++k) {
      int p2 = pg * 16 + k;
      int pix2 = pix0 + p2;
      if (pix2 < B_ * HW) xh[(size_t)pix2 * 64 + c2] = tile[p2][c2];
    }
  } else {
    for (int k = 0; k < 16; ++k) {
      int p2 = pg * 16 + k;
      int pix2 = pix0 + p2;
      if (pix2 < B_ * HW) xhb[(size_t)pix2 * 64 + c2] = f2bf(tile[p2][c2]);
    }
  }
}

// -------- MFMA conv (flag=0 only): all three convs as one 64px x 64col GEMM ------
// C = X · Wb^T, K=576 (tap*64+c). Structural copy of verified k_score staging:
// wave0 stages A rows (tap-shifted pixels), wave1 stages B rows (wB), named-reg
// prefetch, SLST=72, identical frag + C/D mappings.
__global__ __launch_bounds__(256) void k_conv3(
    const int* __restrict__ flag, const float* __restrict__ ws,
    const ushort_t* __restrict__ xhb,
    ushort_t* __restrict__ b1h, ushort_t* __restrict__ b1l,
    ushort_t* __restrict__ b2h, ushort_t* __restrict__ b2l,
    float* __restrict__ b3)
{
  if (*flag) return;
  __shared__ ushort_t sA[64 * SLST], sB[64 * SLST];
  int bz = blockIdx.z;
  int px0 = blockIdx.x * 64;
  int tid = threadIdx.x, lane = tid & 63, wv = tid >> 6;

  int pix = px0 + lane;
  bool pok = pix < HW;
  int ph = pok ? pix / W_ : 0;
  int pw = pok ? pix - ph * W_ : 0;
  const ushort_t* xb = xhb + (size_t)bz * HW * 64;
  const ushort_t* wB = (const ushort_t*)(ws + WB_O);
  ushort_t* drow = ((wv == 0) ? sA : sB) + lane * SLST;

  int fr = lane & 31, kh = (lane >> 5) << 3;
  int aoff = (((wv >> 1) << 5) + fr) * SLST + kh;
  int boff = (((wv & 1) << 5) + fr) * SLST + kh;

  f32x16 acc = {0.f,0.f,0.f,0.f,0.f,0.f,0.f,0.f,0.f,0.f,0.f,0.f,0.f,0.f,0.f,0.f};
  const int4 z4 = make_int4(0, 0, 0, 0);
  int4 v0 = z4, v1 = z4, v2 = z4, v3 = z4, v4 = z4, v5 = z4, v6 = z4, v7 = z4;

  // prefetch round 0 (tap 0: dh=-1, dw=-1)
  if (wv == 0) {
    int hh = ph - 1, ww = pw - 1;
    if (pok && hh >= 0 && ww >= 0) {
      const int4* s = (const int4*)(xb + (size_t)(hh * W_ + ww) * 64);
      v0 = s[0]; v1 = s[1]; v2 = s[2]; v3 = s[3]; v4 = s[4]; v5 = s[5]; v6 = s[6]; v7 = s[7];
    }
  } else if (wv == 1) {
    const int4* s = (const int4*)(wB + (size_t)lane * 64);
    v0 = s[0]; v1 = s[1]; v2 = s[2]; v3 = s[3]; v4 = s[4]; v5 = s[5]; v6 = s[6]; v7 = s[7];
  }

  for (int r = 0; r < 9; ++r) {
    __syncthreads();
    if (wv < 2) {
      *(int4*)(drow + 0)  = v0;  *(int4*)(drow + 8)  = v1;
      *(int4*)(drow + 16) = v2;  *(int4*)(drow + 24) = v3;
      *(int4*)(drow + 32) = v4;  *(int4*)(drow + 40) = v5;
      *(int4*)(drow + 48) = v6;  *(int4*)(drow + 56) = v7;
    }
    __syncthreads();
    if (r < 8) {
      int rn = r + 1;
      if (wv == 0) {
        int hh = ph + rn / 3 - 1, ww = pw + rn % 3 - 1;
        if (pok && (unsigned)hh < (unsigned)H_ && (unsigned)ww < (unsigned)W_) {
          const int4* s = (const int4*)(xb + (size_t)(hh * W_ + ww) * 64);
          v0 = s[0]; v1 = s[1]; v2 = s[2]; v3 = s[3]; v4 = s[4]; v5 = s[5]; v6 = s[6]; v7 = s[7];
        } else {
          v0 = z4; v1 = z4; v2 = z4; v3 = z4; v4 = z4; v5 = z4; v6 = z4; v7 = z4;
        }
      } else if (wv == 1) {
        const int4* s = (const int4*)(wB + ((size_t)rn * 64 + lane) * 64);
        v0 = s[0]; v1 = s[1]; v2 = s[2]; v3 = s[3]; v4 = s[4]; v5 = s[5]; v6 = s[6]; v7 = s[7];
      }
    }
#pragma unroll
    for (int t = 0; t < 4; ++t) {
      bfv8 a = *(const bfv8*)(sA + aoff + t * 16);
      bfv8 b = *(const bfv8*)(sB + boff + t * 16);
      acc = __builtin_amdgcn_mfma_f32_32x32x16_bf16(a, b, acc, 0, 0, 0);
    }
  }

  int nw = ((wv & 1) << 5) + fr;
  int mwb = (wv >> 1) << 5;
#pragma unroll
  for (int r = 0; r < 16; ++r) {
    int m = mwb + (r & 3) + ((r >> 2) << 3) + ((lane >> 5) << 2);
    int p2 = px0 + m;
    if (p2 >= HW) continue;
    size_t ob = ((size_t)bz * HW + p2) * 16;
    float val = acc[r];
    if (nw < 16) {
      ushort_t h2, l2; splitbf(val + ws[BG_O + nw], h2, l2);
      b1h[ob + nw] = h2; b1l[ob + nw] = l2;
    } else if (nw < 32) {
      int o = nw - 16; ushort_t h2, l2; splitbf(val + ws[BT_O + o], h2, l2);
      b2h[ob + o] = h2; b2l[ob + o] = l2;
    } else if (nw < 48) {
      int o = nw - 32; b3[ob + o] = val + ws[BP_O + o];
    }
  }
}

// -------- fp32 conv from fp32 xh (flag=1 fallback; gate=1 skips when flag=0) -----
__global__ __launch_bounds__(256) void k_conv2(
    const int* __restrict__ flag, int gate,
    const float* __restrict__ ws, const float* __restrict__ xh,
    ushort_t* __restrict__ b1h, ushort_t* __restrict__ b1l,
    ushort_t* __restrict__ b2h, ushort_t* __restrict__ b2l,
    float* __restrict__ b3)
{
  if (gate && *flag == 0) return;
  int pix = blockIdx.x * 256 + threadIdx.x;
  int o0 = blockIdx.y * 8;
  int b = blockIdx.z;
  if (pix >= HW) return;
  int h = pix / W_, w = pix - h * W_;

  const float* WG = ws + WG_O;
  const float4* xh4 = (const float4*)xh;

  float a1[8], a2[8], a3[8];
#pragma unroll
  for (int o = 0; o < 8; ++o) { a1[o] = 0.f; a2[o] = 0.f; a3[o] = 0.f; }

  size_t cbase = ((size_t)b * HW + pix) * 16;
  for (int c4 = 0; c4 < 16; ++c4) {
    float4 xv = xh4[cbase + c4];
#pragma unroll
    for (int j = 0; j < 4; ++j) {
      float xj = (j == 0) ? xv.x : (j == 1) ? xv.y : (j == 2) ? xv.z : xv.w;
      const float* tp = ws + WT_O + (c4 * 4 + j) * 16 + o0;
      const float* pp = ws + WP_O + (c4 * 4 + j) * 16 + o0;
#pragma unroll
      for (int o = 0; o < 8; ++o) { a2[o] += xj * tp[o]; a3[o] += xj * pp[o]; }
    }
  }
  for (int dh = 0; dh < 3; ++dh) {
    int hh = h + dh - 1;
    if ((unsigned)hh >= (unsigned)H_) continue;
    for (int dw = 0; dw < 3; ++dw) {
      int ww = w + dw - 1;
      if ((unsigned)ww >= (unsigned)W_) continue;
      int tap = dh * 3 + dw;
      size_t pbase = ((size_t)b * HW + hh * W_ + ww) * 16;
      const float* wgt = WG + tap * 1024 + o0;
      for (int c4 = 0; c4 < 16; ++c4) {
        float4 xv = xh4[pbase + c4];
#pragma unroll
        for (int j = 0; j < 4; ++j) {
          float xj = (j == 0) ? xv.x : (j == 1) ? xv.y : (j == 2) ? xv.z : xv.w;
          const float* wp_ = wgt + (c4 * 4 + j) * 16;
#pragma unroll
          for (int o = 0; o < 8; ++o) a1[o] += xj * wp_[o];
        }
      }
    }
  }
  size_t ob = ((size_t)b * HW + pix) * 16 + o0;
#pragma unroll
  for (int o = 0; o < 8; ++o) {
    float v1 = a1[o] + ws[BG_O + o0 + o];
    float v2 = a2[o] + ws[BT_O + o0 + o];
    ushort_t hh2, ll2;
    splitbf(v1, hh2, ll2); b1h[ob + o] = hh2; b1l[ob + o] = ll2;
    splitbf(v2, hh2, ll2); b2h[ob + o] = hh2; b2l[ob + o] = ll2;
    b3[ob + o] = a3[o] + ws[BP_O + o0 + o];
  }
}

// -------- fallback conv (LOW tier), same outputs ---------------------------------
template <typename T>
__device__ __forceinline__ void convF_body(
    const void* x, const void* g_w, const void* g_b,
    const void* t_w, const void* t_b, const void* p_w, const void* p_b,
    ushort_t* b1h, ushort_t* b1l, ushort_t* b2h, ushort_t* b2l, float* b3,
    float* sgw, float* stw, float* spw)
{
  int tid = threadIdx.y * 32 + threadIdx.x;
  for (int i = tid; i < CI * CIN * 9; i += 256) sgw[i] = Ld<T>::f(g_w, i);
  for (int i = tid; i < CI * CIN; i += 256) { stw[i] = Ld<T>::f(t_w, i); spw[i] = Ld<T>::f(p_w, i); }
  __syncthreads();

  int w = blockIdx.x * 32 + threadIdx.x;
  int h = blockIdx.y * 8 + threadIdx.y;
  int b = blockIdx.z;
  if (w >= W_ || h >= H_) return;

  float a1[CI], a2[CI], a3[CI];
#pragma unroll
  for (int o = 0; o < CI; ++o) { a1[o] = 0.f; a2[o] = 0.f; a3[o] = 0.f; }

  const size_t xb = (size_t)b * CIN * HW;
  for (int c = 0; c < CIN; ++c) {
    float xv[9];
#pragma unroll
    for (int dh = 0; dh < 3; ++dh) {
      int hh = h + dh - 1;
      bool rok = ((unsigned)hh < (unsigned)H_);
#pragma unroll
      for (int dw = 0; dw < 3; ++dw) {
        int ww = w + dw - 1;
        bool ok = rok && ((unsigned)ww < (unsigned)W_);
        xv[dh * 3 + dw] = ok ? Ld<T>::f(x, (int)(xb + (size_t)c * HW + hh * W_ + ww)) : 0.f;
      }
    }
    float xc = xv[4];
#pragma unroll
    for (int o = 0; o < CI; ++o) {
      const float* gg = &sgw[(o * CIN + c) * 9];
      float s = gg[0]*xv[0] + gg[1]*xv[1] + gg[2]*xv[2]
              + gg[3]*xv[3] + gg[4]*xv[4] + gg[5]*xv[5]
              + gg[6]*xv[6] + gg[7]*xv[7] + gg[8]*xv[8];
      a1[o] += s;
      a2[o] += stw[o * CIN + c] * xc;
      a3[o] += spw[o * CIN + c] * xc;
    }
  }
  size_t base = ((size_t)b * HW + h * W_ + w) * CI;
#pragma unroll
  for (int o = 0; o < CI; ++o) {
    float v1 = a1[o] + Ld<T>::f(g_b, o);
    float v2 = a2[o] + Ld<T>::f(t_b, o);
    ushort_t hh2, ll2;
    splitbf(v1, hh2, ll2); b1h[base + o] = hh2; b1l[base + o] = ll2;
    splitbf(v2, hh2, ll2); b2h[base + o] = hh2; b2l[base + o] = ll2;
    b3[base + o] = a3[o] + Ld<T>::f(p_b, o);
  }
}

__global__ __launch_bounds__(256) void k_convF(
    const int* __restrict__ flag, const void* x,
    const void* g_w, const void* g_b, const void* t_w, const void* t_b,
    const void* p_w, const void* p_b,
    ushort_t* __restrict__ b1h, ushort_t* __restrict__ b1l,
    ushort_t* __restrict__ b2h, ushort_t* __restrict__ b2l,
    float* __restrict__ b3)
{
  __shared__ float sgw[CI * CIN * 9];
  __shared__ float stw[CI * CIN];
  __shared__ float spw[CI * CIN];
  if (*flag) convF_body<float>(x, g_w, g_b, t_w, t_b, p_w, p_b, b1h, b1l, b2h, b2l, b3, sgw, stw, spw);
  else       convF_body<bf16 >(x, g_w, g_b, t_w, t_b, p_w, p_b, b1h, b1l, b2h, b2l, b3, sgw, stw, spw);
}

// -------- S3[b, pos*16+c] = sum over patches of b3 -------------------------------
__global__ __launch_bounds__(256) void k_colsum(const float* __restrict__ b3, float* __restrict__ S3)
{
  __shared__ float red[16][17];
  int b = blockIdx.x, pos = blockIdx.y;
  int ki = pos / 7, kj = pos % 7;
  int c = threadIdx.x & 15, chunk = threadIdx.x >> 4;
  const float* B3 = b3 + (size_t)b * HW * CI;
  float s = 0.f;
  for (int l = chunk; l < L_; l += 16) {
    int lh = l / OH_, lw = l % OH_;
    s += B3[((lh * ST + ki) * W_ + lw * ST + kj) * CI + c];
  }
  red[chunk][c] = s;
  __syncthreads();
  if (threadIdx.x < 16) {
    float t = 0.f;
#pragma unroll
    for (int k = 0; k < 16; ++k) t += red[k][threadIdx.x];
    S3[(b * 49 + pos) * 16 + threadIdx.x] = t;
  }
}

// -------- score GEMM via split-bf16 MFMA, 14-round K-loop (r9, verified) ---------
__global__ __launch_bounds__(256) void k_score(
    const ushort_t* __restrict__ b1h, const ushort_t* __restrict__ b1l,
    const ushort_t* __restrict__ b2h, const ushort_t* __restrict__ b2l,
    float* __restrict__ scb, int b0, unsigned scstride_z)
{
  __shared__ ushort_t sm[4][64 * SLST];
  int batch = b0 + blockIdx.z;
  size_t poff_g = (size_t)batch * HW * CI;
  float* Sc = scb + (size_t)blockIdx.z * scstride_z;

  int tid = threadIdx.x;
  int m0 = blockIdx.y * 64, n0 = blockIdx.x * 64;
  int lane = tid & 63;
  int wv = tid >> 6;

  int srow = (wv < 2) ? (m0 + lane) : (n0 + lane);
  if (srow > L_ - 1) srow = L_ - 1;
  int slh = srow / OH_, slw = srow - slh * OH_;
  int sbase = (slh * ST) * W_ + slw * ST;
  const ushort_t* splane = (wv == 0) ? (b1h + poff_g) : (wv == 1) ? (b1l + poff_g)
                          : (wv == 2) ? (b2h + poff_g) : (b2l + poff_g);
  ushort_t* drow = sm[wv] + lane * SLST;

  int fr = lane & 31;
  int kh = (lane >> 5) << 3;
  int aoff = (((wv >> 1) << 5) + fr) * SLST + kh;
  int boff = (((wv & 1) << 5) + fr) * SLST + kh;

  f32x16 acc = {0.f,0.f,0.f,0.f,0.f,0.f,0.f,0.f,0.f,0.f,0.f,0.f,0.f,0.f,0.f,0.f};

  int4 v0, v1, v2, v3, v4, v5, v6, v7;
  {
    const int4* src = (const int4*)(splane + (size_t)sbase * 16);
    v0 = src[0]; v1 = src[1]; v2 = src[2]; v3 = src[3];
    v4 = src[4]; v5 = src[5]; v6 = src[6]; v7 = src[7];
  }

  for (int r = 0; r < 14; ++r) {
    int half = r & 1;
    __syncthreads();
    *(int4*)(drow + 0)  = v0;  *(int4*)(drow + 8)  = v1;
    *(int4*)(drow + 16) = v2;  *(int4*)(drow + 24) = v3;
    *(int4*)(drow + 32) = v4;  *(int4*)(drow + 40) = v5;
    if (!half) { *(int4*)(drow + 48) = v6; *(int4*)(drow + 56) = v7; }
    __syncthreads();
    if (r < 13) {
      int rn = r + 1;
      int nki = rn >> 1, nkj0 = (rn & 1) * 4;
      const int4* src = (const int4*)(splane + (size_t)(sbase + nki * W_ + nkj0) * 16);
      v0 = src[0]; v1 = src[1]; v2 = src[2]; v3 = src[3]; v4 = src[4]; v5 = src[5];
      if (!(rn & 1)) { v6 = src[6]; v7 = src[7]; }
    }
    if (!half) {
#pragma unroll
      for (int t = 0; t < 4; ++t) {
        bfv8 ah = *(const bfv8*)(sm[0] + aoff + t * 16);
        bfv8 al = *(const bfv8*)(sm[1] + aoff + t * 16);
        bfv8 bh = *(const bfv8*)(sm[2] + boff + t * 16);
        bfv8 bl = *(const bfv8*)(sm[3] + boff + t * 16);
        acc = __builtin_amdgcn_mfma_f32_32x32x16_bf16(al, bh, acc, 0, 0, 0);
        acc = __builtin_amdgcn_mfma_f32_32x32x16_bf16(ah, bl, acc, 0, 0, 0);
        acc = __builtin_amdgcn_mfma_f32_32x32x16_bf16(ah, bh, acc, 0, 0, 0);
      }
    } else {
#pragma unroll
      for (int t = 0; t < 3; ++t) {
        bfv8 ah = *(const bfv8*)(sm[0] + aoff + t * 16);
        bfv8 al = *(const bfv8*)(sm[1] + aoff + t * 16);
        bfv8 bh = *(const bfv8*)(sm[2] + boff + t * 16);
        bfv8 bl = *(const bfv8*)(sm[3] + boff + t * 16);
        acc = __builtin_amdgcn_mfma_f32_32x32x16_bf16(al, bh, acc, 0, 0, 0);
        acc = __builtin_amdgcn_mfma_f32_32x32x16_bf16(ah, bl, acc, 0, 0, 0);
        acc = __builtin_amdgcn_mfma_f32_32x32x16_bf16(ah, bh, acc, 0, 0, 0);
      }
    }
  }

  int mw = m0 + ((wv >> 1) << 5);
  int nw = n0 + ((wv & 1) << 5) + (lane & 31);
  if (nw < L_) {
#pragma unroll
    for (int r = 0; r < 16; ++r) {
      int m = mw + (r & 3) + ((r >> 2) << 3) + ((lane >> 5) << 2);
      if (m < L_) Sc[(size_t)m * SROW + nw] = acc[r];
    }
  }
}

// -------- top-100 + softmax weights: 1 wave per row, register-resident -----------
__global__ __launch_bounds__(64) void k_topk(
    const float* __restrict__ scb, float* __restrict__ tkw, int* __restrict__ tkp,
    unsigned scstride_z)
{
  __shared__ float swv[TOPM];
  __shared__ int spx[TOPM];
  int lane = threadIdx.x;
  int l = blockIdx.x, bz = blockIdx.y;
  const float4* row4 = (const float4*)(scb + (size_t)bz * scstride_z + (size_t)l * SROW);
  int trow = (bz * L_ + l) * TKROW;

  unsigned k[16];
#pragma unroll
  for (int q = 0; q < 4; ++q) {
    float4 v = row4[q * 64 + lane];
    int ib = (q * 64 + lane) * 4;
    k[q * 4 + 0] = (ib + 0 < L_) ? fmap(v.x) : 0u;
    k[q * 4 + 1] = (ib + 1 < L_) ? fmap(v.y) : 0u;
    k[q * 4 + 2] = (ib + 2 < L_) ? fmap(v.z) : 0u;
    k[q * 4 + 3] = (ib + 3 < L_) ? fmap(v.w) : 0u;
  }

  unsigned mk = 0;
#pragma unroll
  for (int r = 0; r < 16; ++r) mk = max(mk, k[r]);
#pragma unroll
  for (int o = 32; o; o >>= 1) mk = max(mk, (unsigned)__shfl_down((int)mk, o));
  mk = (unsigned)__shfl((int)mk, 0);
  float vmax = unfmap(mk);

  unsigned alive = 0xFFFFu;
  unsigned prefix = 0; int base = 0;
  for (int bit = 30; bit >= 0; bit -= 2) {
    int c1 = 0, c2 = 0, c3 = 0;
#pragma unroll
    for (int r = 0; r < 16; ++r) {
      if ((alive >> r) & 1) {
        unsigned f = (k[r] >> bit) & 3u;
        c3 += (f == 3); c2 += (f >= 2); c1 += (f >= 1);
      }
    }
    int p = c3 | (c2 << 10) | (c1 << 20);
#pragma unroll
    for (int o = 32; o; o >>= 1) p += __shfl_down(p, o);
    p = __shfl(p, 0);
    int n3 = p & 1023, n2 = (p >> 10) & 1023, n1 = (p >> 20) & 1023;
    unsigned ch;
    if (base + n3 >= TOPM) ch = 3;
    else if (base + n2 >= TOPM) { ch = 2; base += n3; }
    else if (base + n1 >= TOPM) { ch = 1; base += n2; }
    else { ch = 0; base += n1; }
    prefix |= ch << bit;
#pragma unroll
    for (int r = 0; r < 16; ++r) {
      if ((alive >> r) & 1) {
        unsigned f = (k[r] >> bit) & 3u;
        if (f != ch) alive &= ~(1u << r);
      }
    }
  }
  int nA = base;
  int needT = TOPM - nA;

  int cA = 0, cT = 0;
#pragma unroll
  for (int r = 0; r < 16; ++r) { cA += (k[r] > prefix); cT += (k[r] == prefix); }
  int pk = cA | (cT << 16);
  int incl = pk;
#pragma unroll
  for (int o = 1; o < 64; o <<= 1) { int t = __shfl_up(incl, o); if (lane >= o) incl += t; }
  int excl = incl - pk;
  int tA = excl & 0xFFFF, tT = excl >> 16;

  float M = fmaxf(10.f * vmax, 0.f);
  float e0 = expf(-M);
  float z = 0.f;
#pragma unroll
  for (int r = 0; r < 16; ++r) {
    unsigned kk = k[r];
    int slot = -1;
    if (kk > prefix) slot = tA++;
    else if (kk == prefix) { if (tT < needT) slot = nA + tT; tT++; }
    if (slot >= 0) {
      float v = unfmap(kk);
      float wv = expf(10.f * v - M);
      swv[slot] = wv; z += wv;
      int gi = 256 * (r >> 2) + 4 * lane + (r & 3);
      int lh = gi / OH_, lw = gi - lh * OH_;
      spx[slot] = ((lh * ST) * W_ + lw * ST) * CI;
    }
  }
#pragma unroll
  for (int o = 32; o; o >>= 1) z += __shfl_down(z, o);
  z = __shfl(z, 0);
  float Z = z + (float)(L_ - TOPM) * e0;
  float invZ = 1.f / Z;
  float w0 = e0 / Z;
  __syncthreads();
#pragma unroll
  for (int s0 = 0; s0 < 2; ++s0) {
    int s = lane + 64 * s0;
    if (s < TOPM) {
      tkw[trow + s] = swv[s] * invZ - w0;
      tkp[trow + s] = spx[s];
    }
  }
  if (lane == 0) tkw[trow + TOPM] = w0;
}

// -------- PV gather: agg[l,:] = sum_j wj*B3[pix_j,:] + w0*S3 ---------------------
__global__ __launch_bounds__(256) void k_pv(
    const float* __restrict__ tkw, const int* __restrict__ tkp,
    const float* __restrict__ b3, const float* __restrict__ s3,
    float* __restrict__ agb, int b0, unsigned agstride_z)
{
  int l = blockIdx.x, bz = blockIdx.y;
  int batch = b0 + bz;
  int trow = (bz * L_ + l) * TKROW;
  const float* B3 = b3 + (size_t)batch * HW * CI;
  const float* S3 = s3 + (size_t)batch * D_;
  float* agg = agb + (size_t)bz * agstride_z;
  int tid = threadIdx.x;
  if (tid >= 196) return;

  float w0 = tkw[trow + TOPM];
  int pos = tid >> 2;
  int c0 = (tid << 2) & 15;
  int ki = pos / 7, kj = pos - (pos / 7) * 7;
  int poff = (ki * W_ + kj) * CI + c0;

  float ax = 0.f, ay = 0.f, az = 0.f, aw = 0.f;
  for (int j0 = 0; j0 < TOPM; j0 += 4) {
    float w_0 = tkw[trow + j0 + 0];
    float w_1 = tkw[trow + j0 + 1];
    float w_2 = tkw[trow + j0 + 2];
    float w_3 = tkw[trow + j0 + 3];
    int p_0 = tkp[trow + j0 + 0];
    int p_1 = tkp[trow + j0 + 1];
    int p_2 = tkp[trow + j0 + 2];
    int p_3 = tkp[trow + j0 + 3];
    const float4 q0 = *(const float4*)(B3 + p_0 + poff);
    const float4 q1 = *(const float4*)(B3 + p_1 + poff);
    const float4 q2 = *(const float4*)(B3 + p_2 + poff);
    const float4 q3 = *(const float4*)(B3 + p_3 + poff);
    ax += w_0 * q0.x; ay += w_0 * q0.y; az += w_0 * q0.z; aw += w_0 * q0.w;
    ax += w_1 * q1.x; ay += w_1 * q1.y; az += w_1 * q1.z; aw += w_1 * q1.w;
    ax += w_2 * q2.x; ay += w_2 * q2.y; az += w_2 * q2.z; aw += w_2 * q2.w;
    ax += w_3 * q3.x; ay += w_3 * q3.y; az += w_3 * q3.z; aw += w_3 * q3.w;
  }
  const float4 s4 = *(const float4*)(S3 + tid * 4);
  ax += w0 * s4.x; ay += w0 * s4.y; az += w0 * s4.z; aw += w0 * s4.w;
  *(float4*)(agg + (size_t)l * D_ + tid * 4) = make_float4(ax, ay, az, aw);
}

// -------- fold + mask divide + restore (16->64), batched -------------------------
__global__ __launch_bounds__(256) void k_fold(
    const int* __restrict__ flag, const float* __restrict__ ws,
    const float* __restrict__ agb, void* __restrict__ out,
    int b0, unsigned agstride_z)
{
  __shared__ float srw[CIN * CI];
  int tid = threadIdx.x;
  for (int i = tid; i < CIN * CI; i += 256) srw[i] = ws[RW_O + i];
  __syncthreads();

  int bz = blockIdx.y;
  int batch = b0 + bz;
  const float* agg = agb + (size_t)bz * agstride_z;

  int gid = blockIdx.x * 256 + tid;
  if (gid >= HW) return;
  int h = gid / W_;
  int w = gid % W_;

  int lh0 = (h >= KS - 1) ? ((h - (KS - 1) + (ST - 1)) >> 2) : 0;
  int lh1 = min(OH_ - 1, h >> 2);
  int lw0 = (w >= KS - 1) ? ((w - (KS - 1) + (ST - 1)) >> 2) : 0;
  int lw1 = min(OH_ - 1, w >> 2);

  float t[CI];
#pragma unroll
  for (int c = 0; c < CI; ++c) t[c] = 0.f;
  for (int lh = lh0; lh <= lh1; ++lh) {
    int ki = h - ST * lh;
    for (int lw = lw0; lw <= lw1; ++lw) {
      int kj = w - ST * lw;
      const float* pb = agg + (size_t)(lh * OH_ + lw) * D_ + (ki * KS + kj) * CI;
      float4 q0 = *(const float4*)(pb);
      float4 q1 = *(const float4*)(pb + 4);
      float4 q2 = *(const float4*)(pb + 8);
      float4 q3 = *(const float4*)(pb + 12);
      t[0] += q0.x; t[1] += q0.y; t[2] += q0.z; t[3] += q0.w;
      t[4] += q1.x; t[5] += q1.y; t[6] += q1.z; t[7] += q1.w;
      t[8] += q2.x; t[9] += q2.y; t[10] += q2.z; t[11] += q2.w;
      t[12] += q3.x; t[13] += q3.y; t[14] += q3.z; t[15] += q3.w;
    }
  }
  float cnt = (float)((lh1 - lh0 + 1) * (lw1 - lw0 + 1));
  float r[CI];
#pragma unroll
  for (int c = 0; c < CI; ++c) r[c] = t[c] / (cnt * ws[SM_O + c] + ws[SB_O + c] + 1e-8f);

  size_t ob = (size_t)batch * CIN * HW + (size_t)h * W_ + w;
  if (*flag) {
    float* of = (float*)out;
#pragma unroll
    for (int o = 0; o < CIN; ++o) {
      float s = ws[RB_O + o];
#pragma unroll
      for (int c = 0; c < CI; ++c) s += srw[o * CI + c] * r[c];
      of[ob + (size_t)o * HW] = s;
    }
  } else {
    bf16* of = (bf16*)out;
#pragma unroll
    for (int o = 0; o < CIN; ++o) {
      float s = ws[RB_O + o];
#pragma unroll
      for (int c = 0; c < CI; ++c) s += srw[o * CI + c] * r[c];
      of[ob + (size_t)o * HW] = __float2bfloat16(s);
    }
  }
}

extern "C" void kernel_launch(void* const* d_in, const int* in_sizes, int n_in,
                              void* d_out, int out_size, void* d_ws, size_t ws_size,
                              hipStream_t stream)
{
  const void* x    = d_in[0];
  const void* g_w  = d_in[1];
  const void* g_b  = d_in[2];
  const void* th_w = d_in[3];
  const void* th_b = d_in[4];
  const void* ph_w = d_in[5];
  const void* ph_b = d_in[6];
  const void* m_w  = d_in[7];
  const void* m_b  = d_in[8];
  const void* r_w  = d_in[9];
  const void* r_b  = d_in[10];

  float* W = (float*)d_ws;
  int* flag = (int*)d_ws;
  ushort_t* planes = (ushort_t*)(W + B1_O);
  ushort_t* b1h = planes;
  ushort_t* b1l = planes + (size_t)N1;
  ushort_t* b2h = planes + (size_t)2 * N1;
  ushort_t* b2l = planes + (size_t)3 * N1;
  float* b3 = W + B1_O + 2 * N1;
  float* s3 = W + S3_O;

  k_detect<<<1, 64, 0, stream>>>((const unsigned short*)x, flag);
  k_prep<<<1, 256, 0, stream>>>(flag, g_w, th_w, ph_w, g_b, th_b, ph_b,
                                m_w, m_b, r_w, r_b, W);

  if (ws_size >= FULL_BYTES) {
    float* xh = W + REG_O;                     // fp32 HWC (flag=1 only), dead after conv
    float* sc = W + REG_O;                     // 4 x SCSLOT, aliases xh
    float* ag = W + REG_O + XHSZ;              // 4 x AGSZ
    ushort_t* xhb = (ushort_t*)(W + REG_O + XHSZ);  // bf16 HWC (flag=0), dead before k_pv
    float* tkw = W + B1_O + N1;                // b2h region (dead after k_score)
    int*   tkp = (int*)(W + B1_O + N1 + N1 / 2);
    k_hwc<<<dim3((B_ * HW + 63) / 64), 256, 0, stream>>>(flag, x, xh, xhb, 1);
    k_conv3<<<dim3((HW + 63) / 64, 1, B_), 256, 0, stream>>>(
        flag, W, xhb, b1h, b1l, b2h, b2l, b3);
    k_conv2<<<dim3(64, 2, B_), 256, 0, stream>>>(flag, 1, W, xh, b1h, b1l, b2h, b2l, b3);
    k_colsum<<<dim3(B_, 49), 256, 0, stream>>>(b3, s3);
    k_score<<<dim3(16, 16, B_), 256, 0, stream>>>(b1h, b1l, b2h, b2l, sc, 0, SCSLOT);
    k_topk<<<dim3(L_, B_), 64, 0, stream>>>(sc, tkw, tkp, SCSLOT);
    k_pv<<<dim3(L_, B_), 256, 0, stream>>>(tkw, tkp, b3, s3, ag, 0, AGSZ);
    k_fold<<<dim3(64, B_), 256, 0, stream>>>(flag, W, ag, d_out, 0, AGSZ);
  } else if (ws_size >= MID_BYTES) {
    float* xh = W + REG_O;
    float* sc = W + REG_O;
    float* ag = W + REG_O + SCSLOT;
    k_hwc<<<dim3((B_ * HW + 63) / 64), 256, 0, stream>>>(flag, x, xh, (ushort_t*)xh, 0);
    k_conv2<<<dim3(64, 2, B_), 256, 0, stream>>>(flag, 0, W, xh, b1h, b1l, b2h, b2l, b3);
    k_colsum<<<dim3(B_, 49), 256, 0, stream>>>(b3, s3);
    for (int b = 0; b < B_; ++b) {
      float* tkw = W + B1_O + N1 + (size_t)b * (HW * CI / 2);
      int*   tkp = (int*)(W + B1_O + N1 + N1 / 2 + (size_t)b * (HW * CI / 2));
      k_score<<<dim3(16, 16, 1), 256, 0, stream>>>(b1h, b1l, b2h, b2l, sc, b, 0);
      k_topk<<<dim3(L_, 1), 64, 0, stream>>>(sc, tkw, tkp, 0);
      k_pv<<<dim3(L_, 1), 256, 0, stream>>>(tkw, tkp, b3, s3, ag, b, 0);
      k_fold<<<dim3(64, 1), 256, 0, stream>>>(flag, W, ag, d_out, b, 0);
    }
  } else {
    float* sc = W + REG_O;
    float* ag = W + REG_O + SCSLOT;
    k_convF<<<dim3(4, 16, B_), dim3(32, 8, 1), 0, stream>>>(
        flag, x, g_w, g_b, th_w, th_b, ph_w, ph_b, b1h, b1l, b2h, b2l, b3);
    k_colsum<<<dim3(B_, 49), 256, 0, stream>>>(b3, s3);
    for (int b = 0; b < B_; ++b) {
      float* tkw = W + B1_O + N1 + (size_t)b * (HW * CI / 2);
      int*   tkp = (int*)(W + B1_O + N1 + N1 / 2 + (size_t)b * (HW * CI / 2));
      k_score<<<dim3(16, 16, 1), 256, 0, stream>>>(b1h, b1l, b2h, b2l, sc, b, 0);
      k_topk<<<dim3(L_, 1), 64, 0, stream>>>(sc, tkw, tkp, 0);
      k_pv<<<dim3(L_, 1), 256, 0, stream>>>(tkw, tkp, b3, s3, ag, b, 0);
      k_fold<<<dim3(64, 1), 256, 0, stream>>>(flag, W, ag, d_out, b, 0);
    }
  }
}

// Round 11
// 359.893 us; speedup vs baseline: 1.0259x; 1.0259x over previous
//
#include <hip/hip_runtime.h>
#include <hip/hip_bf16.h>

typedef __hip_bfloat16 bf16;
typedef unsigned short ushort_t;
typedef __attribute__((ext_vector_type(8))) __bf16 bfv8;
typedef __attribute__((ext_vector_type(16))) float f32x16;

#define B_   4
#define CIN  64
#define CI   16
#define H_   127
#define W_   127
#define HW   (H_*W_)
#define KS   7
#define ST   4
#define OH_  31
#define L_   961
#define D_   784
#define TOPM 100

// ---- workspace layout (float offsets) ----
#define N1   1032256          // B*HW*CI elements (one conv-out array)
#define WG_O 4
#define WT_O (WG_O + 9216)
#define WP_O (WT_O + 1024)
#define BG_O (WP_O + 1024)
#define BT_O (BG_O + 16)
#define BP_O (BT_O + 16)
#define SM_O (BP_O + 16)
#define SB_O (SM_O + 16)
#define RW_O (SB_O + 16)
#define RB_O (RW_O + 1024)
#define B1_O 12448
// planes region at B1_O: b1h,b1l,b2h,b2l each N1 ushorts (total 2*N1 floats)
#define S3_O (B1_O + 3*N1)
#define WB_O (S3_O + B_*D_)   // conv MFMA B: wBh + wBl, each 9*64*64 ushorts = 36864 floats total
#define REG_O (WB_O + 36864)
#define XHSZ 4129024          // B*HW*64 (ushorts per x plane; 2 planes = XHSZ floats)
#define SROW 964              // padded Sc row stride
#define SCSLOT 926464
#define AGSZ 753424
#define TKROW 112
#define SLST 72               // LDS row stride in ushorts (conflict-free, measured r8)

#define FULL_BYTES ((size_t)(REG_O + XHSZ + 4*AGSZ) * 4)   // ~41.1 MB
#define MID_BYTES  ((size_t)(REG_O + XHSZ) * 4)            // ~29.1 MB

__device__ __forceinline__ float bf2f(bf16 v) { return __bfloat162float(v); }

template <typename T> struct Ld;
template <> struct Ld<float> {
  static __device__ __forceinline__ float f(const void* p, int i) { return ((const float*)p)[i]; }
};
template <> struct Ld<bf16> {
  static __device__ __forceinline__ float f(const void* p, int i) { return bf2f(((const bf16*)p)[i]); }
};

__device__ __forceinline__ unsigned fmap(float f) {
  unsigned u = __float_as_uint(f);
  return (u & 0x80000000u) ? ~u : (u | 0x80000000u);
}
__device__ __forceinline__ float unfmap(unsigned kk) {
  unsigned u = (kk & 0x80000000u) ? (kk & 0x7fffffffu) : ~kk;
  return __uint_as_float(u);
}

// RNE fp32 -> bf16 bits, and hi/lo split
__device__ __forceinline__ ushort_t f2bf(float x) {
  unsigned u = __float_as_uint(x);
  return (ushort_t)((u + 0x7FFFu + ((u >> 16) & 1u)) >> 16);
}
__device__ __forceinline__ void splitbf(float x, ushort_t& h, ushort_t& l) {
  h = f2bf(x);
  float hf = __uint_as_float(((unsigned)h) << 16);
  l = f2bf(x - hf);
}

// -------- dtype detector: flag=1 -> fp32 buffers, flag=0 -> bf16 -----------------
__global__ void k_detect(const unsigned short* __restrict__ xh, int* __restrict__ flag) {
  int tid = threadIdx.x;  // 64
  int c = 0;
#pragma unroll
  for (int j = 0; j < 2; ++j) {
    unsigned u = xh[tid * 2 + j];
    unsigned e = (u >> 7) & 0xFF;
    if (e >= 134) c++;
  }
#pragma unroll
  for (int o = 32; o; o >>= 1) c += __shfl_down(c, o);
  if (tid == 0) *flag = (c >= 8) ? 1 : 0;
}

// -------- weight prep ------------------------------------------------------------
#define LDW(ptr, i) (f ? ((const float*)(ptr))[i] : bf2f(((const bf16*)(ptr))[i]))
__global__ __launch_bounds__(256) void k_prep(
    const int* __restrict__ flag,
    const void* g_w, const void* t_w, const void* p_w,
    const void* g_b, const void* t_b, const void* p_b,
    const void* m_w, const void* m_b, const void* r_w, const void* r_b,
    float* __restrict__ ws)
{
  int tid = threadIdx.x;
  int f = *flag;
  for (int i = tid; i < 9216; i += 256) {
    int o = i & 15, t = i >> 4, c = t & 63, tap = t >> 6;
    ws[WG_O + i] = LDW(g_w, (o * 64 + c) * 9 + tap);
  }
  for (int i = tid; i < 1024; i += 256) {
    int o = i & 15, c = i >> 4;
    ws[WT_O + i] = LDW(t_w, o * 64 + c);
    ws[WP_O + i] = LDW(p_w, o * 64 + c);
  }
  if (tid < 16) {
    ws[BG_O + tid] = LDW(g_b, tid);
    ws[BT_O + tid] = LDW(t_b, tid);
    ws[BP_O + tid] = LDW(p_b, tid);
    float s = 0.f;
    for (int c = 0; c < 64; ++c) s += LDW(m_w, tid * 64 + c);
    ws[SM_O + tid] = s;
    ws[SB_O + tid] = LDW(m_b, tid);
  }
  for (int i = tid; i < 1024; i += 256) ws[RW_O + i] = LDW(r_w, i);
  if (tid < 64) ws[RB_O + tid] = LDW(r_b, tid);
  // conv MFMA B, split hi/lo: wB[tap][col64][c64]. col 0-15 g, 16-31 theta(tap4),
  // 32-47 phi(tap4), 48-63 zero pad.
  ushort_t* wBh = (ushort_t*)(ws + WB_O);
  ushort_t* wBl = wBh + 9 * 64 * 64;
  for (int i = tid; i < 9 * 64 * 64; i += 256) {
    int c = i & 63, t = i >> 6, col = t & 63, tap = t >> 6;
    float v = 0.f;
    if (col < 16) v = LDW(g_w, (col * 64 + c) * 9 + tap);
    else if (col < 32) { if (tap == 4) v = LDW(t_w, (col - 16) * 64 + c); }
    else if (col < 48) { if (tap == 4) v = LDW(p_w, (col - 32) * 64 + c); }
    ushort_t h, l; splitbf(v, h, l);
    wBh[i] = h; wBl[i] = l;
  }
}

// -------- x [B,64,H,W] -> HWC bf16 hi/lo planes ----------------------------------
__global__ __launch_bounds__(256) void k_hwc(
    const int* __restrict__ flag, const void* __restrict__ x,
    ushort_t* __restrict__ xhh, ushort_t* __restrict__ xhl)
{
  __shared__ float tile[64][65];
  int pix0 = blockIdx.x * 64;
  int tid = threadIdx.x;
  int g = tid >> 6, p = tid & 63;
  int pix = pix0 + p;
  bool ok = pix < B_ * HW;
  int bb = ok ? pix / HW : 0;
  int r  = ok ? pix - bb * HW : 0;
  if (*flag) {
    const float* xf = (const float*)x;
    for (int c = g * 16; c < g * 16 + 16; ++c)
      tile[p][c] = ok ? xf[((size_t)bb * CIN + c) * HW + r] : 0.f;
  } else {
    const bf16* xb = (const bf16*)x;
    for (int c = g * 16; c < g * 16 + 16; ++c)
      tile[p][c] = ok ? bf2f(xb[((size_t)bb * CIN + c) * HW + r]) : 0.f;
  }
  __syncthreads();
  int c2 = tid & 63, pg = tid >> 6;
  for (int k = 0; k < 16; ++k) {
    int p2 = pg * 16 + k;
    int pix2 = pix0 + p2;
    if (pix2 < B_ * HW) {
      ushort_t h, l; splitbf(tile[p2][c2], h, l);
      xhh[(size_t)pix2 * 64 + c2] = h;
      xhl[(size_t)pix2 * 64 + c2] = l;
    }
  }
}

// -------- unified split-bf16 MFMA conv: all three convs as 64px x 64col GEMM -----
// C = Xh.Wh^T + Xh.Wl^T + Xl.Wh^T, K=576 (tap*64+c). Structural copy of the
// r9-VERIFIED k_score: 4 staging waves <-> 4 planes (Ah,Al,Bh,Bl), named-reg
// prefetch, SLST=72, identical frag + C/D mappings. 9 rounds x 4 ksteps x 3 mfma.
__global__ __launch_bounds__(256) void k_conv3(
    const float* __restrict__ ws,
    const ushort_t* __restrict__ xhh, const ushort_t* __restrict__ xhl,
    ushort_t* __restrict__ b1h, ushort_t* __restrict__ b1l,
    ushort_t* __restrict__ b2h, ushort_t* __restrict__ b2l,
    float* __restrict__ b3)
{
  __shared__ ushort_t sm[4][64 * SLST];
  int bz = blockIdx.z;
  int px0 = blockIdx.x * 64;
  int tid = threadIdx.x, lane = tid & 63, wv = tid >> 6;

  int pix = px0 + lane;
  bool pok = pix < HW;
  int ph = pok ? pix / W_ : 0;
  int pw = pok ? pix - ph * W_ : 0;
  const ushort_t* xplane = ((wv == 0) ? xhh : xhl) + (size_t)bz * HW * 64;
  const ushort_t* wBh = (const ushort_t*)(ws + WB_O);
  const ushort_t* bsrc = (wv == 2) ? wBh : (wBh + 9 * 64 * 64);
  ushort_t* drow = sm[wv] + lane * SLST;

  int fr = lane & 31, kh = (lane >> 5) << 3;
  int aoff = (((wv >> 1) << 5) + fr) * SLST + kh;
  int boff = (((wv & 1) << 5) + fr) * SLST + kh;

  f32x16 acc = {0.f,0.f,0.f,0.f,0.f,0.f,0.f,0.f,0.f,0.f,0.f,0.f,0.f,0.f,0.f,0.f};
  const int4 z4 = make_int4(0, 0, 0, 0);
  int4 v0 = z4, v1 = z4, v2 = z4, v3 = z4, v4 = z4, v5 = z4, v6 = z4, v7 = z4;

  // prefetch round 0 (tap 0: dh=-1, dw=-1)
  if (wv < 2) {
    int hh = ph - 1, ww = pw - 1;
    if (pok && hh >= 0 && ww >= 0) {
      const int4* s = (const int4*)(xplane + (size_t)(hh * W_ + ww) * 64);
      v0 = s[0]; v1 = s[1]; v2 = s[2]; v3 = s[3]; v4 = s[4]; v5 = s[5]; v6 = s[6]; v7 = s[7];
    }
  } else {
    const int4* s = (const int4*)(bsrc + (size_t)lane * 64);
    v0 = s[0]; v1 = s[1]; v2 = s[2]; v3 = s[3]; v4 = s[4]; v5 = s[5]; v6 = s[6]; v7 = s[7];
  }

  for (int r = 0; r < 9; ++r) {
    __syncthreads();
    *(int4*)(drow + 0)  = v0;  *(int4*)(drow + 8)  = v1;
    *(int4*)(drow + 16) = v2;  *(int4*)(drow + 24) = v3;
    *(int4*)(drow + 32) = v4;  *(int4*)(drow + 40) = v5;
    *(int4*)(drow + 48) = v6;  *(int4*)(drow + 56) = v7;
    __syncthreads();
    if (r < 8) {
      int rn = r + 1;
      if (wv < 2) {
        int hh = ph + rn / 3 - 1, ww = pw + rn % 3 - 1;
        if (pok && (unsigned)hh < (unsigned)H_ && (unsigned)ww < (unsigned)W_) {
          const int4* s = (const int4*)(xplane + (size_t)(hh * W_ + ww) * 64);
          v0 = s[0]; v1 = s[1]; v2 = s[2]; v3 = s[3]; v4 = s[4]; v5 = s[5]; v6 = s[6]; v7 = s[7];
        } else {
          v0 = z4; v1 = z4; v2 = z4; v3 = z4; v4 = z4; v5 = z4; v6 = z4; v7 = z4;
        }
      } else {
        const int4* s = (const int4*)(bsrc + ((size_t)rn * 64 + lane) * 64);
        v0 = s[0]; v1 = s[1]; v2 = s[2]; v3 = s[3]; v4 = s[4]; v5 = s[5]; v6 = s[6]; v7 = s[7];
      }
    }
#pragma unroll
    for (int t = 0; t < 4; ++t) {
      bfv8 ah = *(const bfv8*)(sm[0] + aoff + t * 16);
      bfv8 al = *(const bfv8*)(sm[1] + aoff + t * 16);
      bfv8 bh = *(const bfv8*)(sm[2] + boff + t * 16);
      bfv8 bl = *(const bfv8*)(sm[3] + boff + t * 16);
      acc = __builtin_amdgcn_mfma_f32_32x32x16_bf16(al, bh, acc, 0, 0, 0);
      acc = __builtin_amdgcn_mfma_f32_32x32x16_bf16(ah, bl, acc, 0, 0, 0);
      acc = __builtin_amdgcn_mfma_f32_32x32x16_bf16(ah, bh, acc, 0, 0, 0);
    }
  }

  int nw = ((wv & 1) << 5) + fr;
  int mwb = (wv >> 1) << 5;
#pragma unroll
  for (int r = 0; r < 16; ++r) {
    int m = mwb + (r & 3) + ((r >> 2) << 3) + ((lane >> 5) << 2);
    int p2 = px0 + m;
    if (p2 >= HW) continue;
    size_t ob = ((size_t)bz * HW + p2) * 16;
    float val = acc[r];
    if (nw < 16) {
      ushort_t h2, l2; splitbf(val + ws[BG_O + nw], h2, l2);
      b1h[ob + nw] = h2; b1l[ob + nw] = l2;
    } else if (nw < 32) {
      int o = nw - 16; ushort_t h2, l2; splitbf(val + ws[BT_O + o], h2, l2);
      b2h[ob + o] = h2; b2l[ob + o] = l2;
    } else if (nw < 48) {
      int o = nw - 32; b3[ob + o] = val + ws[BP_O + o];
    }
  }
}

// -------- fallback conv (LOW tier), dtype-templated VALU -------------------------
template <typename T>
__device__ __forceinline__ void convF_body(
    const void* x, const void* g_w, const void* g_b,
    const void* t_w, const void* t_b, const void* p_w, const void* p_b,
    ushort_t* b1h, ushort_t* b1l, ushort_t* b2h, ushort_t* b2l, float* b3,
    float* sgw, float* stw, float* spw)
{
  int tid = threadIdx.y * 32 + threadIdx.x;
  for (int i = tid; i < CI * CIN * 9; i += 256) sgw[i] = Ld<T>::f(g_w, i);
  for (int i = tid; i < CI * CIN; i += 256) { stw[i] = Ld<T>::f(t_w, i); spw[i] = Ld<T>::f(p_w, i); }
  __syncthreads();

  int w = blockIdx.x * 32 + threadIdx.x;
  int h = blockIdx.y * 8 + threadIdx.y;
  int b = blockIdx.z;
  if (w >= W_ || h >= H_) return;

  float a1[CI], a2[CI], a3[CI];
#pragma unroll
  for (int o = 0; o < CI; ++o) { a1[o] = 0.f; a2[o] = 0.f; a3[o] = 0.f; }

  const size_t xb = (size_t)b * CIN * HW;
  for (int c = 0; c < CIN; ++c) {
    float xv[9];
#pragma unroll
    for (int dh = 0; dh < 3; ++dh) {
      int hh = h + dh - 1;
      bool rok = ((unsigned)hh < (unsigned)H_);
#pragma unroll
      for (int dw = 0; dw < 3; ++dw) {
        int ww = w + dw - 1;
        bool ok = rok && ((unsigned)ww < (unsigned)W_);
        xv[dh * 3 + dw] = ok ? Ld<T>::f(x, (int)(xb + (size_t)c * HW + hh * W_ + ww)) : 0.f;
      }
    }
    float xc = xv[4];
#pragma unroll
    for (int o = 0; o < CI; ++o) {
      const float* gg = &sgw[(o * CIN + c) * 9];
      float s = gg[0]*xv[0] + gg[1]*xv[1] + gg[2]*xv[2]
              + gg[3]*xv[3] + gg[4]*xv[4] + gg[5]*xv[5]
              + gg[6]*xv[6] + gg[7]*xv[7] + gg[8]*xv[8];
      a1[o] += s;
      a2[o] += stw[o * CIN + c] * xc;
      a3[o] += spw[o * CIN + c] * xc;
    }
  }
  size_t base = ((size_t)b * HW + h * W_ + w) * CI;
#pragma unroll
  for (int o = 0; o < CI; ++o) {
    float v1 = a1[o] + Ld<T>::f(g_b, o);
    float v2 = a2[o] + Ld<T>::f(t_b, o);
    ushort_t hh2, ll2;
    splitbf(v1, hh2, ll2); b1h[base + o] = hh2; b1l[base + o] = ll2;
    splitbf(v2, hh2, ll2); b2h[base + o] = hh2; b2l[base + o] = ll2;
    b3[base + o] = a3[o] + Ld<T>::f(p_b, o);
  }
}

__global__ __launch_bounds__(256) void k_convF(
    const int* __restrict__ flag, const void* x,
    const void* g_w, const void* g_b, const void* t_w, const void* t_b,
    const void* p_w, const void* p_b,
    ushort_t* __restrict__ b1h, ushort_t* __restrict__ b1l,
    ushort_t* __restrict__ b2h, ushort_t* __restrict__ b2l,
    float* __restrict__ b3)
{
  __shared__ float sgw[CI * CIN * 9];
  __shared__ float stw[CI * CIN];
  __shared__ float spw[CI * CIN];
  if (*flag) convF_body<float>(x, g_w, g_b, t_w, t_b, p_w, p_b, b1h, b1l, b2h, b2l, b3, sgw, stw, spw);
  else       convF_body<bf16 >(x, g_w, g_b, t_w, t_b, p_w, p_b, b1h, b1l, b2h, b2l, b3, sgw, stw, spw);
}

// -------- S3[b, pos*16+c] = sum over patches of b3 -------------------------------
__global__ __launch_bounds__(256) void k_colsum(const float* __restrict__ b3, float* __restrict__ S3)
{
  __shared__ float red[16][17];
  int b = blockIdx.x, pos = blockIdx.y;
  int ki = pos / 7, kj = pos % 7;
  int c = threadIdx.x & 15, chunk = threadIdx.x >> 4;
  const float* B3 = b3 + (size_t)b * HW * CI;
  float s = 0.f;
  for (int l = chunk; l < L_; l += 16) {
    int lh = l / OH_, lw = l % OH_;
    s += B3[((lh * ST + ki) * W_ + lw * ST + kj) * CI + c];
  }
  red[chunk][c] = s;
  __syncthreads();
  if (threadIdx.x < 16) {
    float t = 0.f;
#pragma unroll
    for (int k = 0; k < 16; ++k) t += red[k][threadIdx.x];
    S3[(b * 49 + pos) * 16 + threadIdx.x] = t;
  }
}

// -------- score GEMM via split-bf16 MFMA, 14-round K-loop (r9, verified) ---------
__global__ __launch_bounds__(256) void k_score(
    const ushort_t* __restrict__ b1h, const ushort_t* __restrict__ b1l,
    const ushort_t* __restrict__ b2h, const ushort_t* __restrict__ b2l,
    float* __restrict__ scb, int b0, unsigned scstride_z)
{
  __shared__ ushort_t sm[4][64 * SLST];
  int batch = b0 + blockIdx.z;
  size_t poff_g = (size_t)batch * HW * CI;
  float* Sc = scb + (size_t)blockIdx.z * scstride_z;

  int tid = threadIdx.x;
  int m0 = blockIdx.y * 64, n0 = blockIdx.x * 64;
  int lane = tid & 63;
  int wv = tid >> 6;

  int srow = (wv < 2) ? (m0 + lane) : (n0 + lane);
  if (srow > L_ - 1) srow = L_ - 1;
  int slh = srow / OH_, slw = srow - slh * OH_;
  int sbase = (slh * ST) * W_ + slw * ST;
  const ushort_t* splane = (wv == 0) ? (b1h + poff_g) : (wv == 1) ? (b1l + poff_g)
                          : (wv == 2) ? (b2h + poff_g) : (b2l + poff_g);
  ushort_t* drow = sm[wv] + lane * SLST;

  int fr = lane & 31;
  int kh = (lane >> 5) << 3;
  int aoff = (((wv >> 1) << 5) + fr) * SLST + kh;
  int boff = (((wv & 1) << 5) + fr) * SLST + kh;

  f32x16 acc = {0.f,0.f,0.f,0.f,0.f,0.f,0.f,0.f,0.f,0.f,0.f,0.f,0.f,0.f,0.f,0.f};

  int4 v0, v1, v2, v3, v4, v5, v6, v7;
  {
    const int4* src = (const int4*)(splane + (size_t)sbase * 16);
    v0 = src[0]; v1 = src[1]; v2 = src[2]; v3 = src[3];
    v4 = src[4]; v5 = src[5]; v6 = src[6]; v7 = src[7];
  }

  for (int r = 0; r < 14; ++r) {
    int half = r & 1;
    __syncthreads();
    *(int4*)(drow + 0)  = v0;  *(int4*)(drow + 8)  = v1;
    *(int4*)(drow + 16) = v2;  *(int4*)(drow + 24) = v3;
    *(int4*)(drow + 32) = v4;  *(int4*)(drow + 40) = v5;
    if (!half) { *(int4*)(drow + 48) = v6; *(int4*)(drow + 56) = v7; }
    __syncthreads();
    if (r < 13) {
      int rn = r + 1;
      int nki = rn >> 1, nkj0 = (rn & 1) * 4;
      const int4* src = (const int4*)(splane + (size_t)(sbase + nki * W_ + nkj0) * 16);
      v0 = src[0]; v1 = src[1]; v2 = src[2]; v3 = src[3]; v4 = src[4]; v5 = src[5];
      if (!(rn & 1)) { v6 = src[6]; v7 = src[7]; }
    }
    if (!half) {
#pragma unroll
      for (int t = 0; t < 4; ++t) {
        bfv8 ah = *(const bfv8*)(sm[0] + aoff + t * 16);
        bfv8 al = *(const bfv8*)(sm[1] + aoff + t * 16);
        bfv8 bh = *(const bfv8*)(sm[2] + boff + t * 16);
        bfv8 bl = *(const bfv8*)(sm[3] + boff + t * 16);
        acc = __builtin_amdgcn_mfma_f32_32x32x16_bf16(al, bh, acc, 0, 0, 0);
        acc = __builtin_amdgcn_mfma_f32_32x32x16_bf16(ah, bl, acc, 0, 0, 0);
        acc = __builtin_amdgcn_mfma_f32_32x32x16_bf16(ah, bh, acc, 0, 0, 0);
      }
    } else {
#pragma unroll
      for (int t = 0; t < 3; ++t) {
        bfv8 ah = *(const bfv8*)(sm[0] + aoff + t * 16);
        bfv8 al = *(const bfv8*)(sm[1] + aoff + t * 16);
        bfv8 bh = *(const bfv8*)(sm[2] + boff + t * 16);
        bfv8 bl = *(const bfv8*)(sm[3] + boff + t * 16);
        acc = __builtin_amdgcn_mfma_f32_32x32x16_bf16(al, bh, acc, 0, 0, 0);
        acc = __builtin_amdgcn_mfma_f32_32x32x16_bf16(ah, bl, acc, 0, 0, 0);
        acc = __builtin_amdgcn_mfma_f32_32x32x16_bf16(ah, bh, acc, 0, 0, 0);
      }
    }
  }

  int mw = m0 + ((wv >> 1) << 5);
  int nw = n0 + ((wv & 1) << 5) + (lane & 31);
  if (nw < L_) {
#pragma unroll
    for (int r = 0; r < 16; ++r) {
      int m = mw + (r & 3) + ((r >> 2) << 3) + ((lane >> 5) << 2);
      if (m < L_) Sc[(size_t)m * SROW + nw] = acc[r];
    }
  }
}

// -------- top-100 + softmax weights: 1 wave per row, register-resident -----------
__global__ __launch_bounds__(64) void k_topk(
    const float* __restrict__ scb, float* __restrict__ tkw, int* __restrict__ tkp,
    unsigned scstride_z)
{
  __shared__ float swv[TOPM];
  __shared__ int spx[TOPM];
  int lane = threadIdx.x;
  int l = blockIdx.x, bz = blockIdx.y;
  const float4* row4 = (const float4*)(scb + (size_t)bz * scstride_z + (size_t)l * SROW);
  int trow = (bz * L_ + l) * TKROW;

  unsigned k[16];
#pragma unroll
  for (int q = 0; q < 4; ++q) {
    float4 v = row4[q * 64 + lane];
    int ib = (q * 64 + lane) * 4;
    k[q * 4 + 0] = (ib + 0 < L_) ? fmap(v.x) : 0u;
    k[q * 4 + 1] = (ib + 1 < L_) ? fmap(v.y) : 0u;
    k[q * 4 + 2] = (ib + 2 < L_) ? fmap(v.z) : 0u;
    k[q * 4 + 3] = (ib + 3 < L_) ? fmap(v.w) : 0u;
  }

  unsigned mk = 0;
#pragma unroll
  for (int r = 0; r < 16; ++r) mk = max(mk, k[r]);
#pragma unroll
  for (int o = 32; o; o >>= 1) mk = max(mk, (unsigned)__shfl_down((int)mk, o));
  mk = (unsigned)__shfl((int)mk, 0);
  float vmax = unfmap(mk);

  unsigned alive = 0xFFFFu;
  unsigned prefix = 0; int base = 0;
  for (int bit = 30; bit >= 0; bit -= 2) {
    int c1 = 0, c2 = 0, c3 = 0;
#pragma unroll
    for (int r = 0; r < 16; ++r) {
      if ((alive >> r) & 1) {
        unsigned f = (k[r] >> bit) & 3u;
        c3 += (f == 3); c2 += (f >= 2); c1 += (f >= 1);
      }
    }
    int p = c3 | (c2 << 10) | (c1 << 20);
#pragma unroll
    for (int o = 32; o; o >>= 1) p += __shfl_down(p, o);
    p = __shfl(p, 0);
    int n3 = p & 1023, n2 = (p >> 10) & 1023, n1 = (p >> 20) & 1023;
    unsigned ch;
    if (base + n3 >= TOPM) ch = 3;
    else if (base + n2 >= TOPM) { ch = 2; base += n3; }
    else if (base + n1 >= TOPM) { ch = 1; base += n2; }
    else { ch = 0; base += n1; }
    prefix |= ch << bit;
#pragma unroll
    for (int r = 0; r < 16; ++r) {
      if ((alive >> r) & 1) {
        unsigned f = (k[r] >> bit) & 3u;
        if (f != ch) alive &= ~(1u << r);
      }
    }
  }
  int nA = base;
  int needT = TOPM - nA;

  int cA = 0, cT = 0;
#pragma unroll
  for (int r = 0; r < 16; ++r) { cA += (k[r] > prefix); cT += (k[r] == prefix); }
  int pk = cA | (cT << 16);
  int incl = pk;
#pragma unroll
  for (int o = 1; o < 64; o <<= 1) { int t = __shfl_up(incl, o); if (lane >= o) incl += t; }
  int excl = incl - pk;
  int tA = excl & 0xFFFF, tT = excl >> 16;

  float M = fmaxf(10.f * vmax, 0.f);
  float e0 = expf(-M);
  float z = 0.f;
#pragma unroll
  for (int r = 0; r < 16; ++r) {
    unsigned kk = k[r];
    int slot = -1;
    if (kk > prefix) slot = tA++;
    else if (kk == prefix) { if (tT < needT) slot = nA + tT; tT++; }
    if (slot >= 0) {
      float v = unfmap(kk);
      float wv = expf(10.f * v - M);
      swv[slot] = wv; z += wv;
      int gi = 256 * (r >> 2) + 4 * lane + (r & 3);
      int lh = gi / OH_, lw = gi - lh * OH_;
      spx[slot] = ((lh * ST) * W_ + lw * ST) * CI;
    }
  }
#pragma unroll
  for (int o = 32; o; o >>= 1) z += __shfl_down(z, o);
  z = __shfl(z, 0);
  float Z = z + (float)(L_ - TOPM) * e0;
  float invZ = 1.f / Z;
  float w0 = e0 / Z;
  __syncthreads();
#pragma unroll
  for (int s0 = 0; s0 < 2; ++s0) {
    int s = lane + 64 * s0;
    if (s < TOPM) {
      tkw[trow + s] = swv[s] * invZ - w0;
      tkp[trow + s] = spx[s];
    }
  }
  if (lane == 0) tkw[trow + TOPM] = w0;
}

// -------- PV gather: agg[l,:] = sum_j wj*B3[pix_j,:] + w0*S3 ---------------------
__global__ __launch_bounds__(256) void k_pv(
    const float* __restrict__ tkw, const int* __restrict__ tkp,
    const float* __restrict__ b3, const float* __restrict__ s3,
    float* __restrict__ agb, int b0, unsigned agstride_z)
{
  int l = blockIdx.x, bz = blockIdx.y;
  int batch = b0 + bz;
  int trow = (bz * L_ + l) * TKROW;
  const float* B3 = b3 + (size_t)batch * HW * CI;
  const float* S3 = s3 + (size_t)batch * D_;
  float* agg = agb + (size_t)bz * agstride_z;
  int tid = threadIdx.x;
  if (tid >= 196) return;

  float w0 = tkw[trow + TOPM];
  int pos = tid >> 2;
  int c0 = (tid << 2) & 15;
  int ki = pos / 7, kj = pos - (pos / 7) * 7;
  int poff = (ki * W_ + kj) * CI + c0;

  float ax = 0.f, ay = 0.f, az = 0.f, aw = 0.f;
  for (int j0 = 0; j0 < TOPM; j0 += 4) {
    float w_0 = tkw[trow + j0 + 0];
    float w_1 = tkw[trow + j0 + 1];
    float w_2 = tkw[trow + j0 + 2];
    float w_3 = tkw[trow + j0 + 3];
    int p_0 = tkp[trow + j0 + 0];
    int p_1 = tkp[trow + j0 + 1];
    int p_2 = tkp[trow + j0 + 2];
    int p_3 = tkp[trow + j0 + 3];
    const float4 q0 = *(const float4*)(B3 + p_0 + poff);
    const float4 q1 = *(const float4*)(B3 + p_1 + poff);
    const float4 q2 = *(const float4*)(B3 + p_2 + poff);
    const float4 q3 = *(const float4*)(B3 + p_3 + poff);
    ax += w_0 * q0.x; ay += w_0 * q0.y; az += w_0 * q0.z; aw += w_0 * q0.w;
    ax += w_1 * q1.x; ay += w_1 * q1.y; az += w_1 * q1.z; aw += w_1 * q1.w;
    ax += w_2 * q2.x; ay += w_2 * q2.y; az += w_2 * q2.z; aw += w_2 * q2.w;
    ax += w_3 * q3.x; ay += w_3 * q3.y; az += w_3 * q3.z; aw += w_3 * q3.w;
  }
  const float4 s4 = *(const float4*)(S3 + tid * 4);
  ax += w0 * s4.x; ay += w0 * s4.y; az += w0 * s4.z; aw += w0 * s4.w;
  *(float4*)(agg + (size_t)l * D_ + tid * 4) = make_float4(ax, ay, az, aw);
}

// -------- fold + mask divide + restore (16->64), batched -------------------------
__global__ __launch_bounds__(256) void k_fold(
    const int* __restrict__ flag, const float* __restrict__ ws,
    const float* __restrict__ agb, void* __restrict__ out,
    int b0, unsigned agstride_z)
{
  __shared__ float srw[CIN * CI];
  int tid = threadIdx.x;
  for (int i = tid; i < CIN * CI; i += 256) srw[i] = ws[RW_O + i];
  __syncthreads();

  int bz = blockIdx.y;
  int batch = b0 + bz;
  const float* agg = agb + (size_t)bz * agstride_z;

  int gid = blockIdx.x * 256 + tid;
  if (gid >= HW) return;
  int h = gid / W_;
  int w = gid % W_;

  int lh0 = (h >= KS - 1) ? ((h - (KS - 1) + (ST - 1)) >> 2) : 0;
  int lh1 = min(OH_ - 1, h >> 2);
  int lw0 = (w >= KS - 1) ? ((w - (KS - 1) + (ST - 1)) >> 2) : 0;
  int lw1 = min(OH_ - 1, w >> 2);

  float t[CI];
#pragma unroll
  for (int c = 0; c < CI; ++c) t[c] = 0.f;
  for (int lh = lh0; lh <= lh1; ++lh) {
    int ki = h - ST * lh;
    for (int lw = lw0; lw <= lw1; ++lw) {
      int kj = w - ST * lw;
      const float* pb = agg + (size_t)(lh * OH_ + lw) * D_ + (ki * KS + kj) * CI;
      float4 q0 = *(const float4*)(pb);
      float4 q1 = *(const float4*)(pb + 4);
      float4 q2 = *(const float4*)(pb + 8);
      float4 q3 = *(const float4*)(pb + 12);
      t[0] += q0.x; t[1] += q0.y; t[2] += q0.z; t[3] += q0.w;
      t[4] += q1.x; t[5] += q1.y; t[6] += q1.z; t[7] += q1.w;
      t[8] += q2.x; t[9] += q2.y; t[10] += q2.z; t[11] += q2.w;
      t[12] += q3.x; t[13] += q3.y; t[14] += q3.z; t[15] += q3.w;
    }
  }
  float cnt = (float)((lh1 - lh0 + 1) * (lw1 - lw0 + 1));
  float r[CI];
#pragma unroll
  for (int c = 0; c < CI; ++c) r[c] = t[c] / (cnt * ws[SM_O + c] + ws[SB_O + c] + 1e-8f);

  size_t ob = (size_t)batch * CIN * HW + (size_t)h * W_ + w;
  if (*flag) {
    float* of = (float*)out;
#pragma unroll
    for (int o = 0; o < CIN; ++o) {
      float s = ws[RB_O + o];
#pragma unroll
      for (int c = 0; c < CI; ++c) s += srw[o * CI + c] * r[c];
      of[ob + (size_t)o * HW] = s;
    }
  } else {
    bf16* of = (bf16*)out;
#pragma unroll
    for (int o = 0; o < CIN; ++o) {
      float s = ws[RB_O + o];
#pragma unroll
      for (int c = 0; c < CI; ++c) s += srw[o * CI + c] * r[c];
      of[ob + (size_t)o * HW] = __float2bfloat16(s);
    }
  }
}

extern "C" void kernel_launch(void* const* d_in, const int* in_sizes, int n_in,
                              void* d_out, int out_size, void* d_ws, size_t ws_size,
                              hipStream_t stream)
{
  const void* x    = d_in[0];
  const void* g_w  = d_in[1];
  const void* g_b  = d_in[2];
  const void* th_w = d_in[3];
  const void* th_b = d_in[4];
  const void* ph_w = d_in[5];
  const void* ph_b = d_in[6];
  const void* m_w  = d_in[7];
  const void* m_b  = d_in[8];
  const void* r_w  = d_in[9];
  const void* r_b  = d_in[10];

  float* W = (float*)d_ws;
  int* flag = (int*)d_ws;
  ushort_t* planes = (ushort_t*)(W + B1_O);
  ushort_t* b1h = planes;
  ushort_t* b1l = planes + (size_t)N1;
  ushort_t* b2h = planes + (size_t)2 * N1;
  ushort_t* b2l = planes + (size_t)3 * N1;
  float* b3 = W + B1_O + 2 * N1;
  float* s3 = W + S3_O;

  k_detect<<<1, 64, 0, stream>>>((const unsigned short*)x, flag);
  k_prep<<<1, 256, 0, stream>>>(flag, g_w, th_w, ph_w, g_b, th_b, ph_b,
                                m_w, m_b, r_w, r_b, W);

  if (ws_size >= FULL_BYTES) {
    ushort_t* xhh = (ushort_t*)(W + REG_O);    // bf16 hi/lo x planes, dead after conv
    ushort_t* xhl = xhh + (size_t)XHSZ;
    float* sc = W + REG_O;                     // 4 x SCSLOT, aliases x planes
    float* ag = W + REG_O + XHSZ;              // 4 x AGSZ
    float* tkw = W + B1_O + N1;                // b2h region (dead after k_score)
    int*   tkp = (int*)(W + B1_O + N1 + N1 / 2);
    k_hwc<<<dim3((B_ * HW + 63) / 64), 256, 0, stream>>>(flag, x, xhh, xhl);
    k_conv3<<<dim3((HW + 63) / 64, 1, B_), 256, 0, stream>>>(
        W, xhh, xhl, b1h, b1l, b2h, b2l, b3);
    k_colsum<<<dim3(B_, 49), 256, 0, stream>>>(b3, s3);
    k_score<<<dim3(16, 16, B_), 256, 0, stream>>>(b1h, b1l, b2h, b2l, sc, 0, SCSLOT);
    k_topk<<<dim3(L_, B_), 64, 0, stream>>>(sc, tkw, tkp, SCSLOT);
    k_pv<<<dim3(L_, B_), 256, 0, stream>>>(tkw, tkp, b3, s3, ag, 0, AGSZ);
    k_fold<<<dim3(64, B_), 256, 0, stream>>>(flag, W, ag, d_out, 0, AGSZ);
  } else if (ws_size >= MID_BYTES) {
    ushort_t* xhh = (ushort_t*)(W + REG_O);
    ushort_t* xhl = xhh + (size_t)XHSZ;
    float* sc = W + REG_O;                     // 1 slot, aliases x planes
    float* ag = W + REG_O + SCSLOT;
    k_hwc<<<dim3((B_ * HW + 63) / 64), 256, 0, stream>>>(flag, x, xhh, xhl);
    k_conv3<<<dim3((HW + 63) / 64, 1, B_), 256, 0, stream>>>(
        W, xhh, xhl, b1h, b1l, b2h, b2l, b3);
    k_colsum<<<dim3(B_, 49), 256, 0, stream>>>(b3, s3);
    for (int b = 0; b < B_; ++b) {
      float* tkw = W + B1_O + N1 + (size_t)b * (HW * CI / 2);
      int*   tkp = (int*)(W + B1_O + N1 + N1 / 2 + (size_t)b * (HW * CI / 2));
      k_score<<<dim3(16, 16, 1), 256, 0, stream>>>(b1h, b1l, b2h, b2l, sc, b, 0);
      k_topk<<<dim3(L_, 1), 64, 0, stream>>>(sc, tkw, tkp, 0);
      k_pv<<<dim3(L_, 1), 256, 0, stream>>>(tkw, tkp, b3, s3, ag, b, 0);
      k_fold<<<dim3(64, 1), 256, 0, stream>>>(flag, W, ag, d_out, b, 0);
    }
  } else {
    float* sc = W + REG_O;
    float* ag = W + REG_O + SCSLOT;
    k_convF<<<dim3(4, 16, B_), dim3(32, 8, 1), 0, stream>>>(
        flag, x, g_w, g_b, th_w, th_b, ph_w, ph_b, b1h, b1l, b2h, b2l, b3);
    k_colsum<<<dim3(B_, 49), 256, 0, stream>>>(b3, s3);
    for (int b = 0; b < B_; ++b) {
      float* tkw = W + B1_O + N1 + (size_t)b * (HW * CI / 2);
      int*   tkp = (int*)(W + B1_O + N1 + N1 / 2 + (size_t)b * (HW * CI / 2));
      k_score<<<dim3(16, 16, 1), 256, 0, stream>>>(b1h, b1l, b2h, b2l, sc, b, 0);
      k_topk<<<dim3(L_, 1), 64, 0, stream>>>(sc, tkw, tkp, 0);
      k_pv<<<dim3(L_, 1), 256, 0, stream>>>(tkw, tkp, b3, s3, ag, b, 0);
      k_fold<<<dim3(64, 1), 256, 0, stream>>>(flag, W, ag, d_out, b, 0);
    }
  }
}

// Round 12
// 347.877 us; speedup vs baseline: 1.0614x; 1.0345x over previous
//
#include <hip/hip_runtime.h>
#include <hip/hip_bf16.h>

typedef __hip_bfloat16 bf16;
typedef unsigned short ushort_t;
typedef __attribute__((ext_vector_type(8))) __bf16 bfv8;
typedef __attribute__((ext_vector_type(16))) float f32x16;

#define B_   4
#define CIN  64
#define CI   16
#define H_   127
#define W_   127
#define HW   (H_*W_)
#define KS   7
#define ST   4
#define OH_  31
#define L_   961
#define D_   784
#define TOPM 100

// ---- workspace layout (float offsets) ----
#define N1   1032256          // B*HW*CI elements (one conv-out array)
#define WG_O 4
#define WT_O (WG_O + 9216)
#define WP_O (WT_O + 1024)
#define BG_O (WP_O + 1024)
#define BT_O (BG_O + 16)
#define BP_O (BT_O + 16)
#define SM_O (BP_O + 16)
#define SB_O (SM_O + 16)
#define RW_O (SB_O + 16)
#define RB_O (RW_O + 1024)
#define B1_O 12448
// planes at B1_O: b1h,b1l,b2h,b2l each N1 ushorts (2*N1 floats); b3 bf16 N1 ushorts
#define S3_O (B1_O + 3*N1)
#define WB_O (S3_O + B_*D_)   // conv MFMA B: wBh + wBl = 36864 floats
#define REG_O (WB_O + 36864)
#define XHSZ 4129024          // B*HW*64 ushorts per x plane (2 planes = XHSZ floats)
#define SROW 964              // padded Sc row stride
#define SCSLOT 926464
#define AGSZ 753424
#define TKROW 112
#define SLST 72               // LDS row stride in ushorts (conflict-free, measured r8)

#define FULL_BYTES ((size_t)(REG_O + XHSZ + 4*AGSZ) * 4)   // ~41.1 MB
#define MID_BYTES  ((size_t)(REG_O + XHSZ) * 4)            // ~29.1 MB

__device__ __forceinline__ float bf2f(bf16 v) { return __bfloat162float(v); }
__device__ __forceinline__ float bflo(unsigned u) { return __uint_as_float(u << 16); }
__device__ __forceinline__ float bfhi(unsigned u) { return __uint_as_float(u & 0xFFFF0000u); }

template <typename T> struct Ld;
template <> struct Ld<float> {
  static __device__ __forceinline__ float f(const void* p, int i) { return ((const float*)p)[i]; }
};
template <> struct Ld<bf16> {
  static __device__ __forceinline__ float f(const void* p, int i) { return bf2f(((const bf16*)p)[i]); }
};

__device__ __forceinline__ unsigned fmap(float f) {
  unsigned u = __float_as_uint(f);
  return (u & 0x80000000u) ? ~u : (u | 0x80000000u);
}
__device__ __forceinline__ float unfmap(unsigned kk) {
  unsigned u = (kk & 0x80000000u) ? (kk & 0x7fffffffu) : ~kk;
  return __uint_as_float(u);
}

// RNE fp32 -> bf16 bits, and hi/lo split
__device__ __forceinline__ ushort_t f2bf(float x) {
  unsigned u = __float_as_uint(x);
  return (ushort_t)((u + 0x7FFFu + ((u >> 16) & 1u)) >> 16);
}
__device__ __forceinline__ void splitbf(float x, ushort_t& h, ushort_t& l) {
  h = f2bf(x);
  float hf = __uint_as_float(((unsigned)h) << 16);
  l = f2bf(x - hf);
}

// -------- dtype detector: flag=1 -> fp32 buffers, flag=0 -> bf16 -----------------
__global__ void k_detect(const unsigned short* __restrict__ xh, int* __restrict__ flag) {
  int tid = threadIdx.x;  // 64
  int c = 0;
#pragma unroll
  for (int j = 0; j < 2; ++j) {
    unsigned u = xh[tid * 2 + j];
    unsigned e = (u >> 7) & 0xFF;
    if (e >= 134) c++;
  }
#pragma unroll
  for (int o = 32; o; o >>= 1) c += __shfl_down(c, o);
  if (tid == 0) *flag = (c >= 8) ? 1 : 0;
}

// -------- weight prep ------------------------------------------------------------
#define LDW(ptr, i) (f ? ((const float*)(ptr))[i] : bf2f(((const bf16*)(ptr))[i]))
__global__ __launch_bounds__(256) void k_prep(
    const int* __restrict__ flag,
    const void* g_w, const void* t_w, const void* p_w,
    const void* g_b, const void* t_b, const void* p_b,
    const void* m_w, const void* m_b, const void* r_w, const void* r_b,
    float* __restrict__ ws)
{
  int tid = threadIdx.x;
  int f = *flag;
  for (int i = tid; i < 9216; i += 256) {
    int o = i & 15, t = i >> 4, c = t & 63, tap = t >> 6;
    ws[WG_O + i] = LDW(g_w, (o * 64 + c) * 9 + tap);
  }
  for (int i = tid; i < 1024; i += 256) {
    int o = i & 15, c = i >> 4;
    ws[WT_O + i] = LDW(t_w, o * 64 + c);
    ws[WP_O + i] = LDW(p_w, o * 64 + c);
  }
  if (tid < 16) {
    ws[BG_O + tid] = LDW(g_b, tid);
    ws[BT_O + tid] = LDW(t_b, tid);
    ws[BP_O + tid] = LDW(p_b, tid);
    float s = 0.f;
    for (int c = 0; c < 64; ++c) s += LDW(m_w, tid * 64 + c);
    ws[SM_O + tid] = s;
    ws[SB_O + tid] = LDW(m_b, tid);
  }
  for (int i = tid; i < 1024; i += 256) ws[RW_O + i] = LDW(r_w, i);
  if (tid < 64) ws[RB_O + tid] = LDW(r_b, tid);
  // conv MFMA B, split hi/lo: wB[tap][col64][c64]
  ushort_t* wBh = (ushort_t*)(ws + WB_O);
  ushort_t* wBl = wBh + 9 * 64 * 64;
  for (int i = tid; i < 9 * 64 * 64; i += 256) {
    int c = i & 63, t = i >> 6, col = t & 63, tap = t >> 6;
    float v = 0.f;
    if (col < 16) v = LDW(g_w, (col * 64 + c) * 9 + tap);
    else if (col < 32) { if (tap == 4) v = LDW(t_w, (col - 16) * 64 + c); }
    else if (col < 48) { if (tap == 4) v = LDW(p_w, (col - 32) * 64 + c); }
    ushort_t h, l; splitbf(v, h, l);
    wBh[i] = h; wBl[i] = l;
  }
}

// -------- x [B,64,H,W] -> HWC bf16 hi/lo planes ----------------------------------
__global__ __launch_bounds__(256) void k_hwc(
    const int* __restrict__ flag, const void* __restrict__ x,
    ushort_t* __restrict__ xhh, ushort_t* __restrict__ xhl)
{
  __shared__ float tile[64][65];
  int pix0 = blockIdx.x * 64;
  int tid = threadIdx.x;
  int g = tid >> 6, p = tid & 63;
  int pix = pix0 + p;
  bool ok = pix < B_ * HW;
  int bb = ok ? pix / HW : 0;
  int r  = ok ? pix - bb * HW : 0;
  if (*flag) {
    const float* xf = (const float*)x;
    for (int c = g * 16; c < g * 16 + 16; ++c)
      tile[p][c] = ok ? xf[((size_t)bb * CIN + c) * HW + r] : 0.f;
  } else {
    const bf16* xb = (const bf16*)x;
    for (int c = g * 16; c < g * 16 + 16; ++c)
      tile[p][c] = ok ? bf2f(xb[((size_t)bb * CIN + c) * HW + r]) : 0.f;
  }
  __syncthreads();
  int c2 = tid & 63, pg = tid >> 6;
  for (int k = 0; k < 16; ++k) {
    int p2 = pg * 16 + k;
    int pix2 = pix0 + p2;
    if (pix2 < B_ * HW) {
      ushort_t h, l; splitbf(tile[p2][c2], h, l);
      xhh[(size_t)pix2 * 64 + c2] = h;
      xhl[(size_t)pix2 * 64 + c2] = l;
    }
  }
}

// -------- unified split-bf16 MFMA conv (r11-verified) ----------------------------
__global__ __launch_bounds__(256) void k_conv3(
    const float* __restrict__ ws,
    const ushort_t* __restrict__ xhh, const ushort_t* __restrict__ xhl,
    ushort_t* __restrict__ b1h, ushort_t* __restrict__ b1l,
    ushort_t* __restrict__ b2h, ushort_t* __restrict__ b2l,
    ushort_t* __restrict__ b3)
{
  __shared__ ushort_t sm[4][64 * SLST];
  int bz = blockIdx.z;
  int px0 = blockIdx.x * 64;
  int tid = threadIdx.x, lane = tid & 63, wv = tid >> 6;

  int pix = px0 + lane;
  bool pok = pix < HW;
  int ph = pok ? pix / W_ : 0;
  int pw = pok ? pix - ph * W_ : 0;
  const ushort_t* xplane = ((wv == 0) ? xhh : xhl) + (size_t)bz * HW * 64;
  const ushort_t* wBh = (const ushort_t*)(ws + WB_O);
  const ushort_t* bsrc = (wv == 2) ? wBh : (wBh + 9 * 64 * 64);
  ushort_t* drow = sm[wv] + lane * SLST;

  int fr = lane & 31, kh = (lane >> 5) << 3;
  int aoff = (((wv >> 1) << 5) + fr) * SLST + kh;
  int boff = (((wv & 1) << 5) + fr) * SLST + kh;

  f32x16 acc = {0.f,0.f,0.f,0.f,0.f,0.f,0.f,0.f,0.f,0.f,0.f,0.f,0.f,0.f,0.f,0.f};
  const int4 z4 = make_int4(0, 0, 0, 0);
  int4 v0 = z4, v1 = z4, v2 = z4, v3 = z4, v4 = z4, v5 = z4, v6 = z4, v7 = z4;

  if (wv < 2) {
    int hh = ph - 1, ww = pw - 1;
    if (pok && hh >= 0 && ww >= 0) {
      const int4* s = (const int4*)(xplane + (size_t)(hh * W_ + ww) * 64);
      v0 = s[0]; v1 = s[1]; v2 = s[2]; v3 = s[3]; v4 = s[4]; v5 = s[5]; v6 = s[6]; v7 = s[7];
    }
  } else {
    const int4* s = (const int4*)(bsrc + (size_t)lane * 64);
    v0 = s[0]; v1 = s[1]; v2 = s[2]; v3 = s[3]; v4 = s[4]; v5 = s[5]; v6 = s[6]; v7 = s[7];
  }

  for (int r = 0; r < 9; ++r) {
    __syncthreads();
    *(int4*)(drow + 0)  = v0;  *(int4*)(drow + 8)  = v1;
    *(int4*)(drow + 16) = v2;  *(int4*)(drow + 24) = v3;
    *(int4*)(drow + 32) = v4;  *(int4*)(drow + 40) = v5;
    *(int4*)(drow + 48) = v6;  *(int4*)(drow + 56) = v7;
    __syncthreads();
    if (r < 8) {
      int rn = r + 1;
      if (wv < 2) {
        int hh = ph + rn / 3 - 1, ww = pw + rn % 3 - 1;
        if (pok && (unsigned)hh < (unsigned)H_ && (unsigned)ww < (unsigned)W_) {
          const int4* s = (const int4*)(xplane + (size_t)(hh * W_ + ww) * 64);
          v0 = s[0]; v1 = s[1]; v2 = s[2]; v3 = s[3]; v4 = s[4]; v5 = s[5]; v6 = s[6]; v7 = s[7];
        } else {
          v0 = z4; v1 = z4; v2 = z4; v3 = z4; v4 = z4; v5 = z4; v6 = z4; v7 = z4;
        }
      } else {
        const int4* s = (const int4*)(bsrc + ((size_t)rn * 64 + lane) * 64);
        v0 = s[0]; v1 = s[1]; v2 = s[2]; v3 = s[3]; v4 = s[4]; v5 = s[5]; v6 = s[6]; v7 = s[7];
      }
    }
#pragma unroll
    for (int t = 0; t < 4; ++t) {
      bfv8 ah = *(const bfv8*)(sm[0] + aoff + t * 16);
      bfv8 al = *(const bfv8*)(sm[1] + aoff + t * 16);
      bfv8 bh = *(const bfv8*)(sm[2] + boff + t * 16);
      bfv8 bl = *(const bfv8*)(sm[3] + boff + t * 16);
      acc = __builtin_amdgcn_mfma_f32_32x32x16_bf16(al, bh, acc, 0, 0, 0);
      acc = __builtin_amdgcn_mfma_f32_32x32x16_bf16(ah, bl, acc, 0, 0, 0);
      acc = __builtin_amdgcn_mfma_f32_32x32x16_bf16(ah, bh, acc, 0, 0, 0);
    }
  }

  int nw = ((wv & 1) << 5) + fr;
  int mwb = (wv >> 1) << 5;
#pragma unroll
  for (int r = 0; r < 16; ++r) {
    int m = mwb + (r & 3) + ((r >> 2) << 3) + ((lane >> 5) << 2);
    int p2 = px0 + m;
    if (p2 >= HW) continue;
    size_t ob = ((size_t)bz * HW + p2) * 16;
    float val = acc[r];
    if (nw < 16) {
      ushort_t h2, l2; splitbf(val + ws[BG_O + nw], h2, l2);
      b1h[ob + nw] = h2; b1l[ob + nw] = l2;
    } else if (nw < 32) {
      int o = nw - 16; ushort_t h2, l2; splitbf(val + ws[BT_O + o], h2, l2);
      b2h[ob + o] = h2; b2l[ob + o] = l2;
    } else if (nw < 48) {
      int o = nw - 32; b3[ob + o] = f2bf(val + ws[BP_O + o]);
    }
  }
}

// -------- fallback conv (LOW tier), dtype-templated VALU -------------------------
template <typename T>
__device__ __forceinline__ void convF_body(
    const void* x, const void* g_w, const void* g_b,
    const void* t_w, const void* t_b, const void* p_w, const void* p_b,
    ushort_t* b1h, ushort_t* b1l, ushort_t* b2h, ushort_t* b2l, ushort_t* b3,
    float* sgw, float* stw, float* spw)
{
  int tid = threadIdx.y * 32 + threadIdx.x;
  for (int i = tid; i < CI * CIN * 9; i += 256) sgw[i] = Ld<T>::f(g_w, i);
  for (int i = tid; i < CI * CIN; i += 256) { stw[i] = Ld<T>::f(t_w, i); spw[i] = Ld<T>::f(p_w, i); }
  __syncthreads();

  int w = blockIdx.x * 32 + threadIdx.x;
  int h = blockIdx.y * 8 + threadIdx.y;
  int b = blockIdx.z;
  if (w >= W_ || h >= H_) return;

  float a1[CI], a2[CI], a3[CI];
#pragma unroll
  for (int o = 0; o < CI; ++o) { a1[o] = 0.f; a2[o] = 0.f; a3[o] = 0.f; }

  const size_t xb = (size_t)b * CIN * HW;
  for (int c = 0; c < CIN; ++c) {
    float xv[9];
#pragma unroll
    for (int dh = 0; dh < 3; ++dh) {
      int hh = h + dh - 1;
      bool rok = ((unsigned)hh < (unsigned)H_);
#pragma unroll
      for (int dw = 0; dw < 3; ++dw) {
        int ww = w + dw - 1;
        bool ok = rok && ((unsigned)ww < (unsigned)W_);
        xv[dh * 3 + dw] = ok ? Ld<T>::f(x, (int)(xb + (size_t)c * HW + hh * W_ + ww)) : 0.f;
      }
    }
    float xc = xv[4];
#pragma unroll
    for (int o = 0; o < CI; ++o) {
      const float* gg = &sgw[(o * CIN + c) * 9];
      float s = gg[0]*xv[0] + gg[1]*xv[1] + gg[2]*xv[2]
              + gg[3]*xv[3] + gg[4]*xv[4] + gg[5]*xv[5]
              + gg[6]*xv[6] + gg[7]*xv[7] + gg[8]*xv[8];
      a1[o] += s;
      a2[o] += stw[o * CIN + c] * xc;
      a3[o] += spw[o * CIN + c] * xc;
    }
  }
  size_t base = ((size_t)b * HW + h * W_ + w) * CI;
#pragma unroll
  for (int o = 0; o < CI; ++o) {
    float v1 = a1[o] + Ld<T>::f(g_b, o);
    float v2 = a2[o] + Ld<T>::f(t_b, o);
    ushort_t hh2, ll2;
    splitbf(v1, hh2, ll2); b1h[base + o] = hh2; b1l[base + o] = ll2;
    splitbf(v2, hh2, ll2); b2h[base + o] = hh2; b2l[base + o] = ll2;
    b3[base + o] = f2bf(a3[o] + Ld<T>::f(p_b, o));
  }
}

__global__ __launch_bounds__(256) void k_convF(
    const int* __restrict__ flag, const void* x,
    const void* g_w, const void* g_b, const void* t_w, const void* t_b,
    const void* p_w, const void* p_b,
    ushort_t* __restrict__ b1h, ushort_t* __restrict__ b1l,
    ushort_t* __restrict__ b2h, ushort_t* __restrict__ b2l,
    ushort_t* __restrict__ b3)
{
  __shared__ float sgw[CI * CIN * 9];
  __shared__ float stw[CI * CIN];
  __shared__ float spw[CI * CIN];
  if (*flag) convF_body<float>(x, g_w, g_b, t_w, t_b, p_w, p_b, b1h, b1l, b2h, b2l, b3, sgw, stw, spw);
  else       convF_body<bf16 >(x, g_w, g_b, t_w, t_b, p_w, p_b, b1h, b1l, b2h, b2l, b3, sgw, stw, spw);
}

// -------- S3[b, pos*16+c] = sum over patches of b3 (bf16 src, fp32 acc) ----------
__global__ __launch_bounds__(256) void k_colsum(const ushort_t* __restrict__ b3, float* __restrict__ S3)
{
  __shared__ float red[16][17];
  int b = blockIdx.x, pos = blockIdx.y;
  int ki = pos / 7, kj = pos % 7;
  int c = threadIdx.x & 15, chunk = threadIdx.x >> 4;
  const ushort_t* B3 = b3 + (size_t)b * HW * CI;
  float s = 0.f;
  for (int l = chunk; l < L_; l += 16) {
    int lh = l / OH_, lw = l % OH_;
    s += bflo((unsigned)B3[((lh * ST + ki) * W_ + lw * ST + kj) * CI + c]);
  }
  red[chunk][c] = s;
  __syncthreads();
  if (threadIdx.x < 16) {
    float t = 0.f;
#pragma unroll
    for (int k = 0; k < 16; ++k) t += red[k][threadIdx.x];
    S3[(b * 49 + pos) * 16 + threadIdx.x] = t;
  }
}

// -------- score GEMM via split-bf16 MFMA, 128x64 tile ---------------------------
// 2 m-subtiles per wave: 6 LDS reads per 6 MFMA (was 4 per 3) -> 2x LDS efficiency.
// LDS = (128+128+64+64)*SLST*2 = 55296 B; grid 512 blocks = 2/CU.
__global__ __launch_bounds__(256) void k_score(
    const ushort_t* __restrict__ b1h, const ushort_t* __restrict__ b1l,
    const ushort_t* __restrict__ b2h, const ushort_t* __restrict__ b2l,
    float* __restrict__ scb, int b0, unsigned scstride_z)
{
  __shared__ ushort_t sAh[128 * SLST], sAl[128 * SLST];
  __shared__ ushort_t sBh[64 * SLST],  sBl[64 * SLST];
  int batch = b0 + blockIdx.z;
  size_t poff_g = (size_t)batch * HW * CI;
  float* Sc = scb + (size_t)blockIdx.z * scstride_z;

  int tid = threadIdx.x;
  int m0 = blockIdx.y * 128, n0 = blockIdx.x * 64;
  int lane = tid & 63;
  int wv = tid >> 6;

  int base_mn = (wv < 2) ? m0 : n0;
  int srow0 = base_mn + lane;       if (srow0 > L_ - 1) srow0 = L_ - 1;
  int srow1 = base_mn + lane + 64;  if (srow1 > L_ - 1) srow1 = L_ - 1;
  int slh0 = srow0 / OH_, slw0 = srow0 - slh0 * OH_;
  int slh1 = srow1 / OH_, slw1 = srow1 - slh1 * OH_;
  int sbase0 = (slh0 * ST) * W_ + slw0 * ST;
  int sbase1 = (slh1 * ST) * W_ + slw1 * ST;
  const ushort_t* splane = (wv == 0) ? (b1h + poff_g) : (wv == 1) ? (b1l + poff_g)
                          : (wv == 2) ? (b2h + poff_g) : (b2l + poff_g);
  ushort_t* dplane = (wv == 0) ? sAh : (wv == 1) ? sAl : (wv == 2) ? sBh : sBl;
  ushort_t* drow0 = dplane + lane * SLST;
  ushort_t* drow1 = dplane + (lane + 64) * SLST;   // only written when wv<2

  int fr = lane & 31;
  int kh = (lane >> 5) << 3;
  int mt = (wv >> 1) << 1;                         // first m-subtile: 0 or 2
  int aoff0 = (mt * 32 + fr) * SLST + kh;
  int aoff1 = ((mt + 1) * 32 + fr) * SLST + kh;
  int boff  = (((wv & 1) << 5) + fr) * SLST + kh;

  f32x16 acc0 = {0.f,0.f,0.f,0.f,0.f,0.f,0.f,0.f,0.f,0.f,0.f,0.f,0.f,0.f,0.f,0.f};
  f32x16 acc1 = {0.f,0.f,0.f,0.f,0.f,0.f,0.f,0.f,0.f,0.f,0.f,0.f,0.f,0.f,0.f,0.f};

  const int4 z4 = make_int4(0, 0, 0, 0);
  int4 v0, v1, v2, v3, v4, v5, v6, v7;
  int4 u0 = z4, u1 = z4, u2 = z4, u3 = z4, u4 = z4, u5 = z4, u6 = z4, u7 = z4;
  {
    const int4* s0 = (const int4*)(splane + (size_t)sbase0 * 16);
    v0 = s0[0]; v1 = s0[1]; v2 = s0[2]; v3 = s0[3];
    v4 = s0[4]; v5 = s0[5]; v6 = s0[6]; v7 = s0[7];
    if (wv < 2) {
      const int4* s1 = (const int4*)(splane + (size_t)sbase1 * 16);
      u0 = s1[0]; u1 = s1[1]; u2 = s1[2]; u3 = s1[3];
      u4 = s1[4]; u5 = s1[5]; u6 = s1[6]; u7 = s1[7];
    }
  }

  for (int r = 0; r < 14; ++r) {
    int half = r & 1;
    __syncthreads();
    *(int4*)(drow0 + 0)  = v0;  *(int4*)(drow0 + 8)  = v1;
    *(int4*)(drow0 + 16) = v2;  *(int4*)(drow0 + 24) = v3;
    *(int4*)(drow0 + 32) = v4;  *(int4*)(drow0 + 40) = v5;
    if (!half) { *(int4*)(drow0 + 48) = v6; *(int4*)(drow0 + 56) = v7; }
    if (wv < 2) {
      *(int4*)(drow1 + 0)  = u0;  *(int4*)(drow1 + 8)  = u1;
      *(int4*)(drow1 + 16) = u2;  *(int4*)(drow1 + 24) = u3;
      *(int4*)(drow1 + 32) = u4;  *(int4*)(drow1 + 40) = u5;
      if (!half) { *(int4*)(drow1 + 48) = u6; *(int4*)(drow1 + 56) = u7; }
    }
    __syncthreads();
    if (r < 13) {
      int rn = r + 1;
      int nki = rn >> 1, nkj0 = (rn & 1) * 4;
      const int4* s0 = (const int4*)(splane + (size_t)(sbase0 + nki * W_ + nkj0) * 16);
      v0 = s0[0]; v1 = s0[1]; v2 = s0[2]; v3 = s0[3]; v4 = s0[4]; v5 = s0[5];
      if (!(rn & 1)) { v6 = s0[6]; v7 = s0[7]; }
      if (wv < 2) {
        const int4* s1 = (const int4*)(splane + (size_t)(sbase1 + nki * W_ + nkj0) * 16);
        u0 = s1[0]; u1 = s1[1]; u2 = s1[2]; u3 = s1[3]; u4 = s1[4]; u5 = s1[5];
        if (!(rn & 1)) { u6 = s1[6]; u7 = s1[7]; }
      }
    }
    if (!half) {
#pragma unroll
      for (int t = 0; t < 4; ++t) {
        bfv8 ah0 = *(const bfv8*)(sAh + aoff0 + t * 16);
        bfv8 al0 = *(const bfv8*)(sAl + aoff0 + t * 16);
        bfv8 ah1 = *(const bfv8*)(sAh + aoff1 + t * 16);
        bfv8 al1 = *(const bfv8*)(sAl + aoff1 + t * 16);
        bfv8 bh  = *(const bfv8*)(sBh + boff + t * 16);
        bfv8 bl  = *(const bfv8*)(sBl + boff + t * 16);
        acc0 = __builtin_amdgcn_mfma_f32_32x32x16_bf16(al0, bh, acc0, 0, 0, 0);
        acc0 = __builtin_amdgcn_mfma_f32_32x32x16_bf16(ah0, bl, acc0, 0, 0, 0);
        acc0 = __builtin_amdgcn_mfma_f32_32x32x16_bf16(ah0, bh, acc0, 0, 0, 0);
        acc1 = __builtin_amdgcn_mfma_f32_32x32x16_bf16(al1, bh, acc1, 0, 0, 0);
        acc1 = __builtin_amdgcn_mfma_f32_32x32x16_bf16(ah1, bl, acc1, 0, 0, 0);
        acc1 = __builtin_amdgcn_mfma_f32_32x32x16_bf16(ah1, bh, acc1, 0, 0, 0);
      }
    } else {
#pragma unroll
      for (int t = 0; t < 3; ++t) {
        bfv8 ah0 = *(const bfv8*)(sAh + aoff0 + t * 16);
        bfv8 al0 = *(const bfv8*)(sAl + aoff0 + t * 16);
        bfv8 ah1 = *(const bfv8*)(sAh + aoff1 + t * 16);
        bfv8 al1 = *(const bfv8*)(sAl + aoff1 + t * 16);
        bfv8 bh  = *(const bfv8*)(sBh + boff + t * 16);
        bfv8 bl  = *(const bfv8*)(sBl + boff + t * 16);
        acc0 = __builtin_amdgcn_mfma_f32_32x32x16_bf16(al0, bh, acc0, 0, 0, 0);
        acc0 = __builtin_amdgcn_mfma_f32_32x32x16_bf16(ah0, bl, acc0, 0, 0, 0);
        acc0 = __builtin_amdgcn_mfma_f32_32x32x16_bf16(ah0, bh, acc0, 0, 0, 0);
        acc1 = __builtin_amdgcn_mfma_f32_32x32x16_bf16(al1, bh, acc1, 0, 0, 0);
        acc1 = __builtin_amdgcn_mfma_f32_32x32x16_bf16(ah1, bl, acc1, 0, 0, 0);
        acc1 = __builtin_amdgcn_mfma_f32_32x32x16_bf16(ah1, bh, acc1, 0, 0, 0);
      }
    }
  }

  int nw = n0 + ((wv & 1) << 5) + fr;
  if (nw < L_) {
    int mw0 = m0 + mt * 32;
#pragma unroll
    for (int r = 0; r < 16; ++r) {
      int m = mw0 + (r & 3) + ((r >> 2) << 3) + ((lane >> 5) << 2);
      if (m < L_) Sc[(size_t)m * SROW + nw] = acc0[r];
    }
    int mw1 = m0 + (mt + 1) * 32;
#pragma unroll
    for (int r = 0; r < 16; ++r) {
      int m = mw1 + (r & 3) + ((r >> 2) << 3) + ((lane >> 5) << 2);
      if (m < L_) Sc[(size_t)m * SROW + nw] = acc1[r];
    }
  }
}

// -------- top-100 + softmax weights: 1 wave per row, register-resident -----------
__global__ __launch_bounds__(64) void k_topk(
    const float* __restrict__ scb, float* __restrict__ tkw, int* __restrict__ tkp,
    unsigned scstride_z)
{
  __shared__ float swv[TOPM];
  __shared__ int spx[TOPM];
  int lane = threadIdx.x;
  int l = blockIdx.x, bz = blockIdx.y;
  const float4* row4 = (const float4*)(scb + (size_t)bz * scstride_z + (size_t)l * SROW);
  int trow = (bz * L_ + l) * TKROW;

  unsigned k[16];
#pragma unroll
  for (int q = 0; q < 4; ++q) {
    float4 v = row4[q * 64 + lane];
    int ib = (q * 64 + lane) * 4;
    k[q * 4 + 0] = (ib + 0 < L_) ? fmap(v.x) : 0u;
    k[q * 4 + 1] = (ib + 1 < L_) ? fmap(v.y) : 0u;
    k[q * 4 + 2] = (ib + 2 < L_) ? fmap(v.z) : 0u;
    k[q * 4 + 3] = (ib + 3 < L_) ? fmap(v.w) : 0u;
  }

  unsigned mk = 0;
#pragma unroll
  for (int r = 0; r < 16; ++r) mk = max(mk, k[r]);
#pragma unroll
  for (int o = 32; o; o >>= 1) mk = max(mk, (unsigned)__shfl_down((int)mk, o));
  mk = (unsigned)__shfl((int)mk, 0);
  float vmax = unfmap(mk);

  unsigned alive = 0xFFFFu;
  unsigned prefix = 0; int base = 0;
  for (int bit = 30; bit >= 0; bit -= 2) {
    int c1 = 0, c2 = 0, c3 = 0;
#pragma unroll
    for (int r = 0; r < 16; ++r) {
      if ((alive >> r) & 1) {
        unsigned f = (k[r] >> bit) & 3u;
        c3 += (f == 3); c2 += (f >= 2); c1 += (f >= 1);
      }
    }
    int p = c3 | (c2 << 10) | (c1 << 20);
#pragma unroll
    for (int o = 32; o; o >>= 1) p += __shfl_down(p, o);
    p = __shfl(p, 0);
    int n3 = p & 1023, n2 = (p >> 10) & 1023, n1 = (p >> 20) & 1023;
    unsigned ch;
    if (base + n3 >= TOPM) ch = 3;
    else if (base + n2 >= TOPM) { ch = 2; base += n3; }
    else if (base + n1 >= TOPM) { ch = 1; base += n2; }
    else { ch = 0; base += n1; }
    prefix |= ch << bit;
#pragma unroll
    for (int r = 0; r < 16; ++r) {
      if ((alive >> r) & 1) {
        unsigned f = (k[r] >> bit) & 3u;
        if (f != ch) alive &= ~(1u << r);
      }
    }
  }
  int nA = base;
  int needT = TOPM - nA;

  int cA = 0, cT = 0;
#pragma unroll
  for (int r = 0; r < 16; ++r) { cA += (k[r] > prefix); cT += (k[r] == prefix); }
  int pk = cA | (cT << 16);
  int incl = pk;
#pragma unroll
  for (int o = 1; o < 64; o <<= 1) { int t = __shfl_up(incl, o); if (lane >= o) incl += t; }
  int excl = incl - pk;
  int tA = excl & 0xFFFF, tT = excl >> 16;

  float M = fmaxf(10.f * vmax, 0.f);
  float e0 = expf(-M);
  float z = 0.f;
#pragma unroll
  for (int r = 0; r < 16; ++r) {
    unsigned kk = k[r];
    int slot = -1;
    if (kk > prefix) slot = tA++;
    else if (kk == prefix) { if (tT < needT) slot = nA + tT; tT++; }
    if (slot >= 0) {
      float v = unfmap(kk);
      float wv = expf(10.f * v - M);
      swv[slot] = wv; z += wv;
      int gi = 256 * (r >> 2) + 4 * lane + (r & 3);
      int lh = gi / OH_, lw = gi - lh * OH_;
      spx[slot] = ((lh * ST) * W_ + lw * ST) * CI;
    }
  }
#pragma unroll
  for (int o = 32; o; o >>= 1) z += __shfl_down(z, o);
  z = __shfl(z, 0);
  float Z = z + (float)(L_ - TOPM) * e0;
  float invZ = 1.f / Z;
  float w0 = e0 / Z;
  __syncthreads();
#pragma unroll
  for (int s0 = 0; s0 < 2; ++s0) {
    int s = lane + 64 * s0;
    if (s < TOPM) {
      tkw[trow + s] = swv[s] * invZ - w0;
      tkp[trow + s] = spx[s];
    }
  }
  if (lane == 0) tkw[trow + TOPM] = w0;
}

// -------- PV gather (bf16 b3): agg[l,:] = sum_j wj*B3[pix_j,:] + w0*S3 -----------
__global__ __launch_bounds__(256) void k_pv(
    const float* __restrict__ tkw, const int* __restrict__ tkp,
    const ushort_t* __restrict__ b3, const float* __restrict__ s3,
    float* __restrict__ agb, int b0, unsigned agstride_z)
{
  int l = blockIdx.x, bz = blockIdx.y;
  int batch = b0 + bz;
  int trow = (bz * L_ + l) * TKROW;
  const ushort_t* B3 = b3 + (size_t)batch * HW * CI;
  const float* S3 = s3 + (size_t)batch * D_;
  float* agg = agb + (size_t)bz * agstride_z;
  int tid = threadIdx.x;
  if (tid >= 196) return;

  float w0 = tkw[trow + TOPM];
  int pos = tid >> 2;
  int c0 = (tid << 2) & 15;
  int ki = pos / 7, kj = pos - (pos / 7) * 7;
  int poff = (ki * W_ + kj) * CI + c0;

  float ax = 0.f, ay = 0.f, az = 0.f, aw = 0.f;
  for (int j0 = 0; j0 < TOPM; j0 += 4) {
    float w_0 = tkw[trow + j0 + 0];
    float w_1 = tkw[trow + j0 + 1];
    float w_2 = tkw[trow + j0 + 2];
    float w_3 = tkw[trow + j0 + 3];
    int p_0 = tkp[trow + j0 + 0];
    int p_1 = tkp[trow + j0 + 1];
    int p_2 = tkp[trow + j0 + 2];
    int p_3 = tkp[trow + j0 + 3];
    const uint2 q0 = *(const uint2*)(B3 + p_0 + poff);
    const uint2 q1 = *(const uint2*)(B3 + p_1 + poff);
    const uint2 q2 = *(const uint2*)(B3 + p_2 + poff);
    const uint2 q3 = *(const uint2*)(B3 + p_3 + poff);
    ax += w_0 * bflo(q0.x); ay += w_0 * bfhi(q0.x); az += w_0 * bflo(q0.y); aw += w_0 * bfhi(q0.y);
    ax += w_1 * bflo(q1.x); ay += w_1 * bfhi(q1.x); az += w_1 * bflo(q1.y); aw += w_1 * bfhi(q1.y);
    ax += w_2 * bflo(q2.x); ay += w_2 * bfhi(q2.x); az += w_2 * bflo(q2.y); aw += w_2 * bfhi(q2.y);
    ax += w_3 * bflo(q3.x); ay += w_3 * bfhi(q3.x); az += w_3 * bflo(q3.y); aw += w_3 * bfhi(q3.y);
  }
  const float4 s4 = *(const float4*)(S3 + tid * 4);
  ax += w0 * s4.x; ay += w0 * s4.y; az += w0 * s4.z; aw += w0 * s4.w;
  *(float4*)(agg + (size_t)l * D_ + tid * 4) = make_float4(ax, ay, az, aw);
}

// -------- fold + mask divide + restore (16->64), batched -------------------------
__global__ __launch_bounds__(256) void k_fold(
    const int* __restrict__ flag, const float* __restrict__ ws,
    const float* __restrict__ agb, void* __restrict__ out,
    int b0, unsigned agstride_z)
{
  __shared__ float srw[CIN * CI];
  int tid = threadIdx.x;
  for (int i = tid; i < CIN * CI; i += 256) srw[i] = ws[RW_O + i];
  __syncthreads();

  int bz = blockIdx.y;
  int batch = b0 + bz;
  const float* agg = agb + (size_t)bz * agstride_z;

  int gid = blockIdx.x * 256 + tid;
  if (gid >= HW) return;
  int h = gid / W_;
  int w = gid % W_;

  int lh0 = (h >= KS - 1) ? ((h - (KS - 1) + (ST - 1)) >> 2) : 0;
  int lh1 = min(OH_ - 1, h >> 2);
  int lw0 = (w >= KS - 1) ? ((w - (KS - 1) + (ST - 1)) >> 2) : 0;
  int lw1 = min(OH_ - 1, w >> 2);

  float t[CI];
#pragma unroll
  for (int c = 0; c < CI; ++c) t[c] = 0.f;
  for (int lh = lh0; lh <= lh1; ++lh) {
    int ki = h - ST * lh;
    for (int lw = lw0; lw <= lw1; ++lw) {
      int kj = w - ST * lw;
      const float* pb = agg + (size_t)(lh * OH_ + lw) * D_ + (ki * KS + kj) * CI;
      float4 q0 = *(const float4*)(pb);
      float4 q1 = *(const float4*)(pb + 4);
      float4 q2 = *(const float4*)(pb + 8);
      float4 q3 = *(const float4*)(pb + 12);
      t[0] += q0.x; t[1] += q0.y; t[2] += q0.z; t[3] += q0.w;
      t[4] += q1.x; t[5] += q1.y; t[6] += q1.z; t[7] += q1.w;
      t[8] += q2.x; t[9] += q2.y; t[10] += q2.z; t[11] += q2.w;
      t[12] += q3.x; t[13] += q3.y; t[14] += q3.z; t[15] += q3.w;
    }
  }
  float cnt = (float)((lh1 - lh0 + 1) * (lw1 - lw0 + 1));
  float r[CI];
#pragma unroll
  for (int c = 0; c < CI; ++c) r[c] = t[c] / (cnt * ws[SM_O + c] + ws[SB_O + c] + 1e-8f);

  size_t ob = (size_t)batch * CIN * HW + (size_t)h * W_ + w;
  if (*flag) {
    float* of = (float*)out;
#pragma unroll
    for (int o = 0; o < CIN; ++o) {
      float s = ws[RB_O + o];
#pragma unroll
      for (int c = 0; c < CI; ++c) s += srw[o * CI + c] * r[c];
      of[ob + (size_t)o * HW] = s;
    }
  } else {
    bf16* of = (bf16*)out;
#pragma unroll
    for (int o = 0; o < CIN; ++o) {
      float s = ws[RB_O + o];
#pragma unroll
      for (int c = 0; c < CI; ++c) s += srw[o * CI + c] * r[c];
      of[ob + (size_t)o * HW] = __float2bfloat16(s);
    }
  }
}

extern "C" void kernel_launch(void* const* d_in, const int* in_sizes, int n_in,
                              void* d_out, int out_size, void* d_ws, size_t ws_size,
                              hipStream_t stream)
{
  const void* x    = d_in[0];
  const void* g_w  = d_in[1];
  const void* g_b  = d_in[2];
  const void* th_w = d_in[3];
  const void* th_b = d_in[4];
  const void* ph_w = d_in[5];
  const void* ph_b = d_in[6];
  const void* m_w  = d_in[7];
  const void* m_b  = d_in[8];
  const void* r_w  = d_in[9];
  const void* r_b  = d_in[10];

  float* W = (float*)d_ws;
  int* flag = (int*)d_ws;
  ushort_t* planes = (ushort_t*)(W + B1_O);
  ushort_t* b1h = planes;
  ushort_t* b1l = planes + (size_t)N1;
  ushort_t* b2h = planes + (size_t)2 * N1;
  ushort_t* b2l = planes + (size_t)3 * N1;
  ushort_t* b3  = planes + (size_t)4 * N1;   // bf16 plane, N1 ushorts
  float* s3 = W + S3_O;

  k_detect<<<1, 64, 0, stream>>>((const unsigned short*)x, flag);
  k_prep<<<1, 256, 0, stream>>>(flag, g_w, th_w, ph_w, g_b, th_b, ph_b,
                                m_w, m_b, r_w, r_b, W);

  if (ws_size >= FULL_BYTES) {
    ushort_t* xhh = (ushort_t*)(W + REG_O);    // bf16 hi/lo x planes, dead after conv
    ushort_t* xhl = xhh + (size_t)XHSZ;
    float* sc = W + REG_O;                     // 4 x SCSLOT, aliases x planes
    float* ag = W + REG_O + XHSZ;              // 4 x AGSZ
    float* tkw = W + B1_O + N1;                // b2h region (dead after k_score)
    int*   tkp = (int*)(W + B1_O + N1 + N1 / 2);
    k_hwc<<<dim3((B_ * HW + 63) / 64), 256, 0, stream>>>(flag, x, xhh, xhl);
    k_conv3<<<dim3((HW + 63) / 64, 1, B_), 256, 0, stream>>>(
        W, xhh, xhl, b1h, b1l, b2h, b2l, b3);
    k_colsum<<<dim3(B_, 49), 256, 0, stream>>>(b3, s3);
    k_score<<<dim3(16, 8, B_), 256, 0, stream>>>(b1h, b1l, b2h, b2l, sc, 0, SCSLOT);
    k_topk<<<dim3(L_, B_), 64, 0, stream>>>(sc, tkw, tkp, SCSLOT);
    k_pv<<<dim3(L_, B_), 256, 0, stream>>>(tkw, tkp, b3, s3, ag, 0, AGSZ);
    k_fold<<<dim3(64, B_), 256, 0, stream>>>(flag, W, ag, d_out, 0, AGSZ);
  } else if (ws_size >= MID_BYTES) {
    ushort_t* xhh = (ushort_t*)(W + REG_O);
    ushort_t* xhl = xhh + (size_t)XHSZ;
    float* sc = W + REG_O;
    float* ag = W + REG_O + SCSLOT;
    k_hwc<<<dim3((B_ * HW + 63) / 64), 256, 0, stream>>>(flag, x, xhh, xhl);
    k_conv3<<<dim3((HW + 63) / 64, 1, B_), 256, 0, stream>>>(
        W, xhh, xhl, b1h, b1l, b2h, b2l, b3);
    k_colsum<<<dim3(B_, 49), 256, 0, stream>>>(b3, s3);
    for (int b = 0; b < B_; ++b) {
      float* tkw = W + B1_O + N1 + (size_t)b * (HW * CI / 2);
      int*   tkp = (int*)(W + B1_O + N1 + N1 / 2 + (size_t)b * (HW * CI / 2));
      k_score<<<dim3(16, 8, 1), 256, 0, stream>>>(b1h, b1l, b2h, b2l, sc, b, 0);
      k_topk<<<dim3(L_, 1), 64, 0, stream>>>(sc, tkw, tkp, 0);
      k_pv<<<dim3(L_, 1), 256, 0, stream>>>(tkw, tkp, b3, s3, ag, b, 0);
      k_fold<<<dim3(64, 1), 256, 0, stream>>>(flag, W, ag, d_out, b, 0);
    }
  } else {
    float* sc = W + REG_O;
    float* ag = W + REG_O + SCSLOT;
    k_convF<<<dim3(4, 16, B_), dim3(32, 8, 1), 0, stream>>>(
        flag, x, g_w, g_b, th_w, th_b, ph_w, ph_b, b1h, b1l, b2h, b2l, b3);
    k_colsum<<<dim3(B_, 49), 256, 0, stream>>>(b3, s3);
    for (int b = 0; b < B_; ++b) {
      float* tkw = W + B1_O + N1 + (size_t)b * (HW * CI / 2);
      int*   tkp = (int*)(W + B1_O + N1 + N1 / 2 + (size_t)b * (HW * CI / 2));
      k_score<<<dim3(16, 8, 1), 256, 0, stream>>>(b1h, b1l, b2h, b2l, sc, b, 0);
      k_topk<<<dim3(L_, 1), 64, 0, stream>>>(sc, tkw, tkp, 0);
      k_pv<<<dim3(L_, 1), 256, 0, stream>>>(tkw, tkp, b3, s3, ag, b, 0);
      k_fold<<<dim3(64, 1), 256, 0, stream>>>(flag, W, ag, d_out, b, 0);
    }
  }
}

// Round 13
// 332.412 us; speedup vs baseline: 1.1108x; 1.0465x over previous
//
#include <hip/hip_runtime.h>
#include <hip/hip_bf16.h>

typedef __hip_bfloat16 bf16;
typedef unsigned short ushort_t;
typedef __attribute__((ext_vector_type(8))) __bf16 bfv8;
typedef __attribute__((ext_vector_type(16))) float f32x16;

#define B_   4
#define CIN  64
#define CI   16
#define H_   127
#define W_   127
#define HW   (H_*W_)
#define KS   7
#define ST   4
#define OH_  31
#define L_   961
#define D_   784
#define TOPM 100

// ---- workspace layout (float offsets) ----
#define N1   1032256          // B*HW*CI elements (one conv-out array)
#define WG_O 4
#define WT_O (WG_O + 9216)
#define WP_O (WT_O + 1024)
#define BG_O (WP_O + 1024)
#define BT_O (BG_O + 16)
#define BP_O (BT_O + 16)
#define SM_O (BP_O + 16)
#define SB_O (SM_O + 16)
#define RW_O (SB_O + 16)
#define RB_O (RW_O + 1024)
#define B1_O 12448
// planes at B1_O: b1h,b1l,b2h,b2l each N1 ushorts (2*N1 floats); b3 bf16 N1 ushorts
#define S3_O (B1_O + 3*N1)
#define WB_O (S3_O + B_*D_)   // conv MFMA B: wBh + wBl = 36864 floats
#define REG_O (WB_O + 36864)
#define XHSZ 4129024          // B*HW*64 ushorts per x plane (2 planes = XHSZ floats)
#define SROW 964              // padded Sc row stride
#define SCSLOT 926464
#define AGSZ 753424
#define TKROW 112
#define SLST 72               // LDS row stride in ushorts (conflict-free, measured r8)

#define FULL_BYTES ((size_t)(REG_O + XHSZ + 4*AGSZ) * 4)   // ~41.1 MB
#define MID_BYTES  ((size_t)(REG_O + XHSZ) * 4)            // ~29.1 MB

__device__ __forceinline__ float bf2f(bf16 v) { return __bfloat162float(v); }
__device__ __forceinline__ float bflo(unsigned u) { return __uint_as_float(u << 16); }
__device__ __forceinline__ float bfhi(unsigned u) { return __uint_as_float(u & 0xFFFF0000u); }

template <typename T> struct Ld;
template <> struct Ld<float> {
  static __device__ __forceinline__ float f(const void* p, int i) { return ((const float*)p)[i]; }
};
template <> struct Ld<bf16> {
  static __device__ __forceinline__ float f(const void* p, int i) { return bf2f(((const bf16*)p)[i]); }
};

__device__ __forceinline__ unsigned fmap(float f) {
  unsigned u = __float_as_uint(f);
  return (u & 0x80000000u) ? ~u : (u | 0x80000000u);
}
__device__ __forceinline__ float unfmap(unsigned kk) {
  unsigned u = (kk & 0x80000000u) ? (kk & 0x7fffffffu) : ~kk;
  return __uint_as_float(u);
}

// RNE fp32 -> bf16 bits, and hi/lo split
__device__ __forceinline__ ushort_t f2bf(float x) {
  unsigned u = __float_as_uint(x);
  return (ushort_t)((u + 0x7FFFu + ((u >> 16) & 1u)) >> 16);
}
__device__ __forceinline__ void splitbf(float x, ushort_t& h, ushort_t& l) {
  h = f2bf(x);
  float hf = __uint_as_float(((unsigned)h) << 16);
  l = f2bf(x - hf);
}

// -------- dtype detector: flag=1 -> fp32 buffers, flag=0 -> bf16 -----------------
__global__ void k_detect(const unsigned short* __restrict__ xh, int* __restrict__ flag) {
  int tid = threadIdx.x;  // 64
  int c = 0;
#pragma unroll
  for (int j = 0; j < 2; ++j) {
    unsigned u = xh[tid * 2 + j];
    unsigned e = (u >> 7) & 0xFF;
    if (e >= 134) c++;
  }
#pragma unroll
  for (int o = 32; o; o >>= 1) c += __shfl_down(c, o);
  if (tid == 0) *flag = (c >= 8) ? 1 : 0;
}

// -------- weight prep ------------------------------------------------------------
#define LDW(ptr, i) (f ? ((const float*)(ptr))[i] : bf2f(((const bf16*)(ptr))[i]))
__global__ __launch_bounds__(256) void k_prep(
    const int* __restrict__ flag,
    const void* g_w, const void* t_w, const void* p_w,
    const void* g_b, const void* t_b, const void* p_b,
    const void* m_w, const void* m_b, const void* r_w, const void* r_b,
    float* __restrict__ ws)
{
  int tid = threadIdx.x;
  int f = *flag;
  for (int i = tid; i < 9216; i += 256) {
    int o = i & 15, t = i >> 4, c = t & 63, tap = t >> 6;
    ws[WG_O + i] = LDW(g_w, (o * 64 + c) * 9 + tap);
  }
  for (int i = tid; i < 1024; i += 256) {
    int o = i & 15, c = i >> 4;
    ws[WT_O + i] = LDW(t_w, o * 64 + c);
    ws[WP_O + i] = LDW(p_w, o * 64 + c);
  }
  if (tid < 16) {
    ws[BG_O + tid] = LDW(g_b, tid);
    ws[BT_O + tid] = LDW(t_b, tid);
    ws[BP_O + tid] = LDW(p_b, tid);
    float s = 0.f;
    for (int c = 0; c < 64; ++c) s += LDW(m_w, tid * 64 + c);
    ws[SM_O + tid] = s;
    ws[SB_O + tid] = LDW(m_b, tid);
  }
  for (int i = tid; i < 1024; i += 256) ws[RW_O + i] = LDW(r_w, i);
  if (tid < 64) ws[RB_O + tid] = LDW(r_b, tid);
  // conv MFMA B, split hi/lo: wB[tap][col64][c64]
  ushort_t* wBh = (ushort_t*)(ws + WB_O);
  ushort_t* wBl = wBh + 9 * 64 * 64;
  for (int i = tid; i < 9 * 64 * 64; i += 256) {
    int c = i & 63, t = i >> 6, col = t & 63, tap = t >> 6;
    float v = 0.f;
    if (col < 16) v = LDW(g_w, (col * 64 + c) * 9 + tap);
    else if (col < 32) { if (tap == 4) v = LDW(t_w, (col - 16) * 64 + c); }
    else if (col < 48) { if (tap == 4) v = LDW(p_w, (col - 32) * 64 + c); }
    ushort_t h, l; splitbf(v, h, l);
    wBh[i] = h; wBl[i] = l;
  }
}

// -------- x [B,64,H,W] -> HWC bf16 hi/lo planes ----------------------------------
__global__ __launch_bounds__(256) void k_hwc(
    const int* __restrict__ flag, const void* __restrict__ x,
    ushort_t* __restrict__ xhh, ushort_t* __restrict__ xhl)
{
  __shared__ float tile[64][65];
  int pix0 = blockIdx.x * 64;
  int tid = threadIdx.x;
  int g = tid >> 6, p = tid & 63;
  int pix = pix0 + p;
  bool ok = pix < B_ * HW;
  int bb = ok ? pix / HW : 0;
  int r  = ok ? pix - bb * HW : 0;
  if (*flag) {
    const float* xf = (const float*)x;
    for (int c = g * 16; c < g * 16 + 16; ++c)
      tile[p][c] = ok ? xf[((size_t)bb * CIN + c) * HW + r] : 0.f;
  } else {
    const bf16* xb = (const bf16*)x;
    for (int c = g * 16; c < g * 16 + 16; ++c)
      tile[p][c] = ok ? bf2f(xb[((size_t)bb * CIN + c) * HW + r]) : 0.f;
  }
  __syncthreads();
  int c2 = tid & 63, pg = tid >> 6;
  for (int k = 0; k < 16; ++k) {
    int p2 = pg * 16 + k;
    int pix2 = pix0 + p2;
    if (pix2 < B_ * HW) {
      ushort_t h, l; splitbf(tile[p2][c2], h, l);
      xhh[(size_t)pix2 * 64 + c2] = h;
      xhl[(size_t)pix2 * 64 + c2] = l;
    }
  }
}

// -------- unified split-bf16 MFMA conv (r11-verified) ----------------------------
__global__ __launch_bounds__(256) void k_conv3(
    const float* __restrict__ ws,
    const ushort_t* __restrict__ xhh, const ushort_t* __restrict__ xhl,
    ushort_t* __restrict__ b1h, ushort_t* __restrict__ b1l,
    ushort_t* __restrict__ b2h, ushort_t* __restrict__ b2l,
    ushort_t* __restrict__ b3)
{
  __shared__ ushort_t sm[4][64 * SLST];
  int bz = blockIdx.z;
  int px0 = blockIdx.x * 64;
  int tid = threadIdx.x, lane = tid & 63, wv = tid >> 6;

  int pix = px0 + lane;
  bool pok = pix < HW;
  int ph = pok ? pix / W_ : 0;
  int pw = pok ? pix - ph * W_ : 0;
  const ushort_t* xplane = ((wv == 0) ? xhh : xhl) + (size_t)bz * HW * 64;
  const ushort_t* wBh = (const ushort_t*)(ws + WB_O);
  const ushort_t* bsrc = (wv == 2) ? wBh : (wBh + 9 * 64 * 64);
  ushort_t* drow = sm[wv] + lane * SLST;

  int fr = lane & 31, kh = (lane >> 5) << 3;
  int aoff = (((wv >> 1) << 5) + fr) * SLST + kh;
  int boff = (((wv & 1) << 5) + fr) * SLST + kh;

  f32x16 acc = {0.f,0.f,0.f,0.f,0.f,0.f,0.f,0.f,0.f,0.f,0.f,0.f,0.f,0.f,0.f,0.f};
  const int4 z4 = make_int4(0, 0, 0, 0);
  int4 v0 = z4, v1 = z4, v2 = z4, v3 = z4, v4 = z4, v5 = z4, v6 = z4, v7 = z4;

  if (wv < 2) {
    int hh = ph - 1, ww = pw - 1;
    if (pok && hh >= 0 && ww >= 0) {
      const int4* s = (const int4*)(xplane + (size_t)(hh * W_ + ww) * 64);
      v0 = s[0]; v1 = s[1]; v2 = s[2]; v3 = s[3]; v4 = s[4]; v5 = s[5]; v6 = s[6]; v7 = s[7];
    }
  } else {
    const int4* s = (const int4*)(bsrc + (size_t)lane * 64);
    v0 = s[0]; v1 = s[1]; v2 = s[2]; v3 = s[3]; v4 = s[4]; v5 = s[5]; v6 = s[6]; v7 = s[7];
  }

  for (int r = 0; r < 9; ++r) {
    __syncthreads();
    *(int4*)(drow + 0)  = v0;  *(int4*)(drow + 8)  = v1;
    *(int4*)(drow + 16) = v2;  *(int4*)(drow + 24) = v3;
    *(int4*)(drow + 32) = v4;  *(int4*)(drow + 40) = v5;
    *(int4*)(drow + 48) = v6;  *(int4*)(drow + 56) = v7;
    __syncthreads();
    if (r < 8) {
      int rn = r + 1;
      if (wv < 2) {
        int hh = ph + rn / 3 - 1, ww = pw + rn % 3 - 1;
        if (pok && (unsigned)hh < (unsigned)H_ && (unsigned)ww < (unsigned)W_) {
          const int4* s = (const int4*)(xplane + (size_t)(hh * W_ + ww) * 64);
          v0 = s[0]; v1 = s[1]; v2 = s[2]; v3 = s[3]; v4 = s[4]; v5 = s[5]; v6 = s[6]; v7 = s[7];
        } else {
          v0 = z4; v1 = z4; v2 = z4; v3 = z4; v4 = z4; v5 = z4; v6 = z4; v7 = z4;
        }
      } else {
        const int4* s = (const int4*)(bsrc + ((size_t)rn * 64 + lane) * 64);
        v0 = s[0]; v1 = s[1]; v2 = s[2]; v3 = s[3]; v4 = s[4]; v5 = s[5]; v6 = s[6]; v7 = s[7];
      }
    }
#pragma unroll
    for (int t = 0; t < 4; ++t) {
      bfv8 ah = *(const bfv8*)(sm[0] + aoff + t * 16);
      bfv8 al = *(const bfv8*)(sm[1] + aoff + t * 16);
      bfv8 bh = *(const bfv8*)(sm[2] + boff + t * 16);
      bfv8 bl = *(const bfv8*)(sm[3] + boff + t * 16);
      acc = __builtin_amdgcn_mfma_f32_32x32x16_bf16(al, bh, acc, 0, 0, 0);
      acc = __builtin_amdgcn_mfma_f32_32x32x16_bf16(ah, bl, acc, 0, 0, 0);
      acc = __builtin_amdgcn_mfma_f32_32x32x16_bf16(ah, bh, acc, 0, 0, 0);
    }
  }

  int nw = ((wv & 1) << 5) + fr;
  int mwb = (wv >> 1) << 5;
#pragma unroll
  for (int r = 0; r < 16; ++r) {
    int m = mwb + (r & 3) + ((r >> 2) << 3) + ((lane >> 5) << 2);
    int p2 = px0 + m;
    if (p2 >= HW) continue;
    size_t ob = ((size_t)bz * HW + p2) * 16;
    float val = acc[r];
    if (nw < 16) {
      ushort_t h2, l2; splitbf(val + ws[BG_O + nw], h2, l2);
      b1h[ob + nw] = h2; b1l[ob + nw] = l2;
    } else if (nw < 32) {
      int o = nw - 16; ushort_t h2, l2; splitbf(val + ws[BT_O + o], h2, l2);
      b2h[ob + o] = h2; b2l[ob + o] = l2;
    } else if (nw < 48) {
      int o = nw - 32; b3[ob + o] = f2bf(val + ws[BP_O + o]);
    }
  }
}

// -------- fallback conv (LOW tier), dtype-templated VALU -------------------------
template <typename T>
__device__ __forceinline__ void convF_body(
    const void* x, const void* g_w, const void* g_b,
    const void* t_w, const void* t_b, const void* p_w, const void* p_b,
    ushort_t* b1h, ushort_t* b1l, ushort_t* b2h, ushort_t* b2l, ushort_t* b3,
    float* sgw, float* stw, float* spw)
{
  int tid = threadIdx.y * 32 + threadIdx.x;
  for (int i = tid; i < CI * CIN * 9; i += 256) sgw[i] = Ld<T>::f(g_w, i);
  for (int i = tid; i < CI * CIN; i += 256) { stw[i] = Ld<T>::f(t_w, i); spw[i] = Ld<T>::f(p_w, i); }
  __syncthreads();

  int w = blockIdx.x * 32 + threadIdx.x;
  int h = blockIdx.y * 8 + threadIdx.y;
  int b = blockIdx.z;
  if (w >= W_ || h >= H_) return;

  float a1[CI], a2[CI], a3[CI];
#pragma unroll
  for (int o = 0; o < CI; ++o) { a1[o] = 0.f; a2[o] = 0.f; a3[o] = 0.f; }

  const size_t xb = (size_t)b * CIN * HW;
  for (int c = 0; c < CIN; ++c) {
    float xv[9];
#pragma unroll
    for (int dh = 0; dh < 3; ++dh) {
      int hh = h + dh - 1;
      bool rok = ((unsigned)hh < (unsigned)H_);
#pragma unroll
      for (int dw = 0; dw < 3; ++dw) {
        int ww = w + dw - 1;
        bool ok = rok && ((unsigned)ww < (unsigned)W_);
        xv[dh * 3 + dw] = ok ? Ld<T>::f(x, (int)(xb + (size_t)c * HW + hh * W_ + ww)) : 0.f;
      }
    }
    float xc = xv[4];
#pragma unroll
    for (int o = 0; o < CI; ++o) {
      const float* gg = &sgw[(o * CIN + c) * 9];
      float s = gg[0]*xv[0] + gg[1]*xv[1] + gg[2]*xv[2]
              + gg[3]*xv[3] + gg[4]*xv[4] + gg[5]*xv[5]
              + gg[6]*xv[6] + gg[7]*xv[7] + gg[8]*xv[8];
      a1[o] += s;
      a2[o] += stw[o * CIN + c] * xc;
      a3[o] += spw[o * CIN + c] * xc;
    }
  }
  size_t base = ((size_t)b * HW + h * W_ + w) * CI;
#pragma unroll
  for (int o = 0; o < CI; ++o) {
    float v1 = a1[o] + Ld<T>::f(g_b, o);
    float v2 = a2[o] + Ld<T>::f(t_b, o);
    ushort_t hh2, ll2;
    splitbf(v1, hh2, ll2); b1h[base + o] = hh2; b1l[base + o] = ll2;
    splitbf(v2, hh2, ll2); b2h[base + o] = hh2; b2l[base + o] = ll2;
    b3[base + o] = f2bf(a3[o] + Ld<T>::f(p_b, o));
  }
}

__global__ __launch_bounds__(256) void k_convF(
    const int* __restrict__ flag, const void* x,
    const void* g_w, const void* g_b, const void* t_w, const void* t_b,
    const void* p_w, const void* p_b,
    ushort_t* __restrict__ b1h, ushort_t* __restrict__ b1l,
    ushort_t* __restrict__ b2h, ushort_t* __restrict__ b2l,
    ushort_t* __restrict__ b3)
{
  __shared__ float sgw[CI * CIN * 9];
  __shared__ float stw[CI * CIN];
  __shared__ float spw[CI * CIN];
  if (*flag) convF_body<float>(x, g_w, g_b, t_w, t_b, p_w, p_b, b1h, b1l, b2h, b2l, b3, sgw, stw, spw);
  else       convF_body<bf16 >(x, g_w, g_b, t_w, t_b, p_w, p_b, b1h, b1l, b2h, b2l, b3, sgw, stw, spw);
}

// -------- S3[b, pos*16+c] = sum over patches of b3 (bf16 src, fp32 acc) ----------
__global__ __launch_bounds__(256) void k_colsum(const ushort_t* __restrict__ b3, float* __restrict__ S3)
{
  __shared__ float red[16][17];
  int b = blockIdx.x, pos = blockIdx.y;
  int ki = pos / 7, kj = pos % 7;
  int c = threadIdx.x & 15, chunk = threadIdx.x >> 4;
  const ushort_t* B3 = b3 + (size_t)b * HW * CI;
  float s = 0.f;
  for (int l = chunk; l < L_; l += 16) {
    int lh = l / OH_, lw = l % OH_;
    s += bflo((unsigned)B3[((lh * ST + ki) * W_ + lw * ST + kj) * CI + c]);
  }
  red[chunk][c] = s;
  __syncthreads();
  if (threadIdx.x < 16) {
    float t = 0.f;
#pragma unroll
    for (int k = 0; k < 16; ++k) t += red[k][threadIdx.x];
    S3[(b * 49 + pos) * 16 + threadIdx.x] = t;
  }
}

// -------- score GEMM via split-bf16 MFMA, 128x64 tile (r12-verified) -------------
__global__ __launch_bounds__(256) void k_score(
    const ushort_t* __restrict__ b1h, const ushort_t* __restrict__ b1l,
    const ushort_t* __restrict__ b2h, const ushort_t* __restrict__ b2l,
    float* __restrict__ scb, int b0, unsigned scstride_z)
{
  __shared__ ushort_t sAh[128 * SLST], sAl[128 * SLST];
  __shared__ ushort_t sBh[64 * SLST],  sBl[64 * SLST];
  int batch = b0 + blockIdx.z;
  size_t poff_g = (size_t)batch * HW * CI;
  float* Sc = scb + (size_t)blockIdx.z * scstride_z;

  int tid = threadIdx.x;
  int m0 = blockIdx.y * 128, n0 = blockIdx.x * 64;
  int lane = tid & 63;
  int wv = tid >> 6;

  int base_mn = (wv < 2) ? m0 : n0;
  int srow0 = base_mn + lane;       if (srow0 > L_ - 1) srow0 = L_ - 1;
  int srow1 = base_mn + lane + 64;  if (srow1 > L_ - 1) srow1 = L_ - 1;
  int slh0 = srow0 / OH_, slw0 = srow0 - slh0 * OH_;
  int slh1 = srow1 / OH_, slw1 = srow1 - slh1 * OH_;
  int sbase0 = (slh0 * ST) * W_ + slw0 * ST;
  int sbase1 = (slh1 * ST) * W_ + slw1 * ST;
  const ushort_t* splane = (wv == 0) ? (b1h + poff_g) : (wv == 1) ? (b1l + poff_g)
                          : (wv == 2) ? (b2h + poff_g) : (b2l + poff_g);
  ushort_t* dplane = (wv == 0) ? sAh : (wv == 1) ? sAl : (wv == 2) ? sBh : sBl;
  ushort_t* drow0 = dplane + lane * SLST;
  ushort_t* drow1 = dplane + (lane + 64) * SLST;   // only written when wv<2

  int fr = lane & 31;
  int kh = (lane >> 5) << 3;
  int mt = (wv >> 1) << 1;                         // first m-subtile: 0 or 2
  int aoff0 = (mt * 32 + fr) * SLST + kh;
  int aoff1 = ((mt + 1) * 32 + fr) * SLST + kh;
  int boff  = (((wv & 1) << 5) + fr) * SLST + kh;

  f32x16 acc0 = {0.f,0.f,0.f,0.f,0.f,0.f,0.f,0.f,0.f,0.f,0.f,0.f,0.f,0.f,0.f,0.f};
  f32x16 acc1 = {0.f,0.f,0.f,0.f,0.f,0.f,0.f,0.f,0.f,0.f,0.f,0.f,0.f,0.f,0.f,0.f};

  const int4 z4 = make_int4(0, 0, 0, 0);
  int4 v0, v1, v2, v3, v4, v5, v6, v7;
  int4 u0 = z4, u1 = z4, u2 = z4, u3 = z4, u4 = z4, u5 = z4, u6 = z4, u7 = z4;
  {
    const int4* s0 = (const int4*)(splane + (size_t)sbase0 * 16);
    v0 = s0[0]; v1 = s0[1]; v2 = s0[2]; v3 = s0[3];
    v4 = s0[4]; v5 = s0[5]; v6 = s0[6]; v7 = s0[7];
    if (wv < 2) {
      const int4* s1 = (const int4*)(splane + (size_t)sbase1 * 16);
      u0 = s1[0]; u1 = s1[1]; u2 = s1[2]; u3 = s1[3];
      u4 = s1[4]; u5 = s1[5]; u6 = s1[6]; u7 = s1[7];
    }
  }

  for (int r = 0; r < 14; ++r) {
    int half = r & 1;
    __syncthreads();
    *(int4*)(drow0 + 0)  = v0;  *(int4*)(drow0 + 8)  = v1;
    *(int4*)(drow0 + 16) = v2;  *(int4*)(drow0 + 24) = v3;
    *(int4*)(drow0 + 32) = v4;  *(int4*)(drow0 + 40) = v5;
    if (!half) { *(int4*)(drow0 + 48) = v6; *(int4*)(drow0 + 56) = v7; }
    if (wv < 2) {
      *(int4*)(drow1 + 0)  = u0;  *(int4*)(drow1 + 8)  = u1;
      *(int4*)(drow1 + 16) = u2;  *(int4*)(drow1 + 24) = u3;
      *(int4*)(drow1 + 32) = u4;  *(int4*)(drow1 + 40) = u5;
      if (!half) { *(int4*)(drow1 + 48) = u6; *(int4*)(drow1 + 56) = u7; }
    }
    __syncthreads();
    if (r < 13) {
      int rn = r + 1;
      int nki = rn >> 1, nkj0 = (rn & 1) * 4;
      const int4* s0 = (const int4*)(splane + (size_t)(sbase0 + nki * W_ + nkj0) * 16);
      v0 = s0[0]; v1 = s0[1]; v2 = s0[2]; v3 = s0[3]; v4 = s0[4]; v5 = s0[5];
      if (!(rn & 1)) { v6 = s0[6]; v7 = s0[7]; }
      if (wv < 2) {
        const int4* s1 = (const int4*)(splane + (size_t)(sbase1 + nki * W_ + nkj0) * 16);
        u0 = s1[0]; u1 = s1[1]; u2 = s1[2]; u3 = s1[3]; u4 = s1[4]; u5 = s1[5];
        if (!(rn & 1)) { u6 = s1[6]; u7 = s1[7]; }
      }
    }
    if (!half) {
#pragma unroll
      for (int t = 0; t < 4; ++t) {
        bfv8 ah0 = *(const bfv8*)(sAh + aoff0 + t * 16);
        bfv8 al0 = *(const bfv8*)(sAl + aoff0 + t * 16);
        bfv8 ah1 = *(const bfv8*)(sAh + aoff1 + t * 16);
        bfv8 al1 = *(const bfv8*)(sAl + aoff1 + t * 16);
        bfv8 bh  = *(const bfv8*)(sBh + boff + t * 16);
        bfv8 bl  = *(const bfv8*)(sBl + boff + t * 16);
        acc0 = __builtin_amdgcn_mfma_f32_32x32x16_bf16(al0, bh, acc0, 0, 0, 0);
        acc0 = __builtin_amdgcn_mfma_f32_32x32x16_bf16(ah0, bl, acc0, 0, 0, 0);
        acc0 = __builtin_amdgcn_mfma_f32_32x32x16_bf16(ah0, bh, acc0, 0, 0, 0);
        acc1 = __builtin_amdgcn_mfma_f32_32x32x16_bf16(al1, bh, acc1, 0, 0, 0);
        acc1 = __builtin_amdgcn_mfma_f32_32x32x16_bf16(ah1, bl, acc1, 0, 0, 0);
        acc1 = __builtin_amdgcn_mfma_f32_32x32x16_bf16(ah1, bh, acc1, 0, 0, 0);
      }
    } else {
#pragma unroll
      for (int t = 0; t < 3; ++t) {
        bfv8 ah0 = *(const bfv8*)(sAh + aoff0 + t * 16);
        bfv8 al0 = *(const bfv8*)(sAl + aoff0 + t * 16);
        bfv8 ah1 = *(const bfv8*)(sAh + aoff1 + t * 16);
        bfv8 al1 = *(const bfv8*)(sAl + aoff1 + t * 16);
        bfv8 bh  = *(const bfv8*)(sBh + boff + t * 16);
        bfv8 bl  = *(const bfv8*)(sBl + boff + t * 16);
        acc0 = __builtin_amdgcn_mfma_f32_32x32x16_bf16(al0, bh, acc0, 0, 0, 0);
        acc0 = __builtin_amdgcn_mfma_f32_32x32x16_bf16(ah0, bl, acc0, 0, 0, 0);
        acc0 = __builtin_amdgcn_mfma_f32_32x32x16_bf16(ah0, bh, acc0, 0, 0, 0);
        acc1 = __builtin_amdgcn_mfma_f32_32x32x16_bf16(al1, bh, acc1, 0, 0, 0);
        acc1 = __builtin_amdgcn_mfma_f32_32x32x16_bf16(ah1, bl, acc1, 0, 0, 0);
        acc1 = __builtin_amdgcn_mfma_f32_32x32x16_bf16(ah1, bh, acc1, 0, 0, 0);
      }
    }
  }

  int nw = n0 + ((wv & 1) << 5) + fr;
  if (nw < L_) {
    int mw0 = m0 + mt * 32;
#pragma unroll
    for (int r = 0; r < 16; ++r) {
      int m = mw0 + (r & 3) + ((r >> 2) << 3) + ((lane >> 5) << 2);
      if (m < L_) Sc[(size_t)m * SROW + nw] = acc0[r];
    }
    int mw1 = m0 + (mt + 1) * 32;
#pragma unroll
    for (int r = 0; r < 16; ++r) {
      int m = mw1 + (r & 3) + ((r >> 2) << 3) + ((lane >> 5) << 2);
      if (m < L_) Sc[(size_t)m * SROW + nw] = acc1[r];
    }
  }
}

// -------- top-100 + softmax weights: 1 wave per row, register-resident -----------
__global__ __launch_bounds__(64) void k_topk(
    const float* __restrict__ scb, float* __restrict__ tkw, int* __restrict__ tkp,
    unsigned scstride_z)
{
  __shared__ float swv[TOPM];
  __shared__ int spx[TOPM];
  int lane = threadIdx.x;
  int l = blockIdx.x, bz = blockIdx.y;
  const float4* row4 = (const float4*)(scb + (size_t)bz * scstride_z + (size_t)l * SROW);
  int trow = (bz * L_ + l) * TKROW;

  unsigned k[16];
#pragma unroll
  for (int q = 0; q < 4; ++q) {
    float4 v = row4[q * 64 + lane];
    int ib = (q * 64 + lane) * 4;
    k[q * 4 + 0] = (ib + 0 < L_) ? fmap(v.x) : 0u;
    k[q * 4 + 1] = (ib + 1 < L_) ? fmap(v.y) : 0u;
    k[q * 4 + 2] = (ib + 2 < L_) ? fmap(v.z) : 0u;
    k[q * 4 + 3] = (ib + 3 < L_) ? fmap(v.w) : 0u;
  }

  unsigned mk = 0;
#pragma unroll
  for (int r = 0; r < 16; ++r) mk = max(mk, k[r]);
#pragma unroll
  for (int o = 32; o; o >>= 1) mk = max(mk, (unsigned)__shfl_down((int)mk, o));
  mk = (unsigned)__shfl((int)mk, 0);
  float vmax = unfmap(mk);

  unsigned alive = 0xFFFFu;
  unsigned prefix = 0; int base = 0;
  for (int bit = 30; bit >= 0; bit -= 2) {
    int c1 = 0, c2 = 0, c3 = 0;
#pragma unroll
    for (int r = 0; r < 16; ++r) {
      if ((alive >> r) & 1) {
        unsigned f = (k[r] >> bit) & 3u;
        c3 += (f == 3); c2 += (f >= 2); c1 += (f >= 1);
      }
    }
    int p = c3 | (c2 << 10) | (c1 << 20);
#pragma unroll
    for (int o = 32; o; o >>= 1) p += __shfl_down(p, o);
    p = __shfl(p, 0);
    int n3 = p & 1023, n2 = (p >> 10) & 1023, n1 = (p >> 20) & 1023;
    unsigned ch;
    if (base + n3 >= TOPM) ch = 3;
    else if (base + n2 >= TOPM) { ch = 2; base += n3; }
    else if (base + n1 >= TOPM) { ch = 1; base += n2; }
    else { ch = 0; base += n1; }
    prefix |= ch << bit;
#pragma unroll
    for (int r = 0; r < 16; ++r) {
      if ((alive >> r) & 1) {
        unsigned f = (k[r] >> bit) & 3u;
        if (f != ch) alive &= ~(1u << r);
      }
    }
  }
  int nA = base;
  int needT = TOPM - nA;

  int cA = 0, cT = 0;
#pragma unroll
  for (int r = 0; r < 16; ++r) { cA += (k[r] > prefix); cT += (k[r] == prefix); }
  int pk = cA | (cT << 16);
  int incl = pk;
#pragma unroll
  for (int o = 1; o < 64; o <<= 1) { int t = __shfl_up(incl, o); if (lane >= o) incl += t; }
  int excl = incl - pk;
  int tA = excl & 0xFFFF, tT = excl >> 16;

  float M = fmaxf(10.f * vmax, 0.f);
  float e0 = expf(-M);
  float z = 0.f;
#pragma unroll
  for (int r = 0; r < 16; ++r) {
    unsigned kk = k[r];
    int slot = -1;
    if (kk > prefix) slot = tA++;
    else if (kk == prefix) { if (tT < needT) slot = nA + tT; tT++; }
    if (slot >= 0) {
      float v = unfmap(kk);
      float wv = expf(10.f * v - M);
      swv[slot] = wv; z += wv;
      int gi = 256 * (r >> 2) + 4 * lane + (r & 3);
      int lh = gi / OH_, lw = gi - lh * OH_;
      spx[slot] = ((lh * ST) * W_ + lw * ST) * CI;
    }
  }
#pragma unroll
  for (int o = 32; o; o >>= 1) z += __shfl_down(z, o);
  z = __shfl(z, 0);
  float Z = z + (float)(L_ - TOPM) * e0;
  float invZ = 1.f / Z;
  float w0 = e0 / Z;
  __syncthreads();
#pragma unroll
  for (int s0 = 0; s0 < 2; ++s0) {
    int s = lane + 64 * s0;
    if (s < TOPM) {
      tkw[trow + s] = swv[s] * invZ - w0;
      tkp[trow + s] = spx[s];
    }
  }
  if (lane == 0) tkw[trow + TOPM] = w0;
}

// -------- PV gather (bf16 b3, uint4 full-line): 98 lanes x 8 channels ------------
__global__ __launch_bounds__(128) void k_pv(
    const float* __restrict__ tkw, const int* __restrict__ tkp,
    const ushort_t* __restrict__ b3, const float* __restrict__ s3,
    float* __restrict__ agb, int b0, unsigned agstride_z)
{
  int l = blockIdx.x, bz = blockIdx.y;
  int batch = b0 + bz;
  int trow = (bz * L_ + l) * TKROW;
  const ushort_t* B3 = b3 + (size_t)batch * HW * CI;
  const float* S3 = s3 + (size_t)batch * D_;
  float* agg = agb + (size_t)bz * agstride_z;
  int tid = threadIdx.x;
  if (tid >= 98) return;

  float w0 = tkw[trow + TOPM];
  int pos = tid >> 1;
  int c0 = (tid & 1) << 3;                 // 0 or 8
  int ki = pos / 7, kj = pos - (pos / 7) * 7;
  int poff = (ki * W_ + kj) * CI + c0;

  float a0 = 0.f, a1 = 0.f, a2 = 0.f, a3 = 0.f;
  float a4 = 0.f, a5 = 0.f, a6 = 0.f, a7 = 0.f;
  for (int j0 = 0; j0 < TOPM; j0 += 4) {
    float w_0 = tkw[trow + j0 + 0];
    float w_1 = tkw[trow + j0 + 1];
    float w_2 = tkw[trow + j0 + 2];
    float w_3 = tkw[trow + j0 + 3];
    int p_0 = tkp[trow + j0 + 0];
    int p_1 = tkp[trow + j0 + 1];
    int p_2 = tkp[trow + j0 + 2];
    int p_3 = tkp[trow + j0 + 3];
    const uint4 q0 = *(const uint4*)(B3 + p_0 + poff);
    const uint4 q1 = *(const uint4*)(B3 + p_1 + poff);
    const uint4 q2 = *(const uint4*)(B3 + p_2 + poff);
    const uint4 q3 = *(const uint4*)(B3 + p_3 + poff);
    a0 += w_0 * bflo(q0.x); a1 += w_0 * bfhi(q0.x); a2 += w_0 * bflo(q0.y); a3 += w_0 * bfhi(q0.y);
    a4 += w_0 * bflo(q0.z); a5 += w_0 * bfhi(q0.z); a6 += w_0 * bflo(q0.w); a7 += w_0 * bfhi(q0.w);
    a0 += w_1 * bflo(q1.x); a1 += w_1 * bfhi(q1.x); a2 += w_1 * bflo(q1.y); a3 += w_1 * bfhi(q1.y);
    a4 += w_1 * bflo(q1.z); a5 += w_1 * bfhi(q1.z); a6 += w_1 * bflo(q1.w); a7 += w_1 * bfhi(q1.w);
    a0 += w_2 * bflo(q2.x); a1 += w_2 * bfhi(q2.x); a2 += w_2 * bflo(q2.y); a3 += w_2 * bfhi(q2.y);
    a4 += w_2 * bflo(q2.z); a5 += w_2 * bfhi(q2.z); a6 += w_2 * bflo(q2.w); a7 += w_2 * bfhi(q2.w);
    a0 += w_3 * bflo(q3.x); a1 += w_3 * bfhi(q3.x); a2 += w_3 * bflo(q3.y); a3 += w_3 * bfhi(q3.y);
    a4 += w_3 * bflo(q3.z); a5 += w_3 * bfhi(q3.z); a6 += w_3 * bflo(q3.w); a7 += w_3 * bfhi(q3.w);
  }
  const float4 s40 = *(const float4*)(S3 + tid * 8);
  const float4 s41 = *(const float4*)(S3 + tid * 8 + 4);
  a0 += w0 * s40.x; a1 += w0 * s40.y; a2 += w0 * s40.z; a3 += w0 * s40.w;
  a4 += w0 * s41.x; a5 += w0 * s41.y; a6 += w0 * s41.z; a7 += w0 * s41.w;
  float* dst = agg + (size_t)l * D_ + tid * 8;
  *(float4*)(dst)     = make_float4(a0, a1, a2, a3);
  *(float4*)(dst + 4) = make_float4(a4, a5, a6, a7);
}

// -------- fold + mask divide + restore (16->64), batched -------------------------
__global__ __launch_bounds__(256) void k_fold(
    const int* __restrict__ flag, const float* __restrict__ ws,
    const float* __restrict__ agb, void* __restrict__ out,
    int b0, unsigned agstride_z)
{
  __shared__ float srw[CIN * CI];
  int tid = threadIdx.x;
  for (int i = tid; i < CIN * CI; i += 256) srw[i] = ws[RW_O + i];
  __syncthreads();

  int bz = blockIdx.y;
  int batch = b0 + bz;
  const float* agg = agb + (size_t)bz * agstride_z;

  int gid = blockIdx.x * 256 + tid;
  if (gid >= HW) return;
  int h = gid / W_;
  int w = gid % W_;

  int lh0 = (h >= KS - 1) ? ((h - (KS - 1) + (ST - 1)) >> 2) : 0;
  int lh1 = min(OH_ - 1, h >> 2);
  int lw0 = (w >= KS - 1) ? ((w - (KS - 1) + (ST - 1)) >> 2) : 0;
  int lw1 = min(OH_ - 1, w >> 2);

  float t[CI];
#pragma unroll
  for (int c = 0; c < CI; ++c) t[c] = 0.f;
  for (int lh = lh0; lh <= lh1; ++lh) {
    int ki = h - ST * lh;
    for (int lw = lw0; lw <= lw1; ++lw) {
      int kj = w - ST * lw;
      const float* pb = agg + (size_t)(lh * OH_ + lw) * D_ + (ki * KS + kj) * CI;
      float4 q0 = *(const float4*)(pb);
      float4 q1 = *(const float4*)(pb + 4);
      float4 q2 = *(const float4*)(pb + 8);
      float4 q3 = *(const float4*)(pb + 12);
      t[0] += q0.x; t[1] += q0.y; t[2] += q0.z; t[3] += q0.w;
      t[4] += q1.x; t[5] += q1.y; t[6] += q1.z; t[7] += q1.w;
      t[8] += q2.x; t[9] += q2.y; t[10] += q2.z; t[11] += q2.w;
      t[12] += q3.x; t[13] += q3.y; t[14] += q3.z; t[15] += q3.w;
    }
  }
  float cnt = (float)((lh1 - lh0 + 1) * (lw1 - lw0 + 1));
  float r[CI];
#pragma unroll
  for (int c = 0; c < CI; ++c) r[c] = t[c] / (cnt * ws[SM_O + c] + ws[SB_O + c] + 1e-8f);

  size_t ob = (size_t)batch * CIN * HW + (size_t)h * W_ + w;
  if (*flag) {
    float* of = (float*)out;
#pragma unroll
    for (int o = 0; o < CIN; ++o) {
      float s = ws[RB_O + o];
#pragma unroll
      for (int c = 0; c < CI; ++c) s += srw[o * CI + c] * r[c];
      of[ob + (size_t)o * HW] = s;
    }
  } else {
    bf16* of = (bf16*)out;
#pragma unroll
    for (int o = 0; o < CIN; ++o) {
      float s = ws[RB_O + o];
#pragma unroll
      for (int c = 0; c < CI; ++c) s += srw[o * CI + c] * r[c];
      of[ob + (size_t)o * HW] = __float2bfloat16(s);
    }
  }
}

extern "C" void kernel_launch(void* const* d_in, const int* in_sizes, int n_in,
                              void* d_out, int out_size, void* d_ws, size_t ws_size,
                              hipStream_t stream)
{
  const void* x    = d_in[0];
  const void* g_w  = d_in[1];
  const void* g_b  = d_in[2];
  const void* th_w = d_in[3];
  const void* th_b = d_in[4];
  const void* ph_w = d_in[5];
  const void* ph_b = d_in[6];
  const void* m_w  = d_in[7];
  const void* m_b  = d_in[8];
  const void* r_w  = d_in[9];
  const void* r_b  = d_in[10];

  float* W = (float*)d_ws;
  int* flag = (int*)d_ws;
  ushort_t* planes = (ushort_t*)(W + B1_O);
  ushort_t* b1h = planes;
  ushort_t* b1l = planes + (size_t)N1;
  ushort_t* b2h = planes + (size_t)2 * N1;
  ushort_t* b2l = planes + (size_t)3 * N1;
  ushort_t* b3  = planes + (size_t)4 * N1;   // bf16 plane, N1 ushorts
  float* s3 = W + S3_O;

  k_detect<<<1, 64, 0, stream>>>((const unsigned short*)x, flag);
  k_prep<<<1, 256, 0, stream>>>(flag, g_w, th_w, ph_w, g_b, th_b, ph_b,
                                m_w, m_b, r_w, r_b, W);

  if (ws_size >= FULL_BYTES) {
    ushort_t* xhh = (ushort_t*)(W + REG_O);    // bf16 hi/lo x planes, dead after conv
    ushort_t* xhl = xhh + (size_t)XHSZ;
    float* sc = W + REG_O;                     // 4 x SCSLOT, aliases x planes
    float* ag = W + REG_O + XHSZ;              // 4 x AGSZ
    float* tkw = W + B1_O + N1;                // b2h region (dead after k_score)
    int*   tkp = (int*)(W + B1_O + N1 + N1 / 2);
    k_hwc<<<dim3((B_ * HW + 63) / 64), 256, 0, stream>>>(flag, x, xhh, xhl);
    k_conv3<<<dim3((HW + 63) / 64, 1, B_), 256, 0, stream>>>(
        W, xhh, xhl, b1h, b1l, b2h, b2l, b3);
    k_colsum<<<dim3(B_, 49), 256, 0, stream>>>(b3, s3);
    k_score<<<dim3(16, 8, B_), 256, 0, stream>>>(b1h, b1l, b2h, b2l, sc, 0, SCSLOT);
    k_topk<<<dim3(L_, B_), 64, 0, stream>>>(sc, tkw, tkp, SCSLOT);
    k_pv<<<dim3(L_, B_), 128, 0, stream>>>(tkw, tkp, b3, s3, ag, 0, AGSZ);
    k_fold<<<dim3(64, B_), 256, 0, stream>>>(flag, W, ag, d_out, 0, AGSZ);
  } else if (ws_size >= MID_BYTES) {
    ushort_t* xhh = (ushort_t*)(W + REG_O);
    ushort_t* xhl = xhh + (size_t)XHSZ;
    float* sc = W + REG_O;
    float* ag = W + REG_O + SCSLOT;
    k_hwc<<<dim3((B_ * HW + 63) / 64), 256, 0, stream>>>(flag, x, xhh, xhl);
    k_conv3<<<dim3((HW + 63) / 64, 1, B_), 256, 0, stream>>>(
        W, xhh, xhl, b1h, b1l, b2h, b2l, b3);
    k_colsum<<<dim3(B_, 49), 256, 0, stream>>>(b3, s3);
    for (int b = 0; b < B_; ++b) {
      float* tkw = W + B1_O + N1 + (size_t)b * (HW * CI / 2);
      int*   tkp = (int*)(W + B1_O + N1 + N1 / 2 + (size_t)b * (HW * CI / 2));
      k_score<<<dim3(16, 8, 1), 256, 0, stream>>>(b1h, b1l, b2h, b2l, sc, b, 0);
      k_topk<<<dim3(L_, 1), 64, 0, stream>>>(sc, tkw, tkp, 0);
      k_pv<<<dim3(L_, 1), 128, 0, stream>>>(tkw, tkp, b3, s3, ag, b, 0);
      k_fold<<<dim3(64, 1), 256, 0, stream>>>(flag, W, ag, d_out, b, 0);
    }
  } else {
    float* sc = W + REG_O;
    float* ag = W + REG_O + SCSLOT;
    k_convF<<<dim3(4, 16, B_), dim3(32, 8, 1), 0, stream>>>(
        flag, x, g_w, g_b, th_w, th_b, ph_w, ph_b, b1h, b1l, b2h, b2l, b3);
    k_colsum<<<dim3(B_, 49), 256, 0, stream>>>(b3, s3);
    for (int b = 0; b < B_; ++b) {
      float* tkw = W + B1_O + N1 + (size_t)b * (HW * CI / 2);
      int*   tkp = (int*)(W + B1_O + N1 + N1 / 2 + (size_t)b * (HW * CI / 2));
      k_score<<<dim3(16, 8, 1), 256, 0, stream>>>(b1h, b1l, b2h, b2l, sc, b, 0);
      k_topk<<<dim3(L_, 1), 64, 0, stream>>>(sc, tkw, tkp, 0);
      k_pv<<<dim3(L_, 1), 128, 0, stream>>>(tkw, tkp, b3, s3, ag, b, 0);
      k_fold<<<dim3(64, 1), 256, 0, stream>>>(flag, W, ag, d_out, b, 0);
    }
  }
}

// Round 14
// 323.681 us; speedup vs baseline: 1.1407x; 1.0270x over previous
//
#include <hip/hip_runtime.h>
#include <hip/hip_bf16.h>

typedef __hip_bfloat16 bf16;
typedef unsigned short ushort_t;
typedef __attribute__((ext_vector_type(8))) __bf16 bfv8;
typedef __attribute__((ext_vector_type(16))) float f32x16;

#define B_   4
#define CIN  64
#define CI   16
#define H_   127
#define W_   127
#define HW   (H_*W_)
#define KS   7
#define ST   4
#define OH_  31
#define L_   961
#define D_   784
#define TOPM 100

// ---- workspace layout (float offsets) ----
#define N1   1032256          // B*HW*CI elements (one conv-out array)
#define WG_O 4
#define WT_O (WG_O + 9216)
#define WP_O (WT_O + 1024)
#define BG_O (WP_O + 1024)
#define BT_O (BG_O + 16)
#define BP_O (BT_O + 16)
#define SM_O (BP_O + 16)
#define SB_O (SM_O + 16)
#define RW_O (SB_O + 16)
#define RB_O (RW_O + 1024)
#define B1_O 12448
// planes at B1_O: b1h,b1l,b2h,b2l each N1 ushorts (2*N1 floats); b3 bf16 N1 ushorts
#define S3_O (B1_O + 3*N1)
#define WB_O (S3_O + B_*D_)   // conv MFMA B: wBh + wBl = 36864 floats
#define REG_O (WB_O + 36864)
#define XHSZ 4129024          // B*HW*64 ushorts per x plane (2 planes = XHSZ floats)
#define SROW 964              // padded Sc row stride
#define SCSLOT 926464
#define AGSZ 753424
#define TKROW 112
#define SLST 72               // LDS row stride in ushorts (conflict-free, measured r8)

#define FULL_BYTES ((size_t)(REG_O + XHSZ + 4*AGSZ) * 4)   // ~41.1 MB
#define MID_BYTES  ((size_t)(REG_O + XHSZ) * 4)            // ~29.1 MB

__device__ __forceinline__ float bf2f(bf16 v) { return __bfloat162float(v); }
__device__ __forceinline__ float bflo(unsigned u) { return __uint_as_float(u << 16); }
__device__ __forceinline__ float bfhi(unsigned u) { return __uint_as_float(u & 0xFFFF0000u); }

template <typename T> struct Ld;
template <> struct Ld<float> {
  static __device__ __forceinline__ float f(const void* p, int i) { return ((const float*)p)[i]; }
};
template <> struct Ld<bf16> {
  static __device__ __forceinline__ float f(const void* p, int i) { return bf2f(((const bf16*)p)[i]); }
};

__device__ __forceinline__ unsigned fmap(float f) {
  unsigned u = __float_as_uint(f);
  return (u & 0x80000000u) ? ~u : (u | 0x80000000u);
}
__device__ __forceinline__ float unfmap(unsigned kk) {
  unsigned u = (kk & 0x80000000u) ? (kk & 0x7fffffffu) : ~kk;
  return __uint_as_float(u);
}

// RNE fp32 -> bf16 bits, and hi/lo split
__device__ __forceinline__ ushort_t f2bf(float x) {
  unsigned u = __float_as_uint(x);
  return (ushort_t)((u + 0x7FFFu + ((u >> 16) & 1u)) >> 16);
}
__device__ __forceinline__ void splitbf(float x, ushort_t& h, ushort_t& l) {
  h = f2bf(x);
  float hf = __uint_as_float(((unsigned)h) << 16);
  l = f2bf(x - hf);
}

// -------- dtype detector: flag=1 -> fp32 buffers, flag=0 -> bf16 -----------------
__global__ void k_detect(const unsigned short* __restrict__ xh, int* __restrict__ flag) {
  int tid = threadIdx.x;  // 64
  int c = 0;
#pragma unroll
  for (int j = 0; j < 2; ++j) {
    unsigned u = xh[tid * 2 + j];
    unsigned e = (u >> 7) & 0xFF;
    if (e >= 134) c++;
  }
#pragma unroll
  for (int o = 32; o; o >>= 1) c += __shfl_down(c, o);
  if (tid == 0) *flag = (c >= 8) ? 1 : 0;
}

// -------- weight prep ------------------------------------------------------------
#define LDW(ptr, i) (f ? ((const float*)(ptr))[i] : bf2f(((const bf16*)(ptr))[i]))
__global__ __launch_bounds__(256) void k_prep(
    const int* __restrict__ flag,
    const void* g_w, const void* t_w, const void* p_w,
    const void* g_b, const void* t_b, const void* p_b,
    const void* m_w, const void* m_b, const void* r_w, const void* r_b,
    float* __restrict__ ws)
{
  int tid = threadIdx.x;
  int f = *flag;
  for (int i = tid; i < 9216; i += 256) {
    int o = i & 15, t = i >> 4, c = t & 63, tap = t >> 6;
    ws[WG_O + i] = LDW(g_w, (o * 64 + c) * 9 + tap);
  }
  for (int i = tid; i < 1024; i += 256) {
    int o = i & 15, c = i >> 4;
    ws[WT_O + i] = LDW(t_w, o * 64 + c);
    ws[WP_O + i] = LDW(p_w, o * 64 + c);
  }
  if (tid < 16) {
    ws[BG_O + tid] = LDW(g_b, tid);
    ws[BT_O + tid] = LDW(t_b, tid);
    ws[BP_O + tid] = LDW(p_b, tid);
    float s = 0.f;
    for (int c = 0; c < 64; ++c) s += LDW(m_w, tid * 64 + c);
    ws[SM_O + tid] = s;
    ws[SB_O + tid] = LDW(m_b, tid);
  }
  for (int i = tid; i < 1024; i += 256) ws[RW_O + i] = LDW(r_w, i);
  if (tid < 64) ws[RB_O + tid] = LDW(r_b, tid);
  // conv MFMA B, split hi/lo: wB[tap][col64][c64]
  ushort_t* wBh = (ushort_t*)(ws + WB_O);
  ushort_t* wBl = wBh + 9 * 64 * 64;
  for (int i = tid; i < 9 * 64 * 64; i += 256) {
    int c = i & 63, t = i >> 6, col = t & 63, tap = t >> 6;
    float v = 0.f;
    if (col < 16) v = LDW(g_w, (col * 64 + c) * 9 + tap);
    else if (col < 32) { if (tap == 4) v = LDW(t_w, (col - 16) * 64 + c); }
    else if (col < 48) { if (tap == 4) v = LDW(p_w, (col - 32) * 64 + c); }
    ushort_t h, l; splitbf(v, h, l);
    wBh[i] = h; wBl[i] = l;
  }
}

// -------- x [B,64,H,W] -> HWC bf16 hi/lo planes ----------------------------------
__global__ __launch_bounds__(256) void k_hwc(
    const int* __restrict__ flag, const void* __restrict__ x,
    ushort_t* __restrict__ xhh, ushort_t* __restrict__ xhl)
{
  __shared__ float tile[64][65];
  int pix0 = blockIdx.x * 64;
  int tid = threadIdx.x;
  int g = tid >> 6, p = tid & 63;
  int pix = pix0 + p;
  bool ok = pix < B_ * HW;
  int bb = ok ? pix / HW : 0;
  int r  = ok ? pix - bb * HW : 0;
  if (*flag) {
    const float* xf = (const float*)x;
    for (int c = g * 16; c < g * 16 + 16; ++c)
      tile[p][c] = ok ? xf[((size_t)bb * CIN + c) * HW + r] : 0.f;
  } else {
    const bf16* xb = (const bf16*)x;
    for (int c = g * 16; c < g * 16 + 16; ++c)
      tile[p][c] = ok ? bf2f(xb[((size_t)bb * CIN + c) * HW + r]) : 0.f;
  }
  __syncthreads();
  int c2 = tid & 63, pg = tid >> 6;
  for (int k = 0; k < 16; ++k) {
    int p2 = pg * 16 + k;
    int pix2 = pix0 + p2;
    if (pix2 < B_ * HW) {
      ushort_t h, l; splitbf(tile[p2][c2], h, l);
      xhh[(size_t)pix2 * 64 + c2] = h;
      xhl[(size_t)pix2 * 64 + c2] = l;
    }
  }
}

// -------- unified split-bf16 MFMA conv (r11-verified) ----------------------------
__global__ __launch_bounds__(256) void k_conv3(
    const float* __restrict__ ws,
    const ushort_t* __restrict__ xhh, const ushort_t* __restrict__ xhl,
    ushort_t* __restrict__ b1h, ushort_t* __restrict__ b1l,
    ushort_t* __restrict__ b2h, ushort_t* __restrict__ b2l,
    ushort_t* __restrict__ b3)
{
  __shared__ ushort_t sm[4][64 * SLST];
  int bz = blockIdx.z;
  int px0 = blockIdx.x * 64;
  int tid = threadIdx.x, lane = tid & 63, wv = tid >> 6;

  int pix = px0 + lane;
  bool pok = pix < HW;
  int ph = pok ? pix / W_ : 0;
  int pw = pok ? pix - ph * W_ : 0;
  const ushort_t* xplane = ((wv == 0) ? xhh : xhl) + (size_t)bz * HW * 64;
  const ushort_t* wBh = (const ushort_t*)(ws + WB_O);
  const ushort_t* bsrc = (wv == 2) ? wBh : (wBh + 9 * 64 * 64);
  ushort_t* drow = sm[wv] + lane * SLST;

  int fr = lane & 31, kh = (lane >> 5) << 3;
  int aoff = (((wv >> 1) << 5) + fr) * SLST + kh;
  int boff = (((wv & 1) << 5) + fr) * SLST + kh;

  f32x16 acc = {0.f,0.f,0.f,0.f,0.f,0.f,0.f,0.f,0.f,0.f,0.f,0.f,0.f,0.f,0.f,0.f};
  const int4 z4 = make_int4(0, 0, 0, 0);
  int4 v0 = z4, v1 = z4, v2 = z4, v3 = z4, v4 = z4, v5 = z4, v6 = z4, v7 = z4;

  if (wv < 2) {
    int hh = ph - 1, ww = pw - 1;
    if (pok && hh >= 0 && ww >= 0) {
      const int4* s = (const int4*)(xplane + (size_t)(hh * W_ + ww) * 64);
      v0 = s[0]; v1 = s[1]; v2 = s[2]; v3 = s[3]; v4 = s[4]; v5 = s[5]; v6 = s[6]; v7 = s[7];
    }
  } else {
    const int4* s = (const int4*)(bsrc + (size_t)lane * 64);
    v0 = s[0]; v1 = s[1]; v2 = s[2]; v3 = s[3]; v4 = s[4]; v5 = s[5]; v6 = s[6]; v7 = s[7];
  }

  for (int r = 0; r < 9; ++r) {
    __syncthreads();
    *(int4*)(drow + 0)  = v0;  *(int4*)(drow + 8)  = v1;
    *(int4*)(drow + 16) = v2;  *(int4*)(drow + 24) = v3;
    *(int4*)(drow + 32) = v4;  *(int4*)(drow + 40) = v5;
    *(int4*)(drow + 48) = v6;  *(int4*)(drow + 56) = v7;
    __syncthreads();
    if (r < 8) {
      int rn = r + 1;
      if (wv < 2) {
        int hh = ph + rn / 3 - 1, ww = pw + rn % 3 - 1;
        if (pok && (unsigned)hh < (unsigned)H_ && (unsigned)ww < (unsigned)W_) {
          const int4* s = (const int4*)(xplane + (size_t)(hh * W_ + ww) * 64);
          v0 = s[0]; v1 = s[1]; v2 = s[2]; v3 = s[3]; v4 = s[4]; v5 = s[5]; v6 = s[6]; v7 = s[7];
        } else {
          v0 = z4; v1 = z4; v2 = z4; v3 = z4; v4 = z4; v5 = z4; v6 = z4; v7 = z4;
        }
      } else {
        const int4* s = (const int4*)(bsrc + ((size_t)rn * 64 + lane) * 64);
        v0 = s[0]; v1 = s[1]; v2 = s[2]; v3 = s[3]; v4 = s[4]; v5 = s[5]; v6 = s[6]; v7 = s[7];
      }
    }
#pragma unroll
    for (int t = 0; t < 4; ++t) {
      bfv8 ah = *(const bfv8*)(sm[0] + aoff + t * 16);
      bfv8 al = *(const bfv8*)(sm[1] + aoff + t * 16);
      bfv8 bh = *(const bfv8*)(sm[2] + boff + t * 16);
      bfv8 bl = *(const bfv8*)(sm[3] + boff + t * 16);
      acc = __builtin_amdgcn_mfma_f32_32x32x16_bf16(al, bh, acc, 0, 0, 0);
      acc = __builtin_amdgcn_mfma_f32_32x32x16_bf16(ah, bl, acc, 0, 0, 0);
      acc = __builtin_amdgcn_mfma_f32_32x32x16_bf16(ah, bh, acc, 0, 0, 0);
    }
  }

  int nw = ((wv & 1) << 5) + fr;
  int mwb = (wv >> 1) << 5;
#pragma unroll
  for (int r = 0; r < 16; ++r) {
    int m = mwb + (r & 3) + ((r >> 2) << 3) + ((lane >> 5) << 2);
    int p2 = px0 + m;
    if (p2 >= HW) continue;
    size_t ob = ((size_t)bz * HW + p2) * 16;
    float val = acc[r];
    if (nw < 16) {
      ushort_t h2, l2; splitbf(val + ws[BG_O + nw], h2, l2);
      b1h[ob + nw] = h2; b1l[ob + nw] = l2;
    } else if (nw < 32) {
      int o = nw - 16; ushort_t h2, l2; splitbf(val + ws[BT_O + o], h2, l2);
      b2h[ob + o] = h2; b2l[ob + o] = l2;
    } else if (nw < 48) {
      int o = nw - 32; b3[ob + o] = f2bf(val + ws[BP_O + o]);
    }
  }
}

// -------- fallback conv (LOW tier), dtype-templated VALU -------------------------
template <typename T>
__device__ __forceinline__ void convF_body(
    const void* x, const void* g_w, const void* g_b,
    const void* t_w, const void* t_b, const void* p_w, const void* p_b,
    ushort_t* b1h, ushort_t* b1l, ushort_t* b2h, ushort_t* b2l, ushort_t* b3,
    float* sgw, float* stw, float* spw)
{
  int tid = threadIdx.y * 32 + threadIdx.x;
  for (int i = tid; i < CI * CIN * 9; i += 256) sgw[i] = Ld<T>::f(g_w, i);
  for (int i = tid; i < CI * CIN; i += 256) { stw[i] = Ld<T>::f(t_w, i); spw[i] = Ld<T>::f(p_w, i); }
  __syncthreads();

  int w = blockIdx.x * 32 + threadIdx.x;
  int h = blockIdx.y * 8 + threadIdx.y;
  int b = blockIdx.z;
  if (w >= W_ || h >= H_) return;

  float a1[CI], a2[CI], a3[CI];
#pragma unroll
  for (int o = 0; o < CI; ++o) { a1[o] = 0.f; a2[o] = 0.f; a3[o] = 0.f; }

  const size_t xb = (size_t)b * CIN * HW;
  for (int c = 0; c < CIN; ++c) {
    float xv[9];
#pragma unroll
    for (int dh = 0; dh < 3; ++dh) {
      int hh = h + dh - 1;
      bool rok = ((unsigned)hh < (unsigned)H_);
#pragma unroll
      for (int dw = 0; dw < 3; ++dw) {
        int ww = w + dw - 1;
        bool ok = rok && ((unsigned)ww < (unsigned)W_);
        xv[dh * 3 + dw] = ok ? Ld<T>::f(x, (int)(xb + (size_t)c * HW + hh * W_ + ww)) : 0.f;
      }
    }
    float xc = xv[4];
#pragma unroll
    for (int o = 0; o < CI; ++o) {
      const float* gg = &sgw[(o * CIN + c) * 9];
      float s = gg[0]*xv[0] + gg[1]*xv[1] + gg[2]*xv[2]
              + gg[3]*xv[3] + gg[4]*xv[4] + gg[5]*xv[5]
              + gg[6]*xv[6] + gg[7]*xv[7] + gg[8]*xv[8];
      a1[o] += s;
      a2[o] += stw[o * CIN + c] * xc;
      a3[o] += spw[o * CIN + c] * xc;
    }
  }
  size_t base = ((size_t)b * HW + h * W_ + w) * CI;
#pragma unroll
  for (int o = 0; o < CI; ++o) {
    float v1 = a1[o] + Ld<T>::f(g_b, o);
    float v2 = a2[o] + Ld<T>::f(t_b, o);
    ushort_t hh2, ll2;
    splitbf(v1, hh2, ll2); b1h[base + o] = hh2; b1l[base + o] = ll2;
    splitbf(v2, hh2, ll2); b2h[base + o] = hh2; b2l[base + o] = ll2;
    b3[base + o] = f2bf(a3[o] + Ld<T>::f(p_b, o));
  }
}

__global__ __launch_bounds__(256) void k_convF(
    const int* __restrict__ flag, const void* x,
    const void* g_w, const void* g_b, const void* t_w, const void* t_b,
    const void* p_w, const void* p_b,
    ushort_t* __restrict__ b1h, ushort_t* __restrict__ b1l,
    ushort_t* __restrict__ b2h, ushort_t* __restrict__ b2l,
    ushort_t* __restrict__ b3)
{
  __shared__ float sgw[CI * CIN * 9];
  __shared__ float stw[CI * CIN];
  __shared__ float spw[CI * CIN];
  if (*flag) convF_body<float>(x, g_w, g_b, t_w, t_b, p_w, p_b, b1h, b1l, b2h, b2l, b3, sgw, stw, spw);
  else       convF_body<bf16 >(x, g_w, g_b, t_w, t_b, p_w, p_b, b1h, b1l, b2h, b2l, b3, sgw, stw, spw);
}

// -------- S3[b, pos*16+c] = sum over patches of b3 (bf16 src, fp32 acc) ----------
__global__ __launch_bounds__(256) void k_colsum(const ushort_t* __restrict__ b3, float* __restrict__ S3)
{
  __shared__ float red[16][17];
  int b = blockIdx.x, pos = blockIdx.y;
  int ki = pos / 7, kj = pos % 7;
  int c = threadIdx.x & 15, chunk = threadIdx.x >> 4;
  const ushort_t* B3 = b3 + (size_t)b * HW * CI;
  float s = 0.f;
  for (int l = chunk; l < L_; l += 16) {
    int lh = l / OH_, lw = l % OH_;
    s += bflo((unsigned)B3[((lh * ST + ki) * W_ + lw * ST + kj) * CI + c]);
  }
  red[chunk][c] = s;
  __syncthreads();
  if (threadIdx.x < 16) {
    float t = 0.f;
#pragma unroll
    for (int k = 0; k < 16; ++k) t += red[k][threadIdx.x];
    S3[(b * 49 + pos) * 16 + threadIdx.x] = t;
  }
}

// -------- score GEMM via split-bf16 MFMA, 128x64 tile (r12-verified) -------------
__global__ __launch_bounds__(256) void k_score(
    const ushort_t* __restrict__ b1h, const ushort_t* __restrict__ b1l,
    const ushort_t* __restrict__ b2h, const ushort_t* __restrict__ b2l,
    float* __restrict__ scb, int b0, unsigned scstride_z)
{
  __shared__ ushort_t sAh[128 * SLST], sAl[128 * SLST];
  __shared__ ushort_t sBh[64 * SLST],  sBl[64 * SLST];
  int batch = b0 + blockIdx.z;
  size_t poff_g = (size_t)batch * HW * CI;
  float* Sc = scb + (size_t)blockIdx.z * scstride_z;

  int tid = threadIdx.x;
  int m0 = blockIdx.y * 128, n0 = blockIdx.x * 64;
  int lane = tid & 63;
  int wv = tid >> 6;

  int base_mn = (wv < 2) ? m0 : n0;
  int srow0 = base_mn + lane;       if (srow0 > L_ - 1) srow0 = L_ - 1;
  int srow1 = base_mn + lane + 64;  if (srow1 > L_ - 1) srow1 = L_ - 1;
  int slh0 = srow0 / OH_, slw0 = srow0 - slh0 * OH_;
  int slh1 = srow1 / OH_, slw1 = srow1 - slh1 * OH_;
  int sbase0 = (slh0 * ST) * W_ + slw0 * ST;
  int sbase1 = (slh1 * ST) * W_ + slw1 * ST;
  const ushort_t* splane = (wv == 0) ? (b1h + poff_g) : (wv == 1) ? (b1l + poff_g)
                          : (wv == 2) ? (b2h + poff_g) : (b2l + poff_g);
  ushort_t* dplane = (wv == 0) ? sAh : (wv == 1) ? sAl : (wv == 2) ? sBh : sBl;
  ushort_t* drow0 = dplane + lane * SLST;
  ushort_t* drow1 = dplane + (lane + 64) * SLST;   // only written when wv<2

  int fr = lane & 31;
  int kh = (lane >> 5) << 3;
  int mt = (wv >> 1) << 1;                         // first m-subtile: 0 or 2
  int aoff0 = (mt * 32 + fr) * SLST + kh;
  int aoff1 = ((mt + 1) * 32 + fr) * SLST + kh;
  int boff  = (((wv & 1) << 5) + fr) * SLST + kh;

  f32x16 acc0 = {0.f,0.f,0.f,0.f,0.f,0.f,0.f,0.f,0.f,0.f,0.f,0.f,0.f,0.f,0.f,0.f};
  f32x16 acc1 = {0.f,0.f,0.f,0.f,0.f,0.f,0.f,0.f,0.f,0.f,0.f,0.f,0.f,0.f,0.f,0.f};

  const int4 z4 = make_int4(0, 0, 0, 0);
  int4 v0, v1, v2, v3, v4, v5, v6, v7;
  int4 u0 = z4, u1 = z4, u2 = z4, u3 = z4, u4 = z4, u5 = z4, u6 = z4, u7 = z4;
  {
    const int4* s0 = (const int4*)(splane + (size_t)sbase0 * 16);
    v0 = s0[0]; v1 = s0[1]; v2 = s0[2]; v3 = s0[3];
    v4 = s0[4]; v5 = s0[5]; v6 = s0[6]; v7 = s0[7];
    if (wv < 2) {
      const int4* s1 = (const int4*)(splane + (size_t)sbase1 * 16);
      u0 = s1[0]; u1 = s1[1]; u2 = s1[2]; u3 = s1[3];
      u4 = s1[4]; u5 = s1[5]; u6 = s1[6]; u7 = s1[7];
    }
  }

  for (int r = 0; r < 14; ++r) {
    int half = r & 1;
    __syncthreads();
    *(int4*)(drow0 + 0)  = v0;  *(int4*)(drow0 + 8)  = v1;
    *(int4*)(drow0 + 16) = v2;  *(int4*)(drow0 + 24) = v3;
    *(int4*)(drow0 + 32) = v4;  *(int4*)(drow0 + 40) = v5;
    if (!half) { *(int4*)(drow0 + 48) = v6; *(int4*)(drow0 + 56) = v7; }
    if (wv < 2) {
      *(int4*)(drow1 + 0)  = u0;  *(int4*)(drow1 + 8)  = u1;
      *(int4*)(drow1 + 16) = u2;  *(int4*)(drow1 + 24) = u3;
      *(int4*)(drow1 + 32) = u4;  *(int4*)(drow1 + 40) = u5;
      if (!half) { *(int4*)(drow1 + 48) = u6; *(int4*)(drow1 + 56) = u7; }
    }
    __syncthreads();
    if (r < 13) {
      int rn = r + 1;
      int nki = rn >> 1, nkj0 = (rn & 1) * 4;
      const int4* s0 = (const int4*)(splane + (size_t)(sbase0 + nki * W_ + nkj0) * 16);
      v0 = s0[0]; v1 = s0[1]; v2 = s0[2]; v3 = s0[3]; v4 = s0[4]; v5 = s0[5];
      if (!(rn & 1)) { v6 = s0[6]; v7 = s0[7]; }
      if (wv < 2) {
        const int4* s1 = (const int4*)(splane + (size_t)(sbase1 + nki * W_ + nkj0) * 16);
        u0 = s1[0]; u1 = s1[1]; u2 = s1[2]; u3 = s1[3]; u4 = s1[4]; u5 = s1[5];
        if (!(rn & 1)) { u6 = s1[6]; u7 = s1[7]; }
      }
    }
    if (!half) {
#pragma unroll
      for (int t = 0; t < 4; ++t) {
        bfv8 ah0 = *(const bfv8*)(sAh + aoff0 + t * 16);
        bfv8 al0 = *(const bfv8*)(sAl + aoff0 + t * 16);
        bfv8 ah1 = *(const bfv8*)(sAh + aoff1 + t * 16);
        bfv8 al1 = *(const bfv8*)(sAl + aoff1 + t * 16);
        bfv8 bh  = *(const bfv8*)(sBh + boff + t * 16);
        bfv8 bl  = *(const bfv8*)(sBl + boff + t * 16);
        acc0 = __builtin_amdgcn_mfma_f32_32x32x16_bf16(al0, bh, acc0, 0, 0, 0);
        acc0 = __builtin_amdgcn_mfma_f32_32x32x16_bf16(ah0, bl, acc0, 0, 0, 0);
        acc0 = __builtin_amdgcn_mfma_f32_32x32x16_bf16(ah0, bh, acc0, 0, 0, 0);
        acc1 = __builtin_amdgcn_mfma_f32_32x32x16_bf16(al1, bh, acc1, 0, 0, 0);
        acc1 = __builtin_amdgcn_mfma_f32_32x32x16_bf16(ah1, bl, acc1, 0, 0, 0);
        acc1 = __builtin_amdgcn_mfma_f32_32x32x16_bf16(ah1, bh, acc1, 0, 0, 0);
      }
    } else {
#pragma unroll
      for (int t = 0; t < 3; ++t) {
        bfv8 ah0 = *(const bfv8*)(sAh + aoff0 + t * 16);
        bfv8 al0 = *(const bfv8*)(sAl + aoff0 + t * 16);
        bfv8 ah1 = *(const bfv8*)(sAh + aoff1 + t * 16);
        bfv8 al1 = *(const bfv8*)(sAl + aoff1 + t * 16);
        bfv8 bh  = *(const bfv8*)(sBh + boff + t * 16);
        bfv8 bl  = *(const bfv8*)(sBl + boff + t * 16);
        acc0 = __builtin_amdgcn_mfma_f32_32x32x16_bf16(al0, bh, acc0, 0, 0, 0);
        acc0 = __builtin_amdgcn_mfma_f32_32x32x16_bf16(ah0, bl, acc0, 0, 0, 0);
        acc0 = __builtin_amdgcn_mfma_f32_32x32x16_bf16(ah0, bh, acc0, 0, 0, 0);
        acc1 = __builtin_amdgcn_mfma_f32_32x32x16_bf16(al1, bh, acc1, 0, 0, 0);
        acc1 = __builtin_amdgcn_mfma_f32_32x32x16_bf16(ah1, bl, acc1, 0, 0, 0);
        acc1 = __builtin_amdgcn_mfma_f32_32x32x16_bf16(ah1, bh, acc1, 0, 0, 0);
      }
    }
  }

  int nw = n0 + ((wv & 1) << 5) + fr;
  if (nw < L_) {
    int mw0 = m0 + mt * 32;
#pragma unroll
    for (int r = 0; r < 16; ++r) {
      int m = mw0 + (r & 3) + ((r >> 2) << 3) + ((lane >> 5) << 2);
      if (m < L_) Sc[(size_t)m * SROW + nw] = acc0[r];
    }
    int mw1 = m0 + (mt + 1) * 32;
#pragma unroll
    for (int r = 0; r < 16; ++r) {
      int m = mw1 + (r & 3) + ((r >> 2) << 3) + ((lane >> 5) << 2);
      if (m < L_) Sc[(size_t)m * SROW + nw] = acc1[r];
    }
  }
}

// -------- top-100 + softmax weights: 4 rows per block (1 wave each) --------------
__global__ __launch_bounds__(256) void k_topk(
    const float* __restrict__ scb, float* __restrict__ tkw, int* __restrict__ tkp,
    unsigned scstride_z)
{
  __shared__ float swv[4][TOPM];
  __shared__ int spx[4][TOPM];
  int tid = threadIdx.x;
  int wvi = tid >> 6, lane = tid & 63;
  int l = blockIdx.x * 4 + wvi;
  if (l > L_ - 1) l = L_ - 1;        // clamp: duplicate rows write identical data
  int bz = blockIdx.y;
  const float4* row4 = (const float4*)(scb + (size_t)bz * scstride_z + (size_t)l * SROW);
  int trow = (bz * L_ + l) * TKROW;

  unsigned k[16];
#pragma unroll
  for (int q = 0; q < 4; ++q) {
    float4 v = row4[q * 64 + lane];
    int ib = (q * 64 + lane) * 4;
    k[q * 4 + 0] = (ib + 0 < L_) ? fmap(v.x) : 0u;
    k[q * 4 + 1] = (ib + 1 < L_) ? fmap(v.y) : 0u;
    k[q * 4 + 2] = (ib + 2 < L_) ? fmap(v.z) : 0u;
    k[q * 4 + 3] = (ib + 3 < L_) ? fmap(v.w) : 0u;
  }

  unsigned mk = 0;
#pragma unroll
  for (int r = 0; r < 16; ++r) mk = max(mk, k[r]);
#pragma unroll
  for (int o = 32; o; o >>= 1) mk = max(mk, (unsigned)__shfl_down((int)mk, o));
  mk = (unsigned)__shfl((int)mk, 0);
  float vmax = unfmap(mk);

  unsigned alive = 0xFFFFu;
  unsigned prefix = 0; int base = 0;
  for (int bit = 30; bit >= 0; bit -= 2) {
    int c1 = 0, c2 = 0, c3 = 0;
#pragma unroll
    for (int r = 0; r < 16; ++r) {
      if ((alive >> r) & 1) {
        unsigned f = (k[r] >> bit) & 3u;
        c3 += (f == 3); c2 += (f >= 2); c1 += (f >= 1);
      }
    }
    int p = c3 | (c2 << 10) | (c1 << 20);
#pragma unroll
    for (int o = 32; o; o >>= 1) p += __shfl_down(p, o);
    p = __shfl(p, 0);
    int n3 = p & 1023, n2 = (p >> 10) & 1023, n1 = (p >> 20) & 1023;
    unsigned ch;
    if (base + n3 >= TOPM) ch = 3;
    else if (base + n2 >= TOPM) { ch = 2; base += n3; }
    else if (base + n1 >= TOPM) { ch = 1; base += n2; }
    else { ch = 0; base += n1; }
    prefix |= ch << bit;
#pragma unroll
    for (int r = 0; r < 16; ++r) {
      if ((alive >> r) & 1) {
        unsigned f = (k[r] >> bit) & 3u;
        if (f != ch) alive &= ~(1u << r);
      }
    }
  }
  int nA = base;
  int needT = TOPM - nA;

  int cA = 0, cT = 0;
#pragma unroll
  for (int r = 0; r < 16; ++r) { cA += (k[r] > prefix); cT += (k[r] == prefix); }
  int pk = cA | (cT << 16);
  int incl = pk;
#pragma unroll
  for (int o = 1; o < 64; o <<= 1) { int t = __shfl_up(incl, o); if (lane >= o) incl += t; }
  int excl = incl - pk;
  int tA = excl & 0xFFFF, tT = excl >> 16;

  float M = fmaxf(10.f * vmax, 0.f);
  float e0 = expf(-M);
  float z = 0.f;
#pragma unroll
  for (int r = 0; r < 16; ++r) {
    unsigned kk = k[r];
    int slot = -1;
    if (kk > prefix) slot = tA++;
    else if (kk == prefix) { if (tT < needT) slot = nA + tT; tT++; }
    if (slot >= 0) {
      float v = unfmap(kk);
      float wv = expf(10.f * v - M);
      swv[wvi][slot] = wv; z += wv;
      int gi = 256 * (r >> 2) + 4 * lane + (r & 3);
      int lh = gi / OH_, lw = gi - lh * OH_;
      spx[wvi][slot] = ((lh * ST) * W_ + lw * ST) * CI;
    }
  }
#pragma unroll
  for (int o = 32; o; o >>= 1) z += __shfl_down(z, o);
  z = __shfl(z, 0);
  float Z = z + (float)(L_ - TOPM) * e0;
  float invZ = 1.f / Z;
  float w0 = e0 / Z;
  __syncthreads();
#pragma unroll
  for (int s0 = 0; s0 < 2; ++s0) {
    int s = lane + 64 * s0;
    if (s < TOPM) {
      tkw[trow + s] = swv[wvi][s] * invZ - w0;
      tkp[trow + s] = spx[wvi][s];
    }
  }
  if (lane == 0) tkw[trow + TOPM] = w0;
}

// -------- PV gather (bf16 b3, uint4 full-line): 98 lanes x 8 channels ------------
__global__ __launch_bounds__(128) void k_pv(
    const float* __restrict__ tkw, const int* __restrict__ tkp,
    const ushort_t* __restrict__ b3, const float* __restrict__ s3,
    float* __restrict__ agb, int b0, unsigned agstride_z)
{
  int l = blockIdx.x, bz = blockIdx.y;
  int batch = b0 + bz;
  int trow = (bz * L_ + l) * TKROW;
  const ushort_t* B3 = b3 + (size_t)batch * HW * CI;
  const float* S3 = s3 + (size_t)batch * D_;
  float* agg = agb + (size_t)bz * agstride_z;
  int tid = threadIdx.x;
  if (tid >= 98) return;

  float w0 = tkw[trow + TOPM];
  int pos = tid >> 1;
  int c0 = (tid & 1) << 3;                 // 0 or 8
  int ki = pos / 7, kj = pos - (pos / 7) * 7;
  int poff = (ki * W_ + kj) * CI + c0;

  float a0 = 0.f, a1 = 0.f, a2 = 0.f, a3 = 0.f;
  float a4 = 0.f, a5 = 0.f, a6 = 0.f, a7 = 0.f;
  for (int j0 = 0; j0 < TOPM; j0 += 4) {
    float w_0 = tkw[trow + j0 + 0];
    float w_1 = tkw[trow + j0 + 1];
    float w_2 = tkw[trow + j0 + 2];
    float w_3 = tkw[trow + j0 + 3];
    int p_0 = tkp[trow + j0 + 0];
    int p_1 = tkp[trow + j0 + 1];
    int p_2 = tkp[trow + j0 + 2];
    int p_3 = tkp[trow + j0 + 3];
    const uint4 q0 = *(const uint4*)(B3 + p_0 + poff);
    const uint4 q1 = *(const uint4*)(B3 + p_1 + poff);
    const uint4 q2 = *(const uint4*)(B3 + p_2 + poff);
    const uint4 q3 = *(const uint4*)(B3 + p_3 + poff);
    a0 += w_0 * bflo(q0.x); a1 += w_0 * bfhi(q0.x); a2 += w_0 * bflo(q0.y); a3 += w_0 * bfhi(q0.y);
    a4 += w_0 * bflo(q0.z); a5 += w_0 * bfhi(q0.z); a6 += w_0 * bflo(q0.w); a7 += w_0 * bfhi(q0.w);
    a0 += w_1 * bflo(q1.x); a1 += w_1 * bfhi(q1.x); a2 += w_1 * bflo(q1.y); a3 += w_1 * bfhi(q1.y);
    a4 += w_1 * bflo(q1.z); a5 += w_1 * bfhi(q1.z); a6 += w_1 * bflo(q1.w); a7 += w_1 * bfhi(q1.w);
    a0 += w_2 * bflo(q2.x); a1 += w_2 * bfhi(q2.x); a2 += w_2 * bflo(q2.y); a3 += w_2 * bfhi(q2.y);
    a4 += w_2 * bflo(q2.z); a5 += w_2 * bfhi(q2.z); a6 += w_2 * bflo(q2.w); a7 += w_2 * bfhi(q2.w);
    a0 += w_3 * bflo(q3.x); a1 += w_3 * bfhi(q3.x); a2 += w_3 * bflo(q3.y); a3 += w_3 * bfhi(q3.y);
    a4 += w_3 * bflo(q3.z); a5 += w_3 * bfhi(q3.z); a6 += w_3 * bflo(q3.w); a7 += w_3 * bfhi(q3.w);
  }
  const float4 s40 = *(const float4*)(S3 + tid * 8);
  const float4 s41 = *(const float4*)(S3 + tid * 8 + 4);
  a0 += w0 * s40.x; a1 += w0 * s40.y; a2 += w0 * s40.z; a3 += w0 * s40.w;
  a4 += w0 * s41.x; a5 += w0 * s41.y; a6 += w0 * s41.z; a7 += w0 * s41.w;
  float* dst = agg + (size_t)l * D_ + tid * 8;
  *(float4*)(dst)     = make_float4(a0, a1, a2, a3);
  *(float4*)(dst + 4) = make_float4(a4, a5, a6, a7);
}

// -------- fold + mask divide + restore (16->64), batched -------------------------
__global__ __launch_bounds__(256) void k_fold(
    const int* __restrict__ flag, const float* __restrict__ ws,
    const float* __restrict__ agb, void* __restrict__ out,
    int b0, unsigned agstride_z)
{
  __shared__ float srw[CIN * CI];
  int tid = threadIdx.x;
  for (int i = tid; i < CIN * CI; i += 256) srw[i] = ws[RW_O + i];
  __syncthreads();

  int bz = blockIdx.y;
  int batch = b0 + bz;
  const float* agg = agb + (size_t)bz * agstride_z;

  int gid = blockIdx.x * 256 + tid;
  if (gid >= HW) return;
  int h = gid / W_;
  int w = gid % W_;

  int lh0 = (h >= KS - 1) ? ((h - (KS - 1) + (ST - 1)) >> 2) : 0;
  int lh1 = min(OH_ - 1, h >> 2);
  int lw0 = (w >= KS - 1) ? ((w - (KS - 1) + (ST - 1)) >> 2) : 0;
  int lw1 = min(OH_ - 1, w >> 2);

  float t[CI];
#pragma unroll
  for (int c = 0; c < CI; ++c) t[c] = 0.f;
  for (int lh = lh0; lh <= lh1; ++lh) {
    int ki = h - ST * lh;
    for (int lw = lw0; lw <= lw1; ++lw) {
      int kj = w - ST * lw;
      const float* pb = agg + (size_t)(lh * OH_ + lw) * D_ + (ki * KS + kj) * CI;
      float4 q0 = *(const float4*)(pb);
      float4 q1 = *(const float4*)(pb + 4);
      float4 q2 = *(const float4*)(pb + 8);
      float4 q3 = *(const float4*)(pb + 12);
      t[0] += q0.x; t[1] += q0.y; t[2] += q0.z; t[3] += q0.w;
      t[4] += q1.x; t[5] += q1.y; t[6] += q1.z; t[7] += q1.w;
      t[8] += q2.x; t[9] += q2.y; t[10] += q2.z; t[11] += q2.w;
      t[12] += q3.x; t[13] += q3.y; t[14] += q3.z; t[15] += q3.w;
    }
  }
  float cnt = (float)((lh1 - lh0 + 1) * (lw1 - lw0 + 1));
  float r[CI];
#pragma unroll
  for (int c = 0; c < CI; ++c) r[c] = t[c] / (cnt * ws[SM_O + c] + ws[SB_O + c] + 1e-8f);

  size_t ob = (size_t)batch * CIN * HW + (size_t)h * W_ + w;
  if (*flag) {
    float* of = (float*)out;
#pragma unroll
    for (int o = 0; o < CIN; ++o) {
      float s = ws[RB_O + o];
#pragma unroll
      for (int c = 0; c < CI; ++c) s += srw[o * CI + c] * r[c];
      of[ob + (size_t)o * HW] = s;
    }
  } else {
    bf16* of = (bf16*)out;
#pragma unroll
    for (int o = 0; o < CIN; ++o) {
      float s = ws[RB_O + o];
#pragma unroll
      for (int c = 0; c < CI; ++c) s += srw[o * CI + c] * r[c];
      of[ob + (size_t)o * HW] = __float2bfloat16(s);
    }
  }
}

extern "C" void kernel_launch(void* const* d_in, const int* in_sizes, int n_in,
                              void* d_out, int out_size, void* d_ws, size_t ws_size,
                              hipStream_t stream)
{
  const void* x    = d_in[0];
  const void* g_w  = d_in[1];
  const void* g_b  = d_in[2];
  const void* th_w = d_in[3];
  const void* th_b = d_in[4];
  const void* ph_w = d_in[5];
  const void* ph_b = d_in[6];
  const void* m_w  = d_in[7];
  const void* m_b  = d_in[8];
  const void* r_w  = d_in[9];
  const void* r_b  = d_in[10];

  float* W = (float*)d_ws;
  int* flag = (int*)d_ws;
  ushort_t* planes = (ushort_t*)(W + B1_O);
  ushort_t* b1h = planes;
  ushort_t* b1l = planes + (size_t)N1;
  ushort_t* b2h = planes + (size_t)2 * N1;
  ushort_t* b2l = planes + (size_t)3 * N1;
  ushort_t* b3  = planes + (size_t)4 * N1;   // bf16 plane, N1 ushorts
  float* s3 = W + S3_O;

  k_detect<<<1, 64, 0, stream>>>((const unsigned short*)x, flag);
  k_prep<<<1, 256, 0, stream>>>(flag, g_w, th_w, ph_w, g_b, th_b, ph_b,
                                m_w, m_b, r_w, r_b, W);

  if (ws_size >= FULL_BYTES) {
    ushort_t* xhh = (ushort_t*)(W + REG_O);    // bf16 hi/lo x planes, dead after conv
    ushort_t* xhl = xhh + (size_t)XHSZ;
    float* sc = W + REG_O;                     // 4 x SCSLOT, aliases x planes
    float* ag = W + REG_O + XHSZ;              // 4 x AGSZ
    float* tkw = W + B1_O + N1;                // b2h region (dead after k_score)
    int*   tkp = (int*)(W + B1_O + N1 + N1 / 2);
    k_hwc<<<dim3((B_ * HW + 63) / 64), 256, 0, stream>>>(flag, x, xhh, xhl);
    k_conv3<<<dim3((HW + 63) / 64, 1, B_), 256, 0, stream>>>(
        W, xhh, xhl, b1h, b1l, b2h, b2l, b3);
    k_colsum<<<dim3(B_, 49), 256, 0, stream>>>(b3, s3);
    k_score<<<dim3(16, 8, B_), 256, 0, stream>>>(b1h, b1l, b2h, b2l, sc, 0, SCSLOT);
    k_topk<<<dim3((L_ + 3) / 4, B_), 256, 0, stream>>>(sc, tkw, tkp, SCSLOT);
    k_pv<<<dim3(L_, B_), 128, 0, stream>>>(tkw, tkp, b3, s3, ag, 0, AGSZ);
    k_fold<<<dim3(64, B_), 256, 0, stream>>>(flag, W, ag, d_out, 0, AGSZ);
  } else if (ws_size >= MID_BYTES) {
    ushort_t* xhh = (ushort_t*)(W + REG_O);
    ushort_t* xhl = xhh + (size_t)XHSZ;
    float* sc = W + REG_O;
    float* ag = W + REG_O + SCSLOT;
    k_hwc<<<dim3((B_ * HW + 63) / 64), 256, 0, stream>>>(flag, x, xhh, xhl);
    k_conv3<<<dim3((HW + 63) / 64, 1, B_), 256, 0, stream>>>(
        W, xhh, xhl, b1h, b1l, b2h, b2l, b3);
    k_colsum<<<dim3(B_, 49), 256, 0, stream>>>(b3, s3);
    for (int b = 0; b < B_; ++b) {
      float* tkw = W + B1_O + N1 + (size_t)b * (HW * CI / 2);
      int*   tkp = (int*)(W + B1_O + N1 + N1 / 2 + (size_t)b * (HW * CI / 2));
      k_score<<<dim3(16, 8, 1), 256, 0, stream>>>(b1h, b1l, b2h, b2l, sc, b, 0);
      k_topk<<<dim3((L_ + 3) / 4, 1), 256, 0, stream>>>(sc, tkw, tkp, 0);
      k_pv<<<dim3(L_, 1), 128, 0, stream>>>(tkw, tkp, b3, s3, ag, b, 0);
      k_fold<<<dim3(64, 1), 256, 0, stream>>>(flag, W, ag, d_out, b, 0);
    }
  } else {
    float* sc = W + REG_O;
    float* ag = W + REG_O + SCSLOT;
    k_convF<<<dim3(4, 16, B_), dim3(32, 8, 1), 0, stream>>>(
        flag, x, g_w, g_b, th_w, th_b, ph_w, ph_b, b1h, b1l, b2h, b2l, b3);
    k_colsum<<<dim3(B_, 49), 256, 0, stream>>>(b3, s3);
    for (int b = 0; b < B_; ++b) {
      float* tkw = W + B1_O + N1 + (size_t)b * (HW * CI / 2);
      int*   tkp = (int*)(W + B1_O + N1 + N1 / 2 + (size_t)b * (HW * CI / 2));
      k_score<<<dim3(16, 8, 1), 256, 0, stream>>>(b1h, b1l, b2h, b2l, sc, b, 0);
      k_topk<<<dim3((L_ + 3) / 4, 1), 256, 0, stream>>>(sc, tkw, tkp, 0);
      k_pv<<<dim3(L_, 1), 128, 0, stream>>>(tkw, tkp, b3, s3, ag, b, 0);
      k_fold<<<dim3(64, 1), 256, 0, stream>>>(flag, W, ag, d_out, b, 0);
    }
  }
}

// Round 15
// 322.518 us; speedup vs baseline: 1.1448x; 1.0036x over previous
//
#include <hip/hip_runtime.h>
#include <hip/hip_bf16.h>

typedef __hip_bfloat16 bf16;
typedef unsigned short ushort_t;
typedef __attribute__((ext_vector_type(8))) __bf16 bfv8;
typedef __attribute__((ext_vector_type(16))) float f32x16;

#define B_   4
#define CIN  64
#define CI   16
#define H_   127
#define W_   127
#define HW   (H_*W_)
#define KS   7
#define ST   4
#define OH_  31
#define L_   961
#define D_   784
#define TOPM 100

// ---- workspace layout (float offsets) ----
#define N1   1032256          // B*HW*CI elements (one conv-out array)
#define WG_O 4
#define WT_O (WG_O + 9216)
#define WP_O (WT_O + 1024)
#define BG_O (WP_O + 1024)
#define BT_O (BG_O + 16)
#define BP_O (BT_O + 16)
#define SM_O (BP_O + 16)
#define SB_O (SM_O + 16)
#define RW_O (SB_O + 16)
#define RB_O (RW_O + 1024)
#define B1_O 12448
// planes at B1_O: b1h,b1l,b2h,b2l each N1 ushorts (2*N1 floats); b3 bf16 N1 ushorts
#define S3_O (B1_O + 3*N1)
#define WB_O (S3_O + B_*D_)   // conv MFMA B: wBh + wBl = 36864 floats
#define REG_O (WB_O + 36864)
#define XHSZ 4129024          // B*HW*64 ushorts per x plane (2 planes = XHSZ floats)
#define SROW 964              // padded Sc row stride
#define SCSLOT 926464
#define AGSZ 753424
#define TKROW 112
#define SLST 72               // LDS row stride in ushorts (conflict-free, measured r8)

#define FULL_BYTES ((size_t)(REG_O + XHSZ + 4*AGSZ) * 4)   // ~41.1 MB
#define MID_BYTES  ((size_t)(REG_O + XHSZ) * 4)            // ~29.1 MB

__device__ __forceinline__ float bf2f(bf16 v) { return __bfloat162float(v); }
__device__ __forceinline__ float bflo(unsigned u) { return __uint_as_float(u << 16); }
__device__ __forceinline__ float bfhi(unsigned u) { return __uint_as_float(u & 0xFFFF0000u); }

template <typename T> struct Ld;
template <> struct Ld<float> {
  static __device__ __forceinline__ float f(const void* p, int i) { return ((const float*)p)[i]; }
};
template <> struct Ld<bf16> {
  static __device__ __forceinline__ float f(const void* p, int i) { return bf2f(((const bf16*)p)[i]); }
};

__device__ __forceinline__ unsigned fmap(float f) {
  unsigned u = __float_as_uint(f);
  return (u & 0x80000000u) ? ~u : (u | 0x80000000u);
}
__device__ __forceinline__ float unfmap(unsigned kk) {
  unsigned u = (kk & 0x80000000u) ? (kk & 0x7fffffffu) : ~kk;
  return __uint_as_float(u);
}

// RNE fp32 -> bf16 bits, and hi/lo split
__device__ __forceinline__ ushort_t f2bf(float x) {
  unsigned u = __float_as_uint(x);
  return (ushort_t)((u + 0x7FFFu + ((u >> 16) & 1u)) >> 16);
}
__device__ __forceinline__ void splitbf(float x, ushort_t& h, ushort_t& l) {
  h = f2bf(x);
  float hf = __uint_as_float(((unsigned)h) << 16);
  l = f2bf(x - hf);
}

// -------- dtype detector: flag=1 -> fp32 buffers, flag=0 -> bf16 -----------------
__global__ void k_detect(const unsigned short* __restrict__ xh, int* __restrict__ flag) {
  int tid = threadIdx.x;  // 64
  int c = 0;
#pragma unroll
  for (int j = 0; j < 2; ++j) {
    unsigned u = xh[tid * 2 + j];
    unsigned e = (u >> 7) & 0xFF;
    if (e >= 134) c++;
  }
#pragma unroll
  for (int o = 32; o; o >>= 1) c += __shfl_down(c, o);
  if (tid == 0) *flag = (c >= 8) ? 1 : 0;
}

// -------- weight prep ------------------------------------------------------------
#define LDW(ptr, i) (f ? ((const float*)(ptr))[i] : bf2f(((const bf16*)(ptr))[i]))
__global__ __launch_bounds__(256) void k_prep(
    const int* __restrict__ flag,
    const void* g_w, const void* t_w, const void* p_w,
    const void* g_b, const void* t_b, const void* p_b,
    const void* m_w, const void* m_b, const void* r_w, const void* r_b,
    float* __restrict__ ws)
{
  int tid = threadIdx.x;
  int f = *flag;
  for (int i = tid; i < 9216; i += 256) {
    int o = i & 15, t = i >> 4, c = t & 63, tap = t >> 6;
    ws[WG_O + i] = LDW(g_w, (o * 64 + c) * 9 + tap);
  }
  for (int i = tid; i < 1024; i += 256) {
    int o = i & 15, c = i >> 4;
    ws[WT_O + i] = LDW(t_w, o * 64 + c);
    ws[WP_O + i] = LDW(p_w, o * 64 + c);
  }
  if (tid < 16) {
    ws[BG_O + tid] = LDW(g_b, tid);
    ws[BT_O + tid] = LDW(t_b, tid);
    ws[BP_O + tid] = LDW(p_b, tid);
    float s = 0.f;
    for (int c = 0; c < 64; ++c) s += LDW(m_w, tid * 64 + c);
    ws[SM_O + tid] = s;
    ws[SB_O + tid] = LDW(m_b, tid);
  }
  for (int i = tid; i < 1024; i += 256) ws[RW_O + i] = LDW(r_w, i);
  if (tid < 64) ws[RB_O + tid] = LDW(r_b, tid);
  // conv MFMA B, split hi/lo: wB[tap][col64][c64]
  ushort_t* wBh = (ushort_t*)(ws + WB_O);
  ushort_t* wBl = wBh + 9 * 64 * 64;
  for (int i = tid; i < 9 * 64 * 64; i += 256) {
    int c = i & 63, t = i >> 6, col = t & 63, tap = t >> 6;
    float v = 0.f;
    if (col < 16) v = LDW(g_w, (col * 64 + c) * 9 + tap);
    else if (col < 32) { if (tap == 4) v = LDW(t_w, (col - 16) * 64 + c); }
    else if (col < 48) { if (tap == 4) v = LDW(p_w, (col - 32) * 64 + c); }
    ushort_t h, l; splitbf(v, h, l);
    wBh[i] = h; wBl[i] = l;
  }
}

// -------- x [B,64,H,W] -> HWC bf16 hi/lo planes ----------------------------------
__global__ __launch_bounds__(256) void k_hwc(
    const int* __restrict__ flag, const void* __restrict__ x,
    ushort_t* __restrict__ xhh, ushort_t* __restrict__ xhl)
{
  __shared__ float tile[64][65];
  int pix0 = blockIdx.x * 64;
  int tid = threadIdx.x;
  int g = tid >> 6, p = tid & 63;
  int pix = pix0 + p;
  bool ok = pix < B_ * HW;
  int bb = ok ? pix / HW : 0;
  int r  = ok ? pix - bb * HW : 0;
  if (*flag) {
    const float* xf = (const float*)x;
    for (int c = g * 16; c < g * 16 + 16; ++c)
      tile[p][c] = ok ? xf[((size_t)bb * CIN + c) * HW + r] : 0.f;
  } else {
    const bf16* xb = (const bf16*)x;
    for (int c = g * 16; c < g * 16 + 16; ++c)
      tile[p][c] = ok ? bf2f(xb[((size_t)bb * CIN + c) * HW + r]) : 0.f;
  }
  __syncthreads();
  int c2 = tid & 63, pg = tid >> 6;
  for (int k = 0; k < 16; ++k) {
    int p2 = pg * 16 + k;
    int pix2 = pix0 + p2;
    if (pix2 < B_ * HW) {
      ushort_t h, l; splitbf(tile[p2][c2], h, l);
      xhh[(size_t)pix2 * 64 + c2] = h;
      xhl[(size_t)pix2 * 64 + c2] = l;
    }
  }
}

// -------- unified split-bf16 MFMA conv, 128-pixel tile ---------------------------
// C[128px x 64col] = Xh.Wh^T + Xh.Wl^T + Xl.Wh^T, K=576. r12 k_score recipe:
// 2 m-subtiles/wave, 6 LDS reads per 6 MFMA, named-reg prefetch, SLST=72.
__global__ __launch_bounds__(256) void k_conv3(
    const float* __restrict__ ws,
    const ushort_t* __restrict__ xhh, const ushort_t* __restrict__ xhl,
    ushort_t* __restrict__ b1h, ushort_t* __restrict__ b1l,
    ushort_t* __restrict__ b2h, ushort_t* __restrict__ b2l,
    ushort_t* __restrict__ b3)
{
  __shared__ ushort_t sAh[128 * SLST], sAl[128 * SLST];
  __shared__ ushort_t sBh[64 * SLST],  sBl[64 * SLST];
  int bz = blockIdx.z;
  int px0 = blockIdx.x * 128;
  int tid = threadIdx.x, lane = tid & 63, wv = tid >> 6;

  int pix0 = px0 + lane, pix1 = px0 + lane + 64;
  bool pok0 = pix0 < HW, pok1 = pix1 < HW;
  int ph0 = pok0 ? pix0 / W_ : 0, pw0 = pok0 ? pix0 - ph0 * W_ : 0;
  int ph1 = pok1 ? pix1 / W_ : 0, pw1 = pok1 ? pix1 - ph1 * W_ : 0;
  const ushort_t* xplane = ((wv == 0) ? xhh : xhl) + (size_t)bz * HW * 64;
  const ushort_t* wBh_ = (const ushort_t*)(ws + WB_O);
  const ushort_t* bsrc = (wv == 2) ? wBh_ : (wBh_ + 9 * 64 * 64);
  ushort_t* dplane = (wv == 0) ? sAh : (wv == 1) ? sAl : (wv == 2) ? sBh : sBl;
  ushort_t* drow0 = dplane + lane * SLST;
  ushort_t* drow1 = dplane + (lane + 64) * SLST;   // wv<2 only

  int fr = lane & 31, kh = (lane >> 5) << 3;
  int mt = (wv >> 1) << 1;
  int aoff0 = (mt * 32 + fr) * SLST + kh;
  int aoff1 = ((mt + 1) * 32 + fr) * SLST + kh;
  int boff  = (((wv & 1) << 5) + fr) * SLST + kh;

  f32x16 acc0 = {0.f,0.f,0.f,0.f,0.f,0.f,0.f,0.f,0.f,0.f,0.f,0.f,0.f,0.f,0.f,0.f};
  f32x16 acc1 = {0.f,0.f,0.f,0.f,0.f,0.f,0.f,0.f,0.f,0.f,0.f,0.f,0.f,0.f,0.f,0.f};
  const int4 z4 = make_int4(0, 0, 0, 0);
  int4 v0 = z4, v1 = z4, v2 = z4, v3 = z4, v4 = z4, v5 = z4, v6 = z4, v7 = z4;
  int4 u0 = z4, u1 = z4, u2 = z4, u3 = z4, u4 = z4, u5 = z4, u6 = z4, u7 = z4;

  // prefetch tap 0 (dh=-1, dw=-1)
  if (wv < 2) {
    int hh = ph0 - 1, ww = pw0 - 1;
    if (pok0 && hh >= 0 && ww >= 0) {
      const int4* s = (const int4*)(xplane + (size_t)(hh * W_ + ww) * 64);
      v0 = s[0]; v1 = s[1]; v2 = s[2]; v3 = s[3]; v4 = s[4]; v5 = s[5]; v6 = s[6]; v7 = s[7];
    }
    int hh1 = ph1 - 1, ww1 = pw1 - 1;
    if (pok1 && hh1 >= 0 && ww1 >= 0) {
      const int4* s = (const int4*)(xplane + (size_t)(hh1 * W_ + ww1) * 64);
      u0 = s[0]; u1 = s[1]; u2 = s[2]; u3 = s[3]; u4 = s[4]; u5 = s[5]; u6 = s[6]; u7 = s[7];
    }
  } else {
    const int4* s = (const int4*)(bsrc + (size_t)lane * 64);
    v0 = s[0]; v1 = s[1]; v2 = s[2]; v3 = s[3]; v4 = s[4]; v5 = s[5]; v6 = s[6]; v7 = s[7];
  }

  for (int r = 0; r < 9; ++r) {
    __syncthreads();
    *(int4*)(drow0 + 0)  = v0;  *(int4*)(drow0 + 8)  = v1;
    *(int4*)(drow0 + 16) = v2;  *(int4*)(drow0 + 24) = v3;
    *(int4*)(drow0 + 32) = v4;  *(int4*)(drow0 + 40) = v5;
    *(int4*)(drow0 + 48) = v6;  *(int4*)(drow0 + 56) = v7;
    if (wv < 2) {
      *(int4*)(drow1 + 0)  = u0;  *(int4*)(drow1 + 8)  = u1;
      *(int4*)(drow1 + 16) = u2;  *(int4*)(drow1 + 24) = u3;
      *(int4*)(drow1 + 32) = u4;  *(int4*)(drow1 + 40) = u5;
      *(int4*)(drow1 + 48) = u6;  *(int4*)(drow1 + 56) = u7;
    }
    __syncthreads();
    if (r < 8) {
      int rn = r + 1;
      int dh = rn / 3 - 1, dw = rn % 3 - 1;
      if (wv < 2) {
        int hh = ph0 + dh, ww = pw0 + dw;
        if (pok0 && (unsigned)hh < (unsigned)H_ && (unsigned)ww < (unsigned)W_) {
          const int4* s = (const int4*)(xplane + (size_t)(hh * W_ + ww) * 64);
          v0 = s[0]; v1 = s[1]; v2 = s[2]; v3 = s[3]; v4 = s[4]; v5 = s[5]; v6 = s[6]; v7 = s[7];
        } else {
          v0 = z4; v1 = z4; v2 = z4; v3 = z4; v4 = z4; v5 = z4; v6 = z4; v7 = z4;
        }
        int hh1 = ph1 + dh, ww1 = pw1 + dw;
        if (pok1 && (unsigned)hh1 < (unsigned)H_ && (unsigned)ww1 < (unsigned)W_) {
          const int4* s = (const int4*)(xplane + (size_t)(hh1 * W_ + ww1) * 64);
          u0 = s[0]; u1 = s[1]; u2 = s[2]; u3 = s[3]; u4 = s[4]; u5 = s[5]; u6 = s[6]; u7 = s[7];
        } else {
          u0 = z4; u1 = z4; u2 = z4; u3 = z4; u4 = z4; u5 = z4; u6 = z4; u7 = z4;
        }
      } else {
        const int4* s = (const int4*)(bsrc + ((size_t)rn * 64 + lane) * 64);
        v0 = s[0]; v1 = s[1]; v2 = s[2]; v3 = s[3]; v4 = s[4]; v5 = s[5]; v6 = s[6]; v7 = s[7];
      }
    }
#pragma unroll
    for (int t = 0; t < 4; ++t) {
      bfv8 ah0 = *(const bfv8*)(sAh + aoff0 + t * 16);
      bfv8 al0 = *(const bfv8*)(sAl + aoff0 + t * 16);
      bfv8 ah1 = *(const bfv8*)(sAh + aoff1 + t * 16);
      bfv8 al1 = *(const bfv8*)(sAl + aoff1 + t * 16);
      bfv8 bh  = *(const bfv8*)(sBh + boff + t * 16);
      bfv8 bl  = *(const bfv8*)(sBl + boff + t * 16);
      acc0 = __builtin_amdgcn_mfma_f32_32x32x16_bf16(al0, bh, acc0, 0, 0, 0);
      acc0 = __builtin_amdgcn_mfma_f32_32x32x16_bf16(ah0, bl, acc0, 0, 0, 0);
      acc0 = __builtin_amdgcn_mfma_f32_32x32x16_bf16(ah0, bh, acc0, 0, 0, 0);
      acc1 = __builtin_amdgcn_mfma_f32_32x32x16_bf16(al1, bh, acc1, 0, 0, 0);
      acc1 = __builtin_amdgcn_mfma_f32_32x32x16_bf16(ah1, bl, acc1, 0, 0, 0);
      acc1 = __builtin_amdgcn_mfma_f32_32x32x16_bf16(ah1, bh, acc1, 0, 0, 0);
    }
  }

  int nw = ((wv & 1) << 5) + fr;
#pragma unroll
  for (int s = 0; s < 2; ++s) {
    int mbase = (mt + s) * 32;
#pragma unroll
    for (int r = 0; r < 16; ++r) {
      int m = mbase + (r & 3) + ((r >> 2) << 3) + ((lane >> 5) << 2);
      int p2 = px0 + m;
      if (p2 >= HW) continue;
      size_t ob = ((size_t)bz * HW + p2) * 16;
      float val = s ? acc1[r] : acc0[r];
      if (nw < 16) {
        ushort_t h2, l2; splitbf(val + ws[BG_O + nw], h2, l2);
        b1h[ob + nw] = h2; b1l[ob + nw] = l2;
      } else if (nw < 32) {
        int o = nw - 16; ushort_t h2, l2; splitbf(val + ws[BT_O + o], h2, l2);
        b2h[ob + o] = h2; b2l[ob + o] = l2;
      } else if (nw < 48) {
        int o = nw - 32; b3[ob + o] = f2bf(val + ws[BP_O + o]);
      }
    }
  }
}

// -------- fallback conv (LOW tier), dtype-templated VALU -------------------------
template <typename T>
__device__ __forceinline__ void convF_body(
    const void* x, const void* g_w, const void* g_b,
    const void* t_w, const void* t_b, const void* p_w, const void* p_b,
    ushort_t* b1h, ushort_t* b1l, ushort_t* b2h, ushort_t* b2l, ushort_t* b3,
    float* sgw, float* stw, float* spw)
{
  int tid = threadIdx.y * 32 + threadIdx.x;
  for (int i = tid; i < CI * CIN * 9; i += 256) sgw[i] = Ld<T>::f(g_w, i);
  for (int i = tid; i < CI * CIN; i += 256) { stw[i] = Ld<T>::f(t_w, i); spw[i] = Ld<T>::f(p_w, i); }
  __syncthreads();

  int w = blockIdx.x * 32 + threadIdx.x;
  int h = blockIdx.y * 8 + threadIdx.y;
  int b = blockIdx.z;
  if (w >= W_ || h >= H_) return;

  float a1[CI], a2[CI], a3[CI];
#pragma unroll
  for (int o = 0; o < CI; ++o) { a1[o] = 0.f; a2[o] = 0.f; a3[o] = 0.f; }

  const size_t xb = (size_t)b * CIN * HW;
  for (int c = 0; c < CIN; ++c) {
    float xv[9];
#pragma unroll
    for (int dh = 0; dh < 3; ++dh) {
      int hh = h + dh - 1;
      bool rok = ((unsigned)hh < (unsigned)H_);
#pragma unroll
      for (int dw = 0; dw < 3; ++dw) {
        int ww = w + dw - 1;
        bool ok = rok && ((unsigned)ww < (unsigned)W_);
        xv[dh * 3 + dw] = ok ? Ld<T>::f(x, (int)(xb + (size_t)c * HW + hh * W_ + ww)) : 0.f;
      }
    }
    float xc = xv[4];
#pragma unroll
    for (int o = 0; o < CI; ++o) {
      const float* gg = &sgw[(o * CIN + c) * 9];
      float s = gg[0]*xv[0] + gg[1]*xv[1] + gg[2]*xv[2]
              + gg[3]*xv[3] + gg[4]*xv[4] + gg[5]*xv[5]
              + gg[6]*xv[6] + gg[7]*xv[7] + gg[8]*xv[8];
      a1[o] += s;
      a2[o] += stw[o * CIN + c] * xc;
      a3[o] += spw[o * CIN + c] * xc;
    }
  }
  size_t base = ((size_t)b * HW + h * W_ + w) * CI;
#pragma unroll
  for (int o = 0; o < CI; ++o) {
    float v1 = a1[o] + Ld<T>::f(g_b, o);
    float v2 = a2[o] + Ld<T>::f(t_b, o);
    ushort_t hh2, ll2;
    splitbf(v1, hh2, ll2); b1h[base + o] = hh2; b1l[base + o] = ll2;
    splitbf(v2, hh2, ll2); b2h[base + o] = hh2; b2l[base + o] = ll2;
    b3[base + o] = f2bf(a3[o] + Ld<T>::f(p_b, o));
  }
}

__global__ __launch_bounds__(256) void k_convF(
    const int* __restrict__ flag, const void* x,
    const void* g_w, const void* g_b, const void* t_w, const void* t_b,
    const void* p_w, const void* p_b,
    ushort_t* __restrict__ b1h, ushort_t* __restrict__ b1l,
    ushort_t* __restrict__ b2h, ushort_t* __restrict__ b2l,
    ushort_t* __restrict__ b3)
{
  __shared__ float sgw[CI * CIN * 9];
  __shared__ float stw[CI * CIN];
  __shared__ float spw[CI * CIN];
  if (*flag) convF_body<float>(x, g_w, g_b, t_w, t_b, p_w, p_b, b1h, b1l, b2h, b2l, b3, sgw, stw, spw);
  else       convF_body<bf16 >(x, g_w, g_b, t_w, t_b, p_w, p_b, b1h, b1l, b2h, b2l, b3, sgw, stw, spw);
}

// -------- S3[b, pos*16+c] = sum over patches of b3 (bf16 src, fp32 acc) ----------
__global__ __launch_bounds__(256) void k_colsum(const ushort_t* __restrict__ b3, float* __restrict__ S3)
{
  __shared__ float red[16][17];
  int b = blockIdx.x, pos = blockIdx.y;
  int ki = pos / 7, kj = pos % 7;
  int c = threadIdx.x & 15, chunk = threadIdx.x >> 4;
  const ushort_t* B3 = b3 + (size_t)b * HW * CI;
  float s = 0.f;
  for (int l = chunk; l < L_; l += 16) {
    int lh = l / OH_, lw = l % OH_;
    s += bflo((unsigned)B3[((lh * ST + ki) * W_ + lw * ST + kj) * CI + c]);
  }
  red[chunk][c] = s;
  __syncthreads();
  if (threadIdx.x < 16) {
    float t = 0.f;
#pragma unroll
    for (int k = 0; k < 16; ++k) t += red[k][threadIdx.x];
    S3[(b * 49 + pos) * 16 + threadIdx.x] = t;
  }
}

// -------- score GEMM via split-bf16 MFMA, 128x64 tile (r12-verified) -------------
__global__ __launch_bounds__(256) void k_score(
    const ushort_t* __restrict__ b1h, const ushort_t* __restrict__ b1l,
    const ushort_t* __restrict__ b2h, const ushort_t* __restrict__ b2l,
    float* __restrict__ scb, int b0, unsigned scstride_z)
{
  __shared__ ushort_t sAh[128 * SLST], sAl[128 * SLST];
  __shared__ ushort_t sBh[64 * SLST],  sBl[64 * SLST];
  int batch = b0 + blockIdx.z;
  size_t poff_g = (size_t)batch * HW * CI;
  float* Sc = scb + (size_t)blockIdx.z * scstride_z;

  int tid = threadIdx.x;
  int m0 = blockIdx.y * 128, n0 = blockIdx.x * 64;
  int lane = tid & 63;
  int wv = tid >> 6;

  int base_mn = (wv < 2) ? m0 : n0;
  int srow0 = base_mn + lane;       if (srow0 > L_ - 1) srow0 = L_ - 1;
  int srow1 = base_mn + lane + 64;  if (srow1 > L_ - 1) srow1 = L_ - 1;
  int slh0 = srow0 / OH_, slw0 = srow0 - slh0 * OH_;
  int slh1 = srow1 / OH_, slw1 = srow1 - slh1 * OH_;
  int sbase0 = (slh0 * ST) * W_ + slw0 * ST;
  int sbase1 = (slh1 * ST) * W_ + slw1 * ST;
  const ushort_t* splane = (wv == 0) ? (b1h + poff_g) : (wv == 1) ? (b1l + poff_g)
                          : (wv == 2) ? (b2h + poff_g) : (b2l + poff_g);
  ushort_t* dplane = (wv == 0) ? sAh : (wv == 1) ? sAl : (wv == 2) ? sBh : sBl;
  ushort_t* drow0 = dplane + lane * SLST;
  ushort_t* drow1 = dplane + (lane + 64) * SLST;   // only written when wv<2

  int fr = lane & 31;
  int kh = (lane >> 5) << 3;
  int mt = (wv >> 1) << 1;                         // first m-subtile: 0 or 2
  int aoff0 = (mt * 32 + fr) * SLST + kh;
  int aoff1 = ((mt + 1) * 32 + fr) * SLST + kh;
  int boff  = (((wv & 1) << 5) + fr) * SLST + kh;

  f32x16 acc0 = {0.f,0.f,0.f,0.f,0.f,0.f,0.f,0.f,0.f,0.f,0.f,0.f,0.f,0.f,0.f,0.f};
  f32x16 acc1 = {0.f,0.f,0.f,0.f,0.f,0.f,0.f,0.f,0.f,0.f,0.f,0.f,0.f,0.f,0.f,0.f};

  const int4 z4 = make_int4(0, 0, 0, 0);
  int4 v0, v1, v2, v3, v4, v5, v6, v7;
  int4 u0 = z4, u1 = z4, u2 = z4, u3 = z4, u4 = z4, u5 = z4, u6 = z4, u7 = z4;
  {
    const int4* s0 = (const int4*)(splane + (size_t)sbase0 * 16);
    v0 = s0[0]; v1 = s0[1]; v2 = s0[2]; v3 = s0[3];
    v4 = s0[4]; v5 = s0[5]; v6 = s0[6]; v7 = s0[7];
    if (wv < 2) {
      const int4* s1 = (const int4*)(splane + (size_t)sbase1 * 16);
      u0 = s1[0]; u1 = s1[1]; u2 = s1[2]; u3 = s1[3];
      u4 = s1[4]; u5 = s1[5]; u6 = s1[6]; u7 = s1[7];
    }
  }

  for (int r = 0; r < 14; ++r) {
    int half = r & 1;
    __syncthreads();
    *(int4*)(drow0 + 0)  = v0;  *(int4*)(drow0 + 8)  = v1;
    *(int4*)(drow0 + 16) = v2;  *(int4*)(drow0 + 24) = v3;
    *(int4*)(drow0 + 32) = v4;  *(int4*)(drow0 + 40) = v5;
    if (!half) { *(int4*)(drow0 + 48) = v6; *(int4*)(drow0 + 56) = v7; }
    if (wv < 2) {
      *(int4*)(drow1 + 0)  = u0;  *(int4*)(drow1 + 8)  = u1;
      *(int4*)(drow1 + 16) = u2;  *(int4*)(drow1 + 24) = u3;
      *(int4*)(drow1 + 32) = u4;  *(int4*)(drow1 + 40) = u5;
      if (!half) { *(int4*)(drow1 + 48) = u6; *(int4*)(drow1 + 56) = u7; }
    }
    __syncthreads();
    if (r < 13) {
      int rn = r + 1;
      int nki = rn >> 1, nkj0 = (rn & 1) * 4;
      const int4* s0 = (const int4*)(splane + (size_t)(sbase0 + nki * W_ + nkj0) * 16);
      v0 = s0[0]; v1 = s0[1]; v2 = s0[2]; v3 = s0[3]; v4 = s0[4]; v5 = s0[5];
      if (!(rn & 1)) { v6 = s0[6]; v7 = s0[7]; }
      if (wv < 2) {
        const int4* s1 = (const int4*)(splane + (size_t)(sbase1 + nki * W_ + nkj0) * 16);
        u0 = s1[0]; u1 = s1[1]; u2 = s1[2]; u3 = s1[3]; u4 = s1[4]; u5 = s1[5];
        if (!(rn & 1)) { u6 = s1[6]; u7 = s1[7]; }
      }
    }
    if (!half) {
#pragma unroll
      for (int t = 0; t < 4; ++t) {
        bfv8 ah0 = *(const bfv8*)(sAh + aoff0 + t * 16);
        bfv8 al0 = *(const bfv8*)(sAl + aoff0 + t * 16);
        bfv8 ah1 = *(const bfv8*)(sAh + aoff1 + t * 16);
        bfv8 al1 = *(const bfv8*)(sAl + aoff1 + t * 16);
        bfv8 bh  = *(const bfv8*)(sBh + boff + t * 16);
        bfv8 bl  = *(const bfv8*)(sBl + boff + t * 16);
        acc0 = __builtin_amdgcn_mfma_f32_32x32x16_bf16(al0, bh, acc0, 0, 0, 0);
        acc0 = __builtin_amdgcn_mfma_f32_32x32x16_bf16(ah0, bl, acc0, 0, 0, 0);
        acc0 = __builtin_amdgcn_mfma_f32_32x32x16_bf16(ah0, bh, acc0, 0, 0, 0);
        acc1 = __builtin_amdgcn_mfma_f32_32x32x16_bf16(al1, bh, acc1, 0, 0, 0);
        acc1 = __builtin_amdgcn_mfma_f32_32x32x16_bf16(ah1, bl, acc1, 0, 0, 0);
        acc1 = __builtin_amdgcn_mfma_f32_32x32x16_bf16(ah1, bh, acc1, 0, 0, 0);
      }
    } else {
#pragma unroll
      for (int t = 0; t < 3; ++t) {
        bfv8 ah0 = *(const bfv8*)(sAh + aoff0 + t * 16);
        bfv8 al0 = *(const bfv8*)(sAl + aoff0 + t * 16);
        bfv8 ah1 = *(const bfv8*)(sAh + aoff1 + t * 16);
        bfv8 al1 = *(const bfv8*)(sAl + aoff1 + t * 16);
        bfv8 bh  = *(const bfv8*)(sBh + boff + t * 16);
        bfv8 bl  = *(const bfv8*)(sBl + boff + t * 16);
        acc0 = __builtin_amdgcn_mfma_f32_32x32x16_bf16(al0, bh, acc0, 0, 0, 0);
        acc0 = __builtin_amdgcn_mfma_f32_32x32x16_bf16(ah0, bl, acc0, 0, 0, 0);
        acc0 = __builtin_amdgcn_mfma_f32_32x32x16_bf16(ah0, bh, acc0, 0, 0, 0);
        acc1 = __builtin_amdgcn_mfma_f32_32x32x16_bf16(al1, bh, acc1, 0, 0, 0);
        acc1 = __builtin_amdgcn_mfma_f32_32x32x16_bf16(ah1, bl, acc1, 0, 0, 0);
        acc1 = __builtin_amdgcn_mfma_f32_32x32x16_bf16(ah1, bh, acc1, 0, 0, 0);
      }
    }
  }

  int nw = n0 + ((wv & 1) << 5) + fr;
  if (nw < L_) {
    int mw0 = m0 + mt * 32;
#pragma unroll
    for (int r = 0; r < 16; ++r) {
      int m = mw0 + (r & 3) + ((r >> 2) << 3) + ((lane >> 5) << 2);
      if (m < L_) Sc[(size_t)m * SROW + nw] = acc0[r];
    }
    int mw1 = m0 + (mt + 1) * 32;
#pragma unroll
    for (int r = 0; r < 16; ++r) {
      int m = mw1 + (r & 3) + ((r >> 2) << 3) + ((lane >> 5) << 2);
      if (m < L_) Sc[(size_t)m * SROW + nw] = acc1[r];
    }
  }
}

// -------- top-100 + softmax weights: 4 rows per block (1 wave each) --------------
__global__ __launch_bounds__(256) void k_topk(
    const float* __restrict__ scb, float* __restrict__ tkw, int* __restrict__ tkp,
    unsigned scstride_z)
{
  __shared__ float swv[4][TOPM];
  __shared__ int spx[4][TOPM];
  int tid = threadIdx.x;
  int wvi = tid >> 6, lane = tid & 63;
  int l = blockIdx.x * 4 + wvi;
  if (l > L_ - 1) l = L_ - 1;        // clamp: duplicate rows write identical data
  int bz = blockIdx.y;
  const float4* row4 = (const float4*)(scb + (size_t)bz * scstride_z + (size_t)l * SROW);
  int trow = (bz * L_ + l) * TKROW;

  unsigned k[16];
#pragma unroll
  for (int q = 0; q < 4; ++q) {
    float4 v = row4[q * 64 + lane];
    int ib = (q * 64 + lane) * 4;
    k[q * 4 + 0] = (ib + 0 < L_) ? fmap(v.x) : 0u;
    k[q * 4 + 1] = (ib + 1 < L_) ? fmap(v.y) : 0u;
    k[q * 4 + 2] = (ib + 2 < L_) ? fmap(v.z) : 0u;
    k[q * 4 + 3] = (ib + 3 < L_) ? fmap(v.w) : 0u;
  }

  unsigned mk = 0;
#pragma unroll
  for (int r = 0; r < 16; ++r) mk = max(mk, k[r]);
#pragma unroll
  for (int o = 32; o; o >>= 1) mk = max(mk, (unsigned)__shfl_down((int)mk, o));
  mk = (unsigned)__shfl((int)mk, 0);
  float vmax = unfmap(mk);

  unsigned alive = 0xFFFFu;
  unsigned prefix = 0; int base = 0;
  for (int bit = 30; bit >= 0; bit -= 2) {
    int c1 = 0, c2 = 0, c3 = 0;
#pragma unroll
    for (int r = 0; r < 16; ++r) {
      if ((alive >> r) & 1) {
        unsigned f = (k[r] >> bit) & 3u;
        c3 += (f == 3); c2 += (f >= 2); c1 += (f >= 1);
      }
    }
    int p = c3 | (c2 << 10) | (c1 << 20);
#pragma unroll
    for (int o = 32; o; o >>= 1) p += __shfl_down(p, o);
    p = __shfl(p, 0);
    int n3 = p & 1023, n2 = (p >> 10) & 1023, n1 = (p >> 20) & 1023;
    unsigned ch;
    if (base + n3 >= TOPM) ch = 3;
    else if (base + n2 >= TOPM) { ch = 2; base += n3; }
    else if (base + n1 >= TOPM) { ch = 1; base += n2; }
    else { ch = 0; base += n1; }
    prefix |= ch << bit;
#pragma unroll
    for (int r = 0; r < 16; ++r) {
      if ((alive >> r) & 1) {
        unsigned f = (k[r] >> bit) & 3u;
        if (f != ch) alive &= ~(1u << r);
      }
    }
  }
  int nA = base;
  int needT = TOPM - nA;

  int cA = 0, cT = 0;
#pragma unroll
  for (int r = 0; r < 16; ++r) { cA += (k[r] > prefix); cT += (k[r] == prefix); }
  int pk = cA | (cT << 16);
  int incl = pk;
#pragma unroll
  for (int o = 1; o < 64; o <<= 1) { int t = __shfl_up(incl, o); if (lane >= o) incl += t; }
  int excl = incl - pk;
  int tA = excl & 0xFFFF, tT = excl >> 16;

  float M = fmaxf(10.f * vmax, 0.f);
  float e0 = expf(-M);
  float z = 0.f;
#pragma unroll
  for (int r = 0; r < 16; ++r) {
    unsigned kk = k[r];
    int slot = -1;
    if (kk > prefix) slot = tA++;
    else if (kk == prefix) { if (tT < needT) slot = nA + tT; tT++; }
    if (slot >= 0) {
      float v = unfmap(kk);
      float wv = expf(10.f * v - M);
      swv[wvi][slot] = wv; z += wv;
      int gi = 256 * (r >> 2) + 4 * lane + (r & 3);
      int lh = gi / OH_, lw = gi - lh * OH_;
      spx[wvi][slot] = ((lh * ST) * W_ + lw * ST) * CI;
    }
  }
#pragma unroll
  for (int o = 32; o; o >>= 1) z += __shfl_down(z, o);
  z = __shfl(z, 0);
  float Z = z + (float)(L_ - TOPM) * e0;
  float invZ = 1.f / Z;
  float w0 = e0 / Z;
  __syncthreads();
#pragma unroll
  for (int s0 = 0; s0 < 2; ++s0) {
    int s = lane + 64 * s0;
    if (s < TOPM) {
      tkw[trow + s] = swv[wvi][s] * invZ - w0;
      tkp[trow + s] = spx[wvi][s];
    }
  }
  if (lane == 0) tkw[trow + TOPM] = w0;
}

// -------- PV gather (bf16 b3, uint4 full-line): 98 lanes x 8 channels ------------
__global__ __launch_bounds__(128) void k_pv(
    const float* __restrict__ tkw, const int* __restrict__ tkp,
    const ushort_t* __restrict__ b3, const float* __restrict__ s3,
    float* __restrict__ agb, int b0, unsigned agstride_z)
{
  int l = blockIdx.x, bz = blockIdx.y;
  int batch = b0 + bz;
  int trow = (bz * L_ + l) * TKROW;
  const ushort_t* B3 = b3 + (size_t)batch * HW * CI;
  const float* S3 = s3 + (size_t)batch * D_;
  float* agg = agb + (size_t)bz * agstride_z;
  int tid = threadIdx.x;
  if (tid >= 98) return;

  float w0 = tkw[trow + TOPM];
  int pos = tid >> 1;
  int c0 = (tid & 1) << 3;                 // 0 or 8
  int ki = pos / 7, kj = pos - (pos / 7) * 7;
  int poff = (ki * W_ + kj) * CI + c0;

  float a0 = 0.f, a1 = 0.f, a2 = 0.f, a3 = 0.f;
  float a4 = 0.f, a5 = 0.f, a6 = 0.f, a7 = 0.f;
  for (int j0 = 0; j0 < TOPM; j0 += 4) {
    float w_0 = tkw[trow + j0 + 0];
    float w_1 = tkw[trow + j0 + 1];
    float w_2 = tkw[trow + j0 + 2];
    float w_3 = tkw[trow + j0 + 3];
    int p_0 = tkp[trow + j0 + 0];
    int p_1 = tkp[trow + j0 + 1];
    int p_2 = tkp[trow + j0 + 2];
    int p_3 = tkp[trow + j0 + 3];
    const uint4 q0 = *(const uint4*)(B3 + p_0 + poff);
    const uint4 q1 = *(const uint4*)(B3 + p_1 + poff);
    const uint4 q2 = *(const uint4*)(B3 + p_2 + poff);
    const uint4 q3 = *(const uint4*)(B3 + p_3 + poff);
    a0 += w_0 * bflo(q0.x); a1 += w_0 * bfhi(q0.x); a2 += w_0 * bflo(q0.y); a3 += w_0 * bfhi(q0.y);
    a4 += w_0 * bflo(q0.z); a5 += w_0 * bfhi(q0.z); a6 += w_0 * bflo(q0.w); a7 += w_0 * bfhi(q0.w);
    a0 += w_1 * bflo(q1.x); a1 += w_1 * bfhi(q1.x); a2 += w_1 * bflo(q1.y); a3 += w_1 * bfhi(q1.y);
    a4 += w_1 * bflo(q1.z); a5 += w_1 * bfhi(q1.z); a6 += w_1 * bflo(q1.w); a7 += w_1 * bfhi(q1.w);
    a0 += w_2 * bflo(q2.x); a1 += w_2 * bfhi(q2.x); a2 += w_2 * bflo(q2.y); a3 += w_2 * bfhi(q2.y);
    a4 += w_2 * bflo(q2.z); a5 += w_2 * bfhi(q2.z); a6 += w_2 * bflo(q2.w); a7 += w_2 * bfhi(q2.w);
    a0 += w_3 * bflo(q3.x); a1 += w_3 * bfhi(q3.x); a2 += w_3 * bflo(q3.y); a3 += w_3 * bfhi(q3.y);
    a4 += w_3 * bflo(q3.z); a5 += w_3 * bfhi(q3.z); a6 += w_3 * bflo(q3.w); a7 += w_3 * bfhi(q3.w);
  }
  const float4 s40 = *(const float4*)(S3 + tid * 8);
  const float4 s41 = *(const float4*)(S3 + tid * 8 + 4);
  a0 += w0 * s40.x; a1 += w0 * s40.y; a2 += w0 * s40.z; a3 += w0 * s40.w;
  a4 += w0 * s41.x; a5 += w0 * s41.y; a6 += w0 * s41.z; a7 += w0 * s41.w;
  float* dst = agg + (size_t)l * D_ + tid * 8;
  *(float4*)(dst)     = make_float4(a0, a1, a2, a3);
  *(float4*)(dst + 4) = make_float4(a4, a5, a6, a7);
}

// -------- fold + mask divide + restore (16->64), batched -------------------------
__global__ __launch_bounds__(256) void k_fold(
    const int* __restrict__ flag, const float* __restrict__ ws,
    const float* __restrict__ agb, void* __restrict__ out,
    int b0, unsigned agstride_z)
{
  __shared__ float srw[CIN * CI];
  int tid = threadIdx.x;
  for (int i = tid; i < CIN * CI; i += 256) srw[i] = ws[RW_O + i];
  __syncthreads();

  int bz = blockIdx.y;
  int batch = b0 + bz;
  const float* agg = agb + (size_t)bz * agstride_z;

  int gid = blockIdx.x * 256 + tid;
  if (gid >= HW) return;
  int h = gid / W_;
  int w = gid % W_;

  int lh0 = (h >= KS - 1) ? ((h - (KS - 1) + (ST - 1)) >> 2) : 0;
  int lh1 = min(OH_ - 1, h >> 2);
  int lw0 = (w >= KS - 1) ? ((w - (KS - 1) + (ST - 1)) >> 2) : 0;
  int lw1 = min(OH_ - 1, w >> 2);

  float t[CI];
#pragma unroll
  for (int c = 0; c < CI; ++c) t[c] = 0.f;
  for (int lh = lh0; lh <= lh1; ++lh) {
    int ki = h - ST * lh;
    for (int lw = lw0; lw <= lw1; ++lw) {
      int kj = w - ST * lw;
      const float* pb = agg + (size_t)(lh * OH_ + lw) * D_ + (ki * KS + kj) * CI;
      float4 q0 = *(const float4*)(pb);
      float4 q1 = *(const float4*)(pb + 4);
      float4 q2 = *(const float4*)(pb + 8);
      float4 q3 = *(const float4*)(pb + 12);
      t[0] += q0.x; t[1] += q0.y; t[2] += q0.z; t[3] += q0.w;
      t[4] += q1.x; t[5] += q1.y; t[6] += q1.z; t[7] += q1.w;
      t[8] += q2.x; t[9] += q2.y; t[10] += q2.z; t[11] += q2.w;
      t[12] += q3.x; t[13] += q3.y; t[14] += q3.z; t[15] += q3.w;
    }
  }
  float cnt = (float)((lh1 - lh0 + 1) * (lw1 - lw0 + 1));
  float r[CI];
#pragma unroll
  for (int c = 0; c < CI; ++c) r[c] = t[c] / (cnt * ws[SM_O + c] + ws[SB_O + c] + 1e-8f);

  size_t ob = (size_t)batch * CIN * HW + (size_t)h * W_ + w;
  if (*flag) {
    float* of = (float*)out;
#pragma unroll
    for (int o = 0; o < CIN; ++o) {
      float s = ws[RB_O + o];
#pragma unroll
      for (int c = 0; c < CI; ++c) s += srw[o * CI + c] * r[c];
      of[ob + (size_t)o * HW] = s;
    }
  } else {
    bf16* of = (bf16*)out;
#pragma unroll
    for (int o = 0; o < CIN; ++o) {
      float s = ws[RB_O + o];
#pragma unroll
      for (int c = 0; c < CI; ++c) s += srw[o * CI + c] * r[c];
      of[ob + (size_t)o * HW] = __float2bfloat16(s);
    }
  }
}

extern "C" void kernel_launch(void* const* d_in, const int* in_sizes, int n_in,
                              void* d_out, int out_size, void* d_ws, size_t ws_size,
                              hipStream_t stream)
{
  const void* x    = d_in[0];
  const void* g_w  = d_in[1];
  const void* g_b  = d_in[2];
  const void* th_w = d_in[3];
  const void* th_b = d_in[4];
  const void* ph_w = d_in[5];
  const void* ph_b = d_in[6];
  const void* m_w  = d_in[7];
  const void* m_b  = d_in[8];
  const void* r_w  = d_in[9];
  const void* r_b  = d_in[10];

  float* W = (float*)d_ws;
  int* flag = (int*)d_ws;
  ushort_t* planes = (ushort_t*)(W + B1_O);
  ushort_t* b1h = planes;
  ushort_t* b1l = planes + (size_t)N1;
  ushort_t* b2h = planes + (size_t)2 * N1;
  ushort_t* b2l = planes + (size_t)3 * N1;
  ushort_t* b3  = planes + (size_t)4 * N1;   // bf16 plane, N1 ushorts
  float* s3 = W + S3_O;

  k_detect<<<1, 64, 0, stream>>>((const unsigned short*)x, flag);
  k_prep<<<1, 256, 0, stream>>>(flag, g_w, th_w, ph_w, g_b, th_b, ph_b,
                                m_w, m_b, r_w, r_b, W);

  if (ws_size >= FULL_BYTES) {
    ushort_t* xhh = (ushort_t*)(W + REG_O);    // bf16 hi/lo x planes, dead after conv
    ushort_t* xhl = xhh + (size_t)XHSZ;
    float* sc = W + REG_O;                     // 4 x SCSLOT, aliases x planes
    float* ag = W + REG_O + XHSZ;              // 4 x AGSZ
    float* tkw = W + B1_O + N1;                // b2h region (dead after k_score)
    int*   tkp = (int*)(W + B1_O + N1 + N1 / 2);
    k_hwc<<<dim3((B_ * HW + 63) / 64), 256, 0, stream>>>(flag, x, xhh, xhl);
    k_conv3<<<dim3((HW + 127) / 128, 1, B_), 256, 0, stream>>>(
        W, xhh, xhl, b1h, b1l, b2h, b2l, b3);
    k_colsum<<<dim3(B_, 49), 256, 0, stream>>>(b3, s3);
    k_score<<<dim3(16, 8, B_), 256, 0, stream>>>(b1h, b1l, b2h, b2l, sc, 0, SCSLOT);
    k_topk<<<dim3((L_ + 3) / 4, B_), 256, 0, stream>>>(sc, tkw, tkp, SCSLOT);
    k_pv<<<dim3(L_, B_), 128, 0, stream>>>(tkw, tkp, b3, s3, ag, 0, AGSZ);
    k_fold<<<dim3(64, B_), 256, 0, stream>>>(flag, W, ag, d_out, 0, AGSZ);
  } else if (ws_size >= MID_BYTES) {
    ushort_t* xhh = (ushort_t*)(W + REG_O);
    ushort_t* xhl = xhh + (size_t)XHSZ;
    float* sc = W + REG_O;
    float* ag = W + REG_O + SCSLOT;
    k_hwc<<<dim3((B_ * HW + 63) / 64), 256, 0, stream>>>(flag, x, xhh, xhl);
    k_conv3<<<dim3((HW + 127) / 128, 1, B_), 256, 0, stream>>>(
        W, xhh, xhl, b1h, b1l, b2h, b2l, b3);
    k_colsum<<<dim3(B_, 49), 256, 0, stream>>>(b3, s3);
    for (int b = 0; b < B_; ++b) {
      float* tkw = W + B1_O + N1 + (size_t)b * (HW * CI / 2);
      int*   tkp = (int*)(W + B1_O + N1 + N1 / 2 + (size_t)b * (HW * CI / 2));
      k_score<<<dim3(16, 8, 1), 256, 0, stream>>>(b1h, b1l, b2h, b2l, sc, b, 0);
      k_topk<<<dim3((L_ + 3) / 4, 1), 256, 0, stream>>>(sc, tkw, tkp, 0);
      k_pv<<<dim3(L_, 1), 128, 0, stream>>>(tkw, tkp, b3, s3, ag, b, 0);
      k_fold<<<dim3(64, 1), 256, 0, stream>>>(flag, W, ag, d_out, b, 0);
    }
  } else {
    float* sc = W + REG_O;
    float* ag = W + REG_O + SCSLOT;
    k_convF<<<dim3(4, 16, B_), dim3(32, 8, 1), 0, stream>>>(
        flag, x, g_w, g_b, th_w, th_b, ph_w, ph_b, b1h, b1l, b2h, b2l, b3);
    k_colsum<<<dim3(B_, 49), 256, 0, stream>>>(b3, s3);
    for (int b = 0; b < B_; ++b) {
      float* tkw = W + B1_O + N1 + (size_t)b * (HW * CI / 2);
      int*   tkp = (int*)(W + B1_O + N1 + N1 / 2 + (size_t)b * (HW * CI / 2));
      k_score<<<dim3(16, 8, 1), 256, 0, stream>>>(b1h, b1l, b2h, b2l, sc, b, 0);
      k_topk<<<dim3((L_ + 3) / 4, 1), 256, 0, stream>>>(sc, tkw, tkp, 0);
      k_pv<<<dim3(L_, 1), 128, 0, stream>>>(tkw, tkp, b3, s3, ag, b, 0);
      k_fold<<<dim3(64, 1), 256, 0, stream>>>(flag, W, ag, d_out, b, 0);
    }
  }
}